// Round 13
// baseline (189.168 us; speedup 1.0000x reference)
//
#include <hip/hip_runtime.h>
#include <hip/hip_bf16.h>
#include <math.h>

#define TOK 8192       // B*S
#define DIM 256
#define SEQ 1024
#define NH 8
#define FFD 1024
#define NL 2
#define VOCAB 32000
#define QKSTRIDE 2097152   // elems between Q and K head-major blocks

typedef short bf16x8 __attribute__((ext_vector_type(8)));
typedef float f32x4 __attribute__((ext_vector_type(4)));

__device__ __forceinline__ ushort f2bf(float f) {
  union { float f; uint32_t u; } v; v.f = f;
  uint32_t r = v.u + 0x7FFFu + ((v.u >> 16) & 1u);
  return (ushort)(r >> 16);
}

__device__ __forceinline__ float bf2f(ushort u) {
  union { uint32_t u; float f; } v; v.u = (uint32_t)u << 16; return v.f;
}

__device__ __forceinline__ float exp2_n(float x) {
  float r; asm("v_exp_f32 %0, %1" : "=v"(r) : "v"(x)); return r;
}

__device__ __forceinline__ uint32_t cvtpk(float lo, float hi) {
  uint32_t r; asm("v_cvt_pk_bf16_f32 %0, %1, %2" : "=v"(r) : "v"(lo), "v"(hi));
  return r;
}

__device__ __forceinline__ void gload_lds16(const ushort* gp, ushort* lp) {
  __builtin_amdgcn_global_load_lds(
      (const __attribute__((address_space(1))) void*)gp,
      (__attribute__((address_space(3))) void*)lp, 16, 0, 0);
}

// ---------------- embedding + ngram + tfidf bias + fused layer-0 LN ----------------
__global__ __launch_bounds__(256) void embed_ln_kernel(
    const int* __restrict__ ids, const int* __restrict__ ngram_ids,
    const float* __restrict__ tfidf, const float* __restrict__ emb,
    const float* __restrict__ pos, const float* __restrict__ bucket,
    const float* __restrict__ alpha, const float* __restrict__ g1,
    const float* __restrict__ be1,
    float* __restrict__ x, ushort* __restrict__ x2b, float* __restrict__ bm2)
{
  __shared__ int ngs[12];
  __shared__ float red[2][4];
  const int t = blockIdx.x;
  const int id = ids[t];
  int idc = id; if (idc < 0) idc = 0; if (idc > VOCAB-1) idc = VOCAB-1;
  if (threadIdx.x < 12) ngs[threadIdx.x] = ngram_ids[idc*12 + threadIdx.x];
  if (threadIdx.x == 0) {
    const float tf = tfidf[idc];
    const bool msk = (id == 0);
    const float l2e = 1.4426950408889634f;
    bm2[t]       = msk ? -1e30f : tf * alpha[0] * l2e;
    bm2[TOK + t] = msk ? -1e30f : tf * alpha[1] * l2e;
  }
  __syncthreads();
  const int d = threadIdx.x;
  const int s = t & (SEQ - 1);
  float v = emb[(size_t)id*DIM + d] + pos[s*DIM + d];
  float sum = 0.f; int cnt = 0;
  #pragma unroll
  for (int g = 0; g < 12; ++g) {
    const int ng = ngs[g];
    if (ng != 0) { sum += bucket[(size_t)ng*DIM + d]; cnt++; }
  }
  v += sum / fmaxf((float)cnt, 1.0f);
  x[(size_t)t*DIM + d] = v;
  // fused LN (layer 0, ln1)
  const int wave = d >> 6, lane = d & 63;
  float sm = v;
  #pragma unroll
  for (int o = 32; o >= 1; o >>= 1) sm += __shfl_xor(sm, o);
  if (lane == 0) red[0][wave] = sm;
  __syncthreads();
  const float mean = (red[0][0]+red[0][1]+red[0][2]+red[0][3]) * (1.f/256.f);
  const float dv = v - mean;
  float q = dv * dv;
  #pragma unroll
  for (int o = 32; o >= 1; o >>= 1) q += __shfl_xor(q, o);
  if (lane == 0) red[1][wave] = q;
  __syncthreads();
  const float var = (red[1][0]+red[1][1]+red[1][2]+red[1][3]) * (1.f/256.f);
  const float rs = rsqrtf(var + 1e-5f);
  x2b[(size_t)t*DIM + d] = f2bf(dv*rs*g1[d] + be1[d]);
}

// ---------------- layernorm -> bf16 ----------------
__global__ __launch_bounds__(256) void ln_bf16(
    const float* __restrict__ x, const float* __restrict__ g,
    const float* __restrict__ b, ushort* __restrict__ y)
{
  const int wave = threadIdx.x >> 6, lane = threadIdx.x & 63;
  const int row = blockIdx.x * 4 + wave;
  const float* xr = x + (size_t)row * DIM;
  float4 v = *reinterpret_cast<const float4*>(xr + lane*4);
  float s = v.x + v.y + v.z + v.w;
  #pragma unroll
  for (int o = 32; o >= 1; o >>= 1) s += __shfl_xor(s, o);
  const float mean = s * (1.f/256.f);
  const float dx0 = v.x-mean, dx1 = v.y-mean, dx2 = v.z-mean, dx3 = v.w-mean;
  float q = dx0*dx0 + dx1*dx1 + dx2*dx2 + dx3*dx3;
  #pragma unroll
  for (int o = 32; o >= 1; o >>= 1) q += __shfl_xor(q, o);
  const float rs = rsqrtf(q * (1.f/256.f) + 1e-5f);
  float4 gv = *reinterpret_cast<const float4*>(g + lane*4);
  float4 bv = *reinterpret_cast<const float4*>(b + lane*4);
  ushort4 o4;
  o4.x = f2bf(dx0*rs*gv.x + bv.x);
  o4.y = f2bf(dx1*rs*gv.y + bv.y);
  o4.z = f2bf(dx2*rs*gv.z + bv.z);
  o4.w = f2bf(dx3*rs*gv.w + bv.w);
  *reinterpret_cast<ushort4*>(y + (size_t)row*DIM + lane*4) = o4;
}

// ---------------- weight transpose + bf16: f32 [K][N] -> bf16 [N][K] ----------------
struct TDesc { const float* src; ushort* dst; int K; int N; };
struct TDescs { TDesc d[12]; };

__global__ __launch_bounds__(256) void transpose_conv(TDescs descs)
{
  const TDesc t = descs.d[blockIdx.z];
  const int k0 = blockIdx.x * 32, n0 = blockIdx.y * 32;
  if (k0 >= t.K || n0 >= t.N) return;
  __shared__ float tile[32][33];
  const int r = threadIdx.x >> 5, cc = threadIdx.x & 31;
  #pragma unroll
  for (int i = 0; i < 4; ++i)
    tile[r + i*8][cc] = t.src[(size_t)(k0 + r + i*8)*t.N + n0 + cc];
  __syncthreads();
  #pragma unroll
  for (int i = 0; i < 4; ++i)
    t.dst[(size_t)(n0 + r + i*8)*t.K + k0 + cc] = f2bf(tile[cc][r + i*8]);
}

// ---------------- bf16 MFMA GEMM, counted-vmcnt 3-buffer pipeline ----------------
// BM=64, BN=128, BK=32; 4 waves, wave w owns cols [w*32,+32); frags 4x2.
// MODE 1: relu + bf16 out;
// MODE 3: qkv -> Q,K head-major + V permuted (l=0 path);
// MODE 4: K,V BOTH head-major (layer-2 tail path; Cout=K base, vtb=V base).
template<int KDIM, int NDIM, int MODE>
__global__ __launch_bounds__(256) void gemm_mfma(
    const ushort* __restrict__ A, const ushort* __restrict__ Bw,
    const float* __restrict__ bias0, const float* __restrict__ bias1,
    const float* __restrict__ bias2, void* __restrict__ Cout,
    ushort* __restrict__ vtb)
{
  __shared__ ushort Al[3][64*32];
  __shared__ ushort Bl[3][128*32];
  const int bm = blockIdx.y * 64, bn = blockIdx.x * 128;
  const int tid = threadIdx.x, w = tid >> 6, lane = tid & 63;
  const int g = lane >> 4, c = lane & 15;
  const int lrow = lane >> 2, lc8 = (lane & 3) << 3;
  const f32x4 fzero = {0.f, 0.f, 0.f, 0.f};
  f32x4 acc[4][2];
  #pragma unroll
  for (int m = 0; m < 4; ++m) { acc[m][0] = fzero; acc[m][1] = fzero; }

#define STAGE(buf, k0)                                                         \
  {                                                                            \
    _Pragma("unroll")                                                          \
    for (int ch = w; ch < 12; ch += 4) {                                       \
      if (ch < 4)                                                              \
        gload_lds16(A + (size_t)(bm + ch*16 + lrow)*KDIM + (k0) + lc8,         \
                    &Al[buf][ch*512]);                                         \
      else                                                                     \
        gload_lds16(Bw + (size_t)(bn + (ch-4)*16 + lrow)*KDIM + (k0) + lc8,    \
                    &Bl[buf][(ch-4)*512]);                                     \
    }                                                                          \
  }

#define COMPUTE(buf)                                                           \
  {                                                                            \
    bf16x8 af[4], bfr[2];                                                      \
    _Pragma("unroll")                                                          \
    for (int m = 0; m < 4; ++m)                                                \
      af[m] = *(const bf16x8*)&Al[buf][(m*16 + c)*32 + g*8];                   \
    _Pragma("unroll")                                                          \
    for (int n = 0; n < 2; ++n)                                                \
      bfr[n] = *(const bf16x8*)&Bl[buf][(w*32 + n*16 + c)*32 + g*8];           \
    _Pragma("unroll")                                                          \
    for (int m = 0; m < 4; ++m)                                                \
      _Pragma("unroll")                                                        \
      for (int n = 0; n < 2; ++n)                                              \
        acc[m][n] = __builtin_amdgcn_mfma_f32_16x16x32_bf16(af[m], bfr[n], acc[m][n], 0, 0, 0); \
  }

  STAGE(0, 0);
  STAGE(1, 32);
  STAGE(2, 64);
  int buf = 0;
  for (int k0 = 0; k0 + 64 < KDIM; k0 += 32) {
    asm volatile("s_waitcnt vmcnt(6)" ::: "memory");
    __builtin_amdgcn_s_barrier();
    COMPUTE(buf);
    asm volatile("s_waitcnt lgkmcnt(0)" ::: "memory");
    __builtin_amdgcn_s_barrier();
    if (k0 + 96 < KDIM) STAGE(buf, k0 + 96);
    buf = (buf == 2) ? 0 : buf + 1;
  }
  asm volatile("s_waitcnt vmcnt(3)" ::: "memory");
  __builtin_amdgcn_s_barrier();
  COMPUTE(buf);
  buf = (buf == 2) ? 0 : buf + 1;
  asm volatile("s_waitcnt vmcnt(0)" ::: "memory");
  __builtin_amdgcn_s_barrier();
  COMPUTE(buf);
#undef STAGE
#undef COMPUTE

  #pragma unroll
  for (int m = 0; m < 4; ++m) {
    const int row0 = bm + m*16 + g*4;
    #pragma unroll
    for (int n = 0; n < 2; ++n) {
      const int col = bn + w*32 + n*16 + c;
      if (MODE == 1) {
        const float bb = bias0[col];
        #pragma unroll
        for (int r = 0; r < 4; ++r) {
          const float vv = fmaxf(acc[m][n][r] + bb, 0.f);
          const float other = __shfl_xor(vv, 1);
          if ((c & 1) == 0) {
            const uint32_t word = (uint32_t)f2bf(vv) | ((uint32_t)f2bf(other) << 16);
            *(uint32_t*)((ushort*)Cout + (size_t)(row0 + r)*NDIM + col) = word;
          }
        }
      } else if (MODE == 4) {   // K,V both head-major
        const int b_ = row0 >> 10, s = row0 & (SEQ - 1);
        const int hd = col & 255;
        const int hh = hd >> 5, d = hd & 31;
        const float bb = (col < 256) ? bias0[hd] : bias1[hd];
        ushort* dst = ((col < 256) ? (ushort*)Cout : vtb)
                    + (((size_t)(b_*NH + hh)*SEQ + s) << 5) + d;
        #pragma unroll
        for (int r = 0; r < 4; ++r) {
          const float vv = acc[m][n][r] + bb;
          const float other = __shfl_xor(vv, 1);
          if ((c & 1) == 0) {
            const uint32_t word = (uint32_t)f2bf(vv) | ((uint32_t)f2bf(other) << 16);
            *(uint32_t*)(dst + (r << 5)) = word;
          }
        }
      } else {  // MODE 3
        const int b_ = row0 >> 10, s = row0 & (SEQ - 1);
        if (col < 512) {
          const int hd = col & 255;
          const int hh = hd >> 5, d = hd & 31;
          const float bb = (col < 256) ? bias0[hd] : bias1[hd];
          ushort* dst = (ushort*)Cout + (col < 256 ? 0 : QKSTRIDE)
                      + (((size_t)(b_*NH + hh)*SEQ + s) << 5) + d;
          #pragma unroll
          for (int r = 0; r < 4; ++r) {
            const float vv = acc[m][n][r] + bb;
            const float other = __shfl_xor(vv, 1);
            if ((c & 1) == 0) {
              const uint32_t word = (uint32_t)f2bf(vv) | ((uint32_t)f2bf(other) << 16);
              *(uint32_t*)(dst + (r << 5)) = word;
            }
          }
        } else {
          // V: permuted k-slot layout. position p = g'*8 + hi*4 + rr <-> key 16*hi+4*g'+rr
          const int hd = col - 512;
          const int hh = hd >> 5, d = hd & 31;
          const float bb = bias2[hd];
          const int sg = s >> 5, a = (s & 31) >> 2;
          const int pbase = (a & 3)*8 + (a >> 2)*4;
          ushort4 w4;
          w4.x = f2bf(acc[m][n][0] + bb);
          w4.y = f2bf(acc[m][n][1] + bb);
          w4.z = f2bf(acc[m][n][2] + bb);
          w4.w = f2bf(acc[m][n][3] + bb);
          *(ushort4*)(vtb + (((size_t)((b_*NH + hh)*32 + sg)*32 + d) << 5) + pbase) = w4;
        }
      }
    }
  }
}

// ---------------- 64x64-tile accumulate GEMM (N=256), counted-vmcnt 3-buffer ----------------
template<int KDIM>
__global__ __launch_bounds__(256) void gemm64_acc(
    const ushort* __restrict__ A, const ushort* __restrict__ Bw,
    const float* __restrict__ bias, float* __restrict__ C)
{
  __shared__ ushort Al[3][64*32];
  __shared__ ushort Bl[3][64*32];
  const int bm = blockIdx.y * 64, bn = blockIdx.x * 64;
  const int tid = threadIdx.x, w = tid >> 6, lane = tid & 63;
  const int wm = w >> 1, wn = w & 1;
  const int g = lane >> 4, c = lane & 15;
  const int lrow = tid >> 2, lc8 = (tid & 3) << 3;
  const f32x4 fzero = {0.f, 0.f, 0.f, 0.f};
  f32x4 acc[2][2];
  acc[0][0] = fzero; acc[0][1] = fzero; acc[1][0] = fzero; acc[1][1] = fzero;

#define STAGE64(buf, k0)                                                       \
  {                                                                            \
    gload_lds16(A  + (size_t)(bm + lrow)*KDIM + (k0) + lc8,                    \
                &Al[buf][lrow*32 + lc8]);                                      \
    gload_lds16(Bw + (size_t)(bn + lrow)*KDIM + (k0) + lc8,                    \
                &Bl[buf][lrow*32 + lc8]);                                      \
  }

#define COMPUTE64(buf)                                                         \
  {                                                                            \
    bf16x8 af[2], bfr[2];                                                      \
    _Pragma("unroll")                                                          \
    for (int m = 0; m < 2; ++m)                                                \
      af[m] = *(const bf16x8*)&Al[buf][(wm*32 + m*16 + c)*32 + g*8];           \
    _Pragma("unroll")                                                          \
    for (int n = 0; n < 2; ++n)                                                \
      bfr[n] = *(const bf16x8*)&Bl[buf][(wn*32 + n*16 + c)*32 + g*8];          \
    _Pragma("unroll")                                                          \
    for (int m = 0; m < 2; ++m)                                                \
      _Pragma("unroll")                                                        \
      for (int n = 0; n < 2; ++n)                                              \
        acc[m][n] = __builtin_amdgcn_mfma_f32_16x16x32_bf16(af[m], bfr[n], acc[m][n], 0, 0, 0); \
  }

  STAGE64(0, 0);
  STAGE64(1, 32);
  STAGE64(2, 64);
  int buf = 0;
  for (int k0 = 0; k0 + 64 < KDIM; k0 += 32) {
    asm volatile("s_waitcnt vmcnt(4)" ::: "memory");
    __builtin_amdgcn_s_barrier();
    COMPUTE64(buf);
    asm volatile("s_waitcnt lgkmcnt(0)" ::: "memory");
    __builtin_amdgcn_s_barrier();
    if (k0 + 96 < KDIM) STAGE64(buf, k0 + 96);
    buf = (buf == 2) ? 0 : buf + 1;
  }
  asm volatile("s_waitcnt vmcnt(2)" ::: "memory");
  __builtin_amdgcn_s_barrier();
  COMPUTE64(buf);
  buf = (buf == 2) ? 0 : buf + 1;
  asm volatile("s_waitcnt vmcnt(0)" ::: "memory");
  __builtin_amdgcn_s_barrier();
  COMPUTE64(buf);
#undef STAGE64
#undef COMPUTE64

  #pragma unroll
  for (int m = 0; m < 2; ++m) {
    const int row0 = bm + wm*32 + m*16 + g*4;
    #pragma unroll
    for (int n = 0; n < 2; ++n) {
      const int col = bn + wn*32 + n*16 + c;
      const float bb = bias[col];
      #pragma unroll
      for (int r = 0; r < 4; ++r)
        C[(size_t)(row0 + r)*DIM + col] += acc[m][n][r] + bb;
    }
  }
}

// ---------------- flash attention (layer 0): 32 q-rows/block, max-free softmax ----------------
__global__ __launch_bounds__(256) void attn_mfma(
    const ushort* __restrict__ qh, const ushort* __restrict__ kh,
    const ushort* __restrict__ vph, const float* __restrict__ bm2l,
    ushort* __restrict__ O)
{
  const int bid = blockIdx.x;
  const int lin = ((bid & 7) << 8) + (bid >> 3);       // bijective (2048 % 8 == 0)
  const int tid = threadIdx.x, w = tid >> 6, lane = tid & 63;
  const int qw = lin & 31, h = (lin >> 5) & 7, b = lin >> 8;
  const int qb = qw << 5;
  const float scale2 = 0.17677669529663687f * 1.4426950408889634f;  // rsqrt(32)*log2e
  const int g = lane >> 4, c = lane & 15;
  const f32x4 fzero = {0.f, 0.f, 0.f, 0.f};
  const size_t bh = (size_t)(b*NH + h);

  const bf16x8 qf0 = *(const bf16x8*)(qh + ((bh*SEQ + qb + c)      << 5) + g*8);
  const bf16x8 qf1 = *(const bf16x8*)(qh + ((bh*SEQ + qb + 16 + c) << 5) + g*8);
  const ushort* kbase = kh  + ((bh*SEQ) << 5) + g*8;
  const ushort* vbase = vph + ((bh*SEQ) << 5) + g*8;
  const float*  bmb   = bm2l + b*SEQ;

  f32x4 oacc[2][2];
  oacc[0][0] = fzero; oacc[0][1] = fzero; oacc[1][0] = fzero; oacc[1][1] = fzero;
  float l0 = 0.f, l1 = 0.f;

  bf16x8 kfA[4], kfB[4];
  bf16x8 vfA[2][2], vfB[2][2];
  f32x4 bbA[4], bbB[4];

#define LOADT(kt, kf, vf, bb)                                                  \
  {                                                                            \
    _Pragma("unroll")                                                          \
    for (int ks = 0; ks < 4; ++ks) {                                           \
      kf[ks] = *(const bf16x8*)(kbase + (((kt) + ks*16 + c) << 5));            \
      bb[ks] = *(const f32x4*)(bmb + (kt) + ks*16 + g*4);                      \
    }                                                                          \
    _Pragma("unroll")                                                          \
    for (int ds_ = 0; ds_ < 2; ++ds_)                                          \
      _Pragma("unroll")                                                        \
      for (int sg = 0; sg < 2; ++sg)                                           \
        vf[ds_][sg] = *(const bf16x8*)(vbase +                                 \
            (((((kt) >> 5) + sg)*32 + ds_*16 + c) << 5));                      \
  }

#define ATILE(kf, vf, bb)                                                      \
  {                                                                            \
    f32x4 sf0[4], sf1[4];                                                      \
    __builtin_amdgcn_s_setprio(1);                                             \
    _Pragma("unroll")                                                          \
    for (int ks = 0; ks < 4; ++ks)                                             \
      sf0[ks] = __builtin_amdgcn_mfma_f32_16x16x32_bf16(kf[ks], qf0, fzero, 0, 0, 0); \
    _Pragma("unroll")                                                          \
    for (int ks = 0; ks < 4; ++ks)                                             \
      sf1[ks] = __builtin_amdgcn_mfma_f32_16x16x32_bf16(kf[ks], qf1, fzero, 0, 0, 0); \
    __builtin_amdgcn_s_setprio(0);                                             \
    float e0[4][4], e1[4][4];                                                  \
    _Pragma("unroll")                                                          \
    for (int ks = 0; ks < 4; ++ks)                                             \
      _Pragma("unroll")                                                        \
      for (int r = 0; r < 4; ++r) {                                            \
        e0[ks][r] = exp2_n(fmaf(sf0[ks][r], scale2, bb[ks][r]));               \
        e1[ks][r] = exp2_n(fmaf(sf1[ks][r], scale2, bb[ks][r]));               \
      }                                                                        \
    float a0 = 0.f, a1 = 0.f, a2 = 0.f, a3 = 0.f;                              \
    _Pragma("unroll")                                                          \
    for (int r = 0; r < 4; ++r) {                                              \
      a0 += e0[0][r] + e0[1][r]; a1 += e0[2][r] + e0[3][r];                    \
      a2 += e1[0][r] + e1[1][r]; a3 += e1[2][r] + e1[3][r];                    \
    }                                                                          \
    l0 += a0 + a1; l1 += a2 + a3;                                              \
    union { bf16x8 v; uint32_t u[4]; } p00, p01, p10, p11;                     \
    p00.u[0] = cvtpk(e0[0][0], e0[0][1]); p00.u[1] = cvtpk(e0[0][2], e0[0][3]);\
    p00.u[2] = cvtpk(e0[1][0], e0[1][1]); p00.u[3] = cvtpk(e0[1][2], e0[1][3]);\
    p01.u[0] = cvtpk(e0[2][0], e0[2][1]); p01.u[1] = cvtpk(e0[2][2], e0[2][3]);\
    p01.u[2] = cvtpk(e0[3][0], e0[3][1]); p01.u[3] = cvtpk(e0[3][2], e0[3][3]);\
    p10.u[0] = cvtpk(e1[0][0], e1[0][1]); p10.u[1] = cvtpk(e1[0][2], e1[0][3]);\
    p10.u[2] = cvtpk(e1[1][0], e1[1][1]); p10.u[3] = cvtpk(e1[1][2], e1[1][3]);\
    p11.u[0] = cvtpk(e1[2][0], e1[2][1]); p11.u[1] = cvtpk(e1[2][2], e1[2][3]);\
    p11.u[2] = cvtpk(e1[3][0], e1[3][1]); p11.u[3] = cvtpk(e1[3][2], e1[3][3]);\
    __builtin_amdgcn_s_setprio(1);                                             \
    oacc[0][0] = __builtin_amdgcn_mfma_f32_16x16x32_bf16(vf[0][0], p00.v, oacc[0][0], 0, 0, 0); \
    oacc[0][1] = __builtin_amdgcn_mfma_f32_16x16x32_bf16(vf[1][0], p00.v, oacc[0][1], 0, 0, 0); \
    oacc[1][0] = __builtin_amdgcn_mfma_f32_16x16x32_bf16(vf[0][0], p10.v, oacc[1][0], 0, 0, 0); \
    oacc[1][1] = __builtin_amdgcn_mfma_f32_16x16x32_bf16(vf[1][0], p10.v, oacc[1][1], 0, 0, 0); \
    oacc[0][0] = __builtin_amdgcn_mfma_f32_16x16x32_bf16(vf[0][1], p01.v, oacc[0][0], 0, 0, 0); \
    oacc[0][1] = __builtin_amdgcn_mfma_f32_16x16x32_bf16(vf[1][1], p01.v, oacc[0][1], 0, 0, 0); \
    oacc[1][0] = __builtin_amdgcn_mfma_f32_16x16x32_bf16(vf[0][1], p11.v, oacc[1][0], 0, 0, 0); \
    oacc[1][1] = __builtin_amdgcn_mfma_f32_16x16x32_bf16(vf[1][1], p11.v, oacc[1][1], 0, 0, 0); \
    __builtin_amdgcn_s_setprio(0);                                             \
  }

  const int kt0 = w << 8;
  LOADT(kt0, kfA, vfA, bbA);
  LOADT(kt0 + 64, kfB, vfB, bbB);
  ATILE(kfA, vfA, bbA);
  LOADT(kt0 + 128, kfA, vfA, bbA);
  ATILE(kfB, vfB, bbB);
  LOADT(kt0 + 192, kfB, vfB, bbB);
  ATILE(kfA, vfA, bbA);
  ATILE(kfB, vfB, bbB);
#undef LOADT
#undef ATILE

  __shared__ float Lo[4][64][19];
  #pragma unroll
  for (int q = 0; q < 2; ++q)
    #pragma unroll
    for (int ds_ = 0; ds_ < 2; ++ds_)
      #pragma unroll
      for (int i = 0; i < 4; ++i)
        Lo[w][lane][q*8 + ds_*4 + i] = oacc[q][ds_][i];
  Lo[w][lane][16] = l0;
  Lo[w][lane][17] = l1;
  __syncthreads();
  if (w < 2) {
    const int q = w;
    float o[8] = {0.f,0.f,0.f,0.f,0.f,0.f,0.f,0.f};
    float ls = 0.f;
    #pragma unroll
    for (int ww = 0; ww < 4; ++ww) {
      ls += Lo[ww][lane][16 + q];
      #pragma unroll
      for (int i = 0; i < 8; ++i) o[i] += Lo[ww][lane][q*8 + i];
    }
    ls += __shfl_xor(ls, 16);
    ls += __shfl_xor(ls, 32);
    const float inv = 1.f / ls;
    ushort* orow = O + (size_t)(b*SEQ + qb + q*16 + c)*DIM + h*32 + g*4;
    const uint32_t w0 = (uint32_t)f2bf(o[0]*inv) | ((uint32_t)f2bf(o[1]*inv) << 16);
    const uint32_t w1 = (uint32_t)f2bf(o[2]*inv) | ((uint32_t)f2bf(o[3]*inv) << 16);
    const uint32_t w2 = (uint32_t)f2bf(o[4]*inv) | ((uint32_t)f2bf(o[5]*inv) << 16);
    const uint32_t w3 = (uint32_t)f2bf(o[6]*inv) | ((uint32_t)f2bf(o[7]*inv) << 16);
    *(uint32_t*)(orow)      = w0;
    *(uint32_t*)(orow + 2)  = w1;
    *(uint32_t*)(orow + 16) = w2;
    *(uint32_t*)(orow + 18) = w3;
  }
}

// ---------------- layer-2 tail: decode attention with inline Q GEMV ----------------
// grid 64 = (b,h); K,V head-major; max-free base-2 softmax; f32 throughout.
__global__ __launch_bounds__(256) void attn_decode(
    const ushort* __restrict__ x2b, const ushort* __restrict__ Wq1,
    const float* __restrict__ bq1, const ushort* __restrict__ kh,
    const ushort* __restrict__ vh, const float* __restrict__ bm2l,
    float* __restrict__ obuf)
{
  const int b = blockIdx.x >> 3, h = blockIdx.x & 7;
  const int tid = threadIdx.x;
  const float scale2 = 0.17677669529663687f * 1.4426950408889634f;
  __shared__ float xrow[256];
  __shared__ float qv[32];
  xrow[tid] = bf2f(x2b[(size_t)(b*SEQ)*DIM + tid]);
  __syncthreads();
  if (tid < 32) {
    const ushort* wrow = Wq1 + (size_t)(h*32 + tid)*DIM;
    float acc = bq1[h*32 + tid];
    #pragma unroll
    for (int k8 = 0; k8 < 32; ++k8) {
      const bf16x8 wv = *(const bf16x8*)(wrow + k8*8);
      #pragma unroll
      for (int j = 0; j < 8; ++j)
        acc = fmaf(bf2f((ushort)wv[j]), xrow[k8*8 + j], acc);
    }
    qv[tid] = acc;
  }
  __syncthreads();
  const ushort* kb = kh + (((size_t)(b*NH + h))*SEQ << 5);
  const ushort* vb = vh + (((size_t)(b*NH + h))*SEQ << 5);
  const float* bias = bm2l + b*SEQ;
  float o[32];
  #pragma unroll
  for (int d = 0; d < 32; ++d) o[d] = 0.f;
  float lsum = 0.f;
  #pragma unroll
  for (int kk = 0; kk < 4; ++kk) {
    const int key = kk*256 + tid;
    const ushort* kr = kb + (key << 5);
    float dot = 0.f;
    #pragma unroll
    for (int i = 0; i < 4; ++i) {
      const bf16x8 kv8 = *(const bf16x8*)(kr + i*8);
      #pragma unroll
      for (int j = 0; j < 8; ++j)
        dot = fmaf(bf2f((ushort)kv8[j]), qv[i*8 + j], dot);
    }
    const float e = exp2_n(fmaf(dot, scale2, bias[key]));
    lsum += e;
    const ushort* vr = vb + (key << 5);
    #pragma unroll
    for (int i = 0; i < 4; ++i) {
      const bf16x8 vv8 = *(const bf16x8*)(vr + i*8);
      #pragma unroll
      for (int j = 0; j < 8; ++j)
        o[i*8 + j] = fmaf(e, bf2f((ushort)vv8[j]), o[i*8 + j]);
    }
  }
  __shared__ float red[256][33];
  #pragma unroll
  for (int d = 0; d < 32; ++d) red[tid][d] = o[d];
  red[tid][32] = lsum;
  __syncthreads();
  __shared__ float fin[33];
  if (tid < 33) {
    float s = 0.f;
    for (int t = 0; t < 256; ++t) s += red[t][tid];
    fin[tid] = s;
  }
  __syncthreads();
  if (tid < 32)
    obuf[b*DIM + h*32 + tid] = fin[tid] / fin[32];
}

// ---------------- layer-2 fused tail: Wo+res+LN2 + FF1 + FF2+res + final LN + classifier ----------------
// grid 8 (one block per batch), 256 threads. All f32; weights bf16.
__global__ __launch_bounds__(256) void tail_fused(
    const float* __restrict__ obuf, const ushort* __restrict__ WoT1,
    const float* __restrict__ bo1, const float* __restrict__ g21,
    const float* __restrict__ be21,
    const ushort* __restrict__ W1T1, const float* __restrict__ b11,
    const ushort* __restrict__ W2T1, const float* __restrict__ b21,
    const float* __restrict__ x, const float* __restrict__ gf,
    const float* __restrict__ bfb, const float* __restrict__ Wc,
    const float* __restrict__ bc, float* __restrict__ out)
{
  const int b = blockIdx.x, tid = threadIdx.x;
  const int wave = tid >> 6, lane = tid & 63;
  __shared__ float orow[256];
  __shared__ float t2row[256];
  __shared__ float mid[1024];
  __shared__ float red[2][4];
  __shared__ float redc[4][4];
  orow[tid] = obuf[b*DIM + tid];
  __syncthreads();
  // Wo GEMV + residual
  {
    const ushort* wrow = WoT1 + (size_t)tid*DIM;
    float acc = bo1[tid];
    #pragma unroll
    for (int k8 = 0; k8 < 32; ++k8) {
      const bf16x8 wv = *(const bf16x8*)(wrow + k8*8);
      #pragma unroll
      for (int j = 0; j < 8; ++j)
        acc = fmaf(bf2f((ushort)wv[j]), orow[k8*8 + j], acc);
    }
    const float newx = x[(size_t)(b*SEQ)*DIM + tid] + acc;
    // LN2
    float sm = newx;
    #pragma unroll
    for (int o = 32; o >= 1; o >>= 1) sm += __shfl_xor(sm, o);
    if (lane == 0) red[0][wave] = sm;
    __syncthreads();
    const float mean = (red[0][0]+red[0][1]+red[0][2]+red[0][3]) * (1.f/256.f);
    const float dv = newx - mean;
    float q = dv * dv;
    #pragma unroll
    for (int o = 32; o >= 1; o >>= 1) q += __shfl_xor(q, o);
    if (lane == 0) red[1][wave] = q;
    __syncthreads();
    const float var = (red[1][0]+red[1][1]+red[1][2]+red[1][3]) * (1.f/256.f);
    const float rs = rsqrtf(var + 1e-5f);
    t2row[tid] = dv*rs*g21[tid] + be21[tid];
    orow[tid] = newx;           // keep newx for the final residual
  }
  __syncthreads();
  // FF1: 4 cols per thread
  #pragma unroll
  for (int cc = 0; cc < 4; ++cc) {
    const int col = cc*256 + tid;
    const ushort* wrow = W1T1 + (size_t)col*DIM;
    float acc = b11[col];
    #pragma unroll
    for (int k8 = 0; k8 < 32; ++k8) {
      const bf16x8 wv = *(const bf16x8*)(wrow + k8*8);
      #pragma unroll
      for (int j = 0; j < 8; ++j)
        acc = fmaf(bf2f((ushort)wv[j]), t2row[k8*8 + j], acc);
    }
    mid[col] = fmaxf(acc, 0.f);
  }
  __syncthreads();
  // FF2 + residual
  float x2;
  {
    const ushort* wrow = W2T1 + (size_t)tid*FFD;
    float acc = b21[tid];
    #pragma unroll
    for (int k8 = 0; k8 < 128; ++k8) {
      const bf16x8 wv = *(const bf16x8*)(wrow + k8*8);
      #pragma unroll
      for (int j = 0; j < 8; ++j)
        acc = fmaf(bf2f((ushort)wv[j]), mid[k8*8 + j], acc);
    }
    x2 = orow[tid] + acc;
  }
  __syncthreads();
  // final LN
  float sm = x2;
  #pragma unroll
  for (int o = 32; o >= 1; o >>= 1) sm += __shfl_xor(sm, o);
  if (lane == 0) red[0][wave] = sm;
  __syncthreads();
  const float mean = (red[0][0]+red[0][1]+red[0][2]+red[0][3]) * (1.f/256.f);
  const float dv = x2 - mean;
  float q = dv * dv;
  #pragma unroll
  for (int o = 32; o >= 1; o >>= 1) q += __shfl_xor(q, o);
  if (lane == 0) red[1][wave] = q;
  __syncthreads();
  const float var = (red[1][0]+red[1][1]+red[1][2]+red[1][3]) * (1.f/256.f);
  const float rs = rsqrtf(var + 1e-5f);
  const float yn = dv*rs*gf[tid] + bfb[tid];
  // classifier
  float pc[4];
  #pragma unroll
  for (int cc = 0; cc < 4; ++cc) pc[cc] = yn * Wc[tid*4 + cc];
  #pragma unroll
  for (int cc = 0; cc < 4; ++cc) {
    #pragma unroll
    for (int o = 32; o >= 1; o >>= 1) pc[cc] += __shfl_xor(pc[cc], o);
  }
  if (lane == 0) {
    #pragma unroll
    for (int cc = 0; cc < 4; ++cc) redc[wave][cc] = pc[cc];
  }
  __syncthreads();
  if (tid < 4)
    out[b*4 + tid] = redc[0][tid] + redc[1][tid] + redc[2][tid] + redc[3][tid] + bc[tid];
}

extern "C" void kernel_launch(void* const* d_in, const int* in_sizes, int n_in,
                              void* d_out, int out_size, void* d_ws, size_t ws_size,
                              hipStream_t stream)
{
  const int*   ids    = (const int*)d_in[0];
  const int*   ngrams = (const int*)d_in[1];
  const float* tfidf  = (const float*)d_in[2];
  const float* emb    = (const float*)d_in[3];
  const float* pos    = (const float*)d_in[4];
  const float* bucket = (const float*)d_in[5];
  const float* Wq = (const float*)d_in[6];  const float* bq = (const float*)d_in[7];
  const float* Wk = (const float*)d_in[8];  const float* bk = (const float*)d_in[9];
  const float* Wv = (const float*)d_in[10]; const float* bv = (const float*)d_in[11];
  const float* Wo = (const float*)d_in[12]; const float* bo = (const float*)d_in[13];
  const float* g1 = (const float*)d_in[14]; const float* be1= (const float*)d_in[15];
  const float* g2 = (const float*)d_in[16]; const float* be2= (const float*)d_in[17];
  const float* W1 = (const float*)d_in[18]; const float* b1 = (const float*)d_in[19];
  const float* W2 = (const float*)d_in[20]; const float* b2 = (const float*)d_in[21];
  const float* alpha = (const float*)d_in[22];
  const float* gf = (const float*)d_in[23]; const float* bf = (const float*)d_in[24];
  const float* Wc = (const float*)d_in[25]; const float* bc = (const float*)d_in[26];

  uint8_t* base = (uint8_t*)d_ws;
  float*  x      = (float*)  base;                  //  8,388,608
  ushort* x2b    = (ushort*)(base + 8388608);       //  4,194,304
  ushort* qkh    = (ushort*)(base + 12582912);      //  8,388,608 (Q head-major, K at +QKSTRIDE)
  ushort* vtb    = (ushort*)(base + 20971520);      //  4,194,304 (V permuted l0 / V head-major l1)
  ushort* attb   = (ushort*)(base + 25165824);      //  4,194,304 (l0 attn out; l1 tail scratch)
  ushort* midb   = (ushort*)(base + 29360128);      // 16,777,216
  float*  bm2    = (float*) (base + 46137344);      //     65,536 (2 layers)
  ushort* WqkvT  = (ushort*)(base + 46202880);      //    786,432
  ushort* WoT    = (ushort*)(base + 46989312);      //    262,144
  ushort* W1T    = (ushort*)(base + 47251456);      //  1,048,576
  ushort* W2T    = (ushort*)(base + 48300032);      //  1,048,576  -> 49,348,608 total

  // layer-2 tail scratch carved from attb space (dead in layer-1 tail path)
  float*  obuf = (float*)(base + 25165824 + 8192);  // 8*256 f32

  TDescs td;
  for (int l = 0; l < NL; ++l) {
    td.d[6*l+0] = { Wq + (size_t)l*DIM*DIM, WqkvT + (size_t)l*768*DIM +   0*DIM, DIM, DIM };
    td.d[6*l+1] = { Wk + (size_t)l*DIM*DIM, WqkvT + (size_t)l*768*DIM + 256*DIM, DIM, DIM };
    td.d[6*l+2] = { Wv + (size_t)l*DIM*DIM, WqkvT + (size_t)l*768*DIM + 512*DIM, DIM, DIM };
    td.d[6*l+3] = { Wo + (size_t)l*DIM*DIM, WoT  + (size_t)l*DIM*DIM,  DIM, DIM };
    td.d[6*l+4] = { W1 + (size_t)l*DIM*FFD, W1T  + (size_t)l*FFD*DIM,  DIM, FFD };
    td.d[6*l+5] = { W2 + (size_t)l*FFD*DIM, W2T  + (size_t)l*DIM*FFD,  FFD, DIM };
  }
  transpose_conv<<<dim3(32, 32, 12), 256, 0, stream>>>(td);

  embed_ln_kernel<<<TOK, 256, 0, stream>>>(
      ids, ngrams, tfidf, emb, pos, bucket, alpha, g1, be1, x, x2b, bm2);

  const dim3 gqkv(6, TOK/64), gkv(4, TOK/64), gff1(8, TOK/64), g64(4, TOK/64);

  // ---------- layer 0: full pipeline ----------
  gemm_mfma<256, 768, 3><<<gqkv, 256, 0, stream>>>(
      x2b, WqkvT, bq, bk, bv, qkh, vtb);
  attn_mfma<<<2048, 256, 0, stream>>>(qkh, qkh + QKSTRIDE, vtb, bm2, attb);
  gemm64_acc<256><<<g64, 256, 0, stream>>>(attb, WoT, bo, x);
  ln_bf16<<<TOK/4, 256, 0, stream>>>(x, g2, be2, x2b);
  gemm_mfma<256, 1024, 1><<<gff1, 256, 0, stream>>>(
      x2b, W1T, b1, nullptr, nullptr, midb, nullptr);
  gemm64_acc<1024><<<g64, 256, 0, stream>>>(midb, W2T, b2, x);

  // ---------- layer 1: only row 0 per batch feeds the output ----------
  ln_bf16<<<TOK/4, 256, 0, stream>>>(x, g1 + DIM, be1 + DIM, x2b);
  gemm_mfma<256, 512, 4><<<gkv, 256, 0, stream>>>(
      x2b, WqkvT + (size_t)768*DIM + 256*DIM, bk + DIM, bv + DIM, nullptr,
      qkh + QKSTRIDE, vtb);
  attn_decode<<<64, 256, 0, stream>>>(
      x2b, WqkvT + (size_t)768*DIM, bq + DIM,
      qkh + QKSTRIDE, vtb, bm2 + TOK, obuf);
  tail_fused<<<8, 256, 0, stream>>>(
      obuf, WoT + DIM*DIM, bo + DIM, g2 + DIM, be2 + DIM,
      W1T + FFD*DIM, b1 + FFD, W2T + DIM*FFD, b2 + DIM,
      x, gf, bf, Wc, bc, (float*)d_out);
}

// Round 14
// 150.448 us; speedup vs baseline: 1.2574x; 1.2574x over previous
//
#include <hip/hip_runtime.h>
#include <hip/hip_bf16.h>
#include <math.h>

#define TOK 8192       // B*S
#define DIM 256
#define SEQ 1024
#define NH 8
#define FFD 1024
#define NL 2
#define VOCAB 32000
#define QKSTRIDE 2097152   // elems between Q and K head-major blocks

typedef short bf16x8 __attribute__((ext_vector_type(8)));
typedef float f32x4 __attribute__((ext_vector_type(4)));

__device__ __forceinline__ ushort f2bf(float f) {
  union { float f; uint32_t u; } v; v.f = f;
  uint32_t r = v.u + 0x7FFFu + ((v.u >> 16) & 1u);
  return (ushort)(r >> 16);
}

__device__ __forceinline__ float bf2f(ushort u) {
  union { uint32_t u; float f; } v; v.u = (uint32_t)u << 16; return v.f;
}

__device__ __forceinline__ float exp2_n(float x) {
  float r; asm("v_exp_f32 %0, %1" : "=v"(r) : "v"(x)); return r;
}

__device__ __forceinline__ uint32_t cvtpk(float lo, float hi) {
  uint32_t r; asm("v_cvt_pk_bf16_f32 %0, %1, %2" : "=v"(r) : "v"(lo), "v"(hi));
  return r;
}

__device__ __forceinline__ void gload_lds16(const ushort* gp, ushort* lp) {
  __builtin_amdgcn_global_load_lds(
      (const __attribute__((address_space(1))) void*)gp,
      (__attribute__((address_space(3))) void*)lp, 16, 0, 0);
}

// ---------------- embedding + ngram + tfidf bias + fused layer-0 LN ----------------
__global__ __launch_bounds__(256) void embed_ln_kernel(
    const int* __restrict__ ids, const int* __restrict__ ngram_ids,
    const float* __restrict__ tfidf, const float* __restrict__ emb,
    const float* __restrict__ pos, const float* __restrict__ bucket,
    const float* __restrict__ alpha, const float* __restrict__ g1,
    const float* __restrict__ be1,
    float* __restrict__ x, ushort* __restrict__ x2b, float* __restrict__ bm2)
{
  __shared__ int ngs[12];
  __shared__ float red[2][4];
  const int t = blockIdx.x;
  const int id = ids[t];
  int idc = id; if (idc < 0) idc = 0; if (idc > VOCAB-1) idc = VOCAB-1;
  if (threadIdx.x < 12) ngs[threadIdx.x] = ngram_ids[idc*12 + threadIdx.x];
  if (threadIdx.x == 0) {
    const float tf = tfidf[idc];
    const bool msk = (id == 0);
    const float l2e = 1.4426950408889634f;
    bm2[t]       = msk ? -1e30f : tf * alpha[0] * l2e;
    bm2[TOK + t] = msk ? -1e30f : tf * alpha[1] * l2e;
  }
  __syncthreads();
  const int d = threadIdx.x;
  const int s = t & (SEQ - 1);
  float v = emb[(size_t)id*DIM + d] + pos[s*DIM + d];
  float sum = 0.f; int cnt = 0;
  #pragma unroll
  for (int g = 0; g < 12; ++g) {
    const int ng = ngs[g];
    if (ng != 0) { sum += bucket[(size_t)ng*DIM + d]; cnt++; }
  }
  v += sum / fmaxf((float)cnt, 1.0f);
  x[(size_t)t*DIM + d] = v;
  // fused LN (layer 0, ln1)
  const int wave = d >> 6, lane = d & 63;
  float sm = v;
  #pragma unroll
  for (int o = 32; o >= 1; o >>= 1) sm += __shfl_xor(sm, o);
  if (lane == 0) red[0][wave] = sm;
  __syncthreads();
  const float mean = (red[0][0]+red[0][1]+red[0][2]+red[0][3]) * (1.f/256.f);
  const float dv = v - mean;
  float q = dv * dv;
  #pragma unroll
  for (int o = 32; o >= 1; o >>= 1) q += __shfl_xor(q, o);
  if (lane == 0) red[1][wave] = q;
  __syncthreads();
  const float var = (red[1][0]+red[1][1]+red[1][2]+red[1][3]) * (1.f/256.f);
  const float rs = rsqrtf(var + 1e-5f);
  x2b[(size_t)t*DIM + d] = f2bf(dv*rs*g1[d] + be1[d]);
}

// ---------------- layernorm -> bf16 ----------------
__global__ __launch_bounds__(256) void ln_bf16(
    const float* __restrict__ x, const float* __restrict__ g,
    const float* __restrict__ b, ushort* __restrict__ y)
{
  const int wave = threadIdx.x >> 6, lane = threadIdx.x & 63;
  const int row = blockIdx.x * 4 + wave;
  const float* xr = x + (size_t)row * DIM;
  float4 v = *reinterpret_cast<const float4*>(xr + lane*4);
  float s = v.x + v.y + v.z + v.w;
  #pragma unroll
  for (int o = 32; o >= 1; o >>= 1) s += __shfl_xor(s, o);
  const float mean = s * (1.f/256.f);
  const float dx0 = v.x-mean, dx1 = v.y-mean, dx2 = v.z-mean, dx3 = v.w-mean;
  float q = dx0*dx0 + dx1*dx1 + dx2*dx2 + dx3*dx3;
  #pragma unroll
  for (int o = 32; o >= 1; o >>= 1) q += __shfl_xor(q, o);
  const float rs = rsqrtf(q * (1.f/256.f) + 1e-5f);
  float4 gv = *reinterpret_cast<const float4*>(g + lane*4);
  float4 bv = *reinterpret_cast<const float4*>(b + lane*4);
  ushort4 o4;
  o4.x = f2bf(dx0*rs*gv.x + bv.x);
  o4.y = f2bf(dx1*rs*gv.y + bv.y);
  o4.z = f2bf(dx2*rs*gv.z + bv.z);
  o4.w = f2bf(dx3*rs*gv.w + bv.w);
  *reinterpret_cast<ushort4*>(y + (size_t)row*DIM + lane*4) = o4;
}

// ---------------- weight transpose + bf16: f32 [K][N] -> bf16 [N][K] ----------------
struct TDesc { const float* src; ushort* dst; int K; int N; };
struct TDescs { TDesc d[12]; };

__global__ __launch_bounds__(256) void transpose_conv(TDescs descs)
{
  const TDesc t = descs.d[blockIdx.z];
  const int k0 = blockIdx.x * 32, n0 = blockIdx.y * 32;
  if (k0 >= t.K || n0 >= t.N) return;
  __shared__ float tile[32][33];
  const int r = threadIdx.x >> 5, cc = threadIdx.x & 31;
  #pragma unroll
  for (int i = 0; i < 4; ++i)
    tile[r + i*8][cc] = t.src[(size_t)(k0 + r + i*8)*t.N + n0 + cc];
  __syncthreads();
  #pragma unroll
  for (int i = 0; i < 4; ++i)
    t.dst[(size_t)(n0 + r + i*8)*t.K + k0 + cc] = f2bf(tile[cc][r + i*8]);
}

// ---------------- bf16 MFMA GEMM, counted-vmcnt 3-buffer pipeline ----------------
// MODE 1: relu + bf16 out; MODE 3: qkv -> Q,K head-major + V permuted;
// MODE 4: K,V BOTH head-major.
template<int KDIM, int NDIM, int MODE>
__global__ __launch_bounds__(256) void gemm_mfma(
    const ushort* __restrict__ A, const ushort* __restrict__ Bw,
    const float* __restrict__ bias0, const float* __restrict__ bias1,
    const float* __restrict__ bias2, void* __restrict__ Cout,
    ushort* __restrict__ vtb)
{
  __shared__ ushort Al[3][64*32];
  __shared__ ushort Bl[3][128*32];
  const int bm = blockIdx.y * 64, bn = blockIdx.x * 128;
  const int tid = threadIdx.x, w = tid >> 6, lane = tid & 63;
  const int g = lane >> 4, c = lane & 15;
  const int lrow = lane >> 2, lc8 = (lane & 3) << 3;
  const f32x4 fzero = {0.f, 0.f, 0.f, 0.f};
  f32x4 acc[4][2];
  #pragma unroll
  for (int m = 0; m < 4; ++m) { acc[m][0] = fzero; acc[m][1] = fzero; }

#define STAGE(buf, k0)                                                         \
  {                                                                            \
    _Pragma("unroll")                                                          \
    for (int ch = w; ch < 12; ch += 4) {                                       \
      if (ch < 4)                                                              \
        gload_lds16(A + (size_t)(bm + ch*16 + lrow)*KDIM + (k0) + lc8,         \
                    &Al[buf][ch*512]);                                         \
      else                                                                     \
        gload_lds16(Bw + (size_t)(bn + (ch-4)*16 + lrow)*KDIM + (k0) + lc8,    \
                    &Bl[buf][(ch-4)*512]);                                     \
    }                                                                          \
  }

#define COMPUTE(buf)                                                           \
  {                                                                            \
    bf16x8 af[4], bfr[2];                                                      \
    _Pragma("unroll")                                                          \
    for (int m = 0; m < 4; ++m)                                                \
      af[m] = *(const bf16x8*)&Al[buf][(m*16 + c)*32 + g*8];                   \
    _Pragma("unroll")                                                          \
    for (int n = 0; n < 2; ++n)                                                \
      bfr[n] = *(const bf16x8*)&Bl[buf][(w*32 + n*16 + c)*32 + g*8];           \
    _Pragma("unroll")                                                          \
    for (int m = 0; m < 4; ++m)                                                \
      _Pragma("unroll")                                                        \
      for (int n = 0; n < 2; ++n)                                              \
        acc[m][n] = __builtin_amdgcn_mfma_f32_16x16x32_bf16(af[m], bfr[n], acc[m][n], 0, 0, 0); \
  }

  STAGE(0, 0);
  STAGE(1, 32);
  STAGE(2, 64);
  int buf = 0;
  for (int k0 = 0; k0 + 64 < KDIM; k0 += 32) {
    asm volatile("s_waitcnt vmcnt(6)" ::: "memory");
    __builtin_amdgcn_s_barrier();
    COMPUTE(buf);
    asm volatile("s_waitcnt lgkmcnt(0)" ::: "memory");
    __builtin_amdgcn_s_barrier();
    if (k0 + 96 < KDIM) STAGE(buf, k0 + 96);
    buf = (buf == 2) ? 0 : buf + 1;
  }
  asm volatile("s_waitcnt vmcnt(3)" ::: "memory");
  __builtin_amdgcn_s_barrier();
  COMPUTE(buf);
  buf = (buf == 2) ? 0 : buf + 1;
  asm volatile("s_waitcnt vmcnt(0)" ::: "memory");
  __builtin_amdgcn_s_barrier();
  COMPUTE(buf);
#undef STAGE
#undef COMPUTE

  #pragma unroll
  for (int m = 0; m < 4; ++m) {
    const int row0 = bm + m*16 + g*4;
    #pragma unroll
    for (int n = 0; n < 2; ++n) {
      const int col = bn + w*32 + n*16 + c;
      if (MODE == 1) {
        const float bb = bias0[col];
        #pragma unroll
        for (int r = 0; r < 4; ++r) {
          const float vv = fmaxf(acc[m][n][r] + bb, 0.f);
          const float other = __shfl_xor(vv, 1);
          if ((c & 1) == 0) {
            const uint32_t word = (uint32_t)f2bf(vv) | ((uint32_t)f2bf(other) << 16);
            *(uint32_t*)((ushort*)Cout + (size_t)(row0 + r)*NDIM + col) = word;
          }
        }
      } else if (MODE == 4) {   // K,V both head-major
        const int b_ = row0 >> 10, s = row0 & (SEQ - 1);
        const int hd = col & 255;
        const int hh = hd >> 5, d = hd & 31;
        const float bb = (col < 256) ? bias0[hd] : bias1[hd];
        ushort* dst = ((col < 256) ? (ushort*)Cout : vtb)
                    + (((size_t)(b_*NH + hh)*SEQ + s) << 5) + d;
        #pragma unroll
        for (int r = 0; r < 4; ++r) {
          const float vv = acc[m][n][r] + bb;
          const float other = __shfl_xor(vv, 1);
          if ((c & 1) == 0) {
            const uint32_t word = (uint32_t)f2bf(vv) | ((uint32_t)f2bf(other) << 16);
            *(uint32_t*)(dst + (r << 5)) = word;
          }
        }
      } else {  // MODE 3
        const int b_ = row0 >> 10, s = row0 & (SEQ - 1);
        if (col < 512) {
          const int hd = col & 255;
          const int hh = hd >> 5, d = hd & 31;
          const float bb = (col < 256) ? bias0[hd] : bias1[hd];
          ushort* dst = (ushort*)Cout + (col < 256 ? 0 : QKSTRIDE)
                      + (((size_t)(b_*NH + hh)*SEQ + s) << 5) + d;
          #pragma unroll
          for (int r = 0; r < 4; ++r) {
            const float vv = acc[m][n][r] + bb;
            const float other = __shfl_xor(vv, 1);
            if ((c & 1) == 0) {
              const uint32_t word = (uint32_t)f2bf(vv) | ((uint32_t)f2bf(other) << 16);
              *(uint32_t*)(dst + (r << 5)) = word;
            }
          }
        } else {
          const int hd = col - 512;
          const int hh = hd >> 5, d = hd & 31;
          const float bb = bias2[hd];
          const int sg = s >> 5, a = (s & 31) >> 2;
          const int pbase = (a & 3)*8 + (a >> 2)*4;
          ushort4 w4;
          w4.x = f2bf(acc[m][n][0] + bb);
          w4.y = f2bf(acc[m][n][1] + bb);
          w4.z = f2bf(acc[m][n][2] + bb);
          w4.w = f2bf(acc[m][n][3] + bb);
          *(ushort4*)(vtb + (((size_t)((b_*NH + hh)*32 + sg)*32 + d) << 5) + pbase) = w4;
        }
      }
    }
  }
}

// ---------------- 64x64-tile accumulate GEMM (N=256), counted-vmcnt 3-buffer ----------------
template<int KDIM>
__global__ __launch_bounds__(256) void gemm64_acc(
    const ushort* __restrict__ A, const ushort* __restrict__ Bw,
    const float* __restrict__ bias, float* __restrict__ C)
{
  __shared__ ushort Al[3][64*32];
  __shared__ ushort Bl[3][64*32];
  const int bm = blockIdx.y * 64, bn = blockIdx.x * 64;
  const int tid = threadIdx.x, w = tid >> 6, lane = tid & 63;
  const int wm = w >> 1, wn = w & 1;
  const int g = lane >> 4, c = lane & 15;
  const int lrow = tid >> 2, lc8 = (tid & 3) << 3;
  const f32x4 fzero = {0.f, 0.f, 0.f, 0.f};
  f32x4 acc[2][2];
  acc[0][0] = fzero; acc[0][1] = fzero; acc[1][0] = fzero; acc[1][1] = fzero;

#define STAGE64(buf, k0)                                                       \
  {                                                                            \
    gload_lds16(A  + (size_t)(bm + lrow)*KDIM + (k0) + lc8,                    \
                &Al[buf][lrow*32 + lc8]);                                      \
    gload_lds16(Bw + (size_t)(bn + lrow)*KDIM + (k0) + lc8,                    \
                &Bl[buf][lrow*32 + lc8]);                                      \
  }

#define COMPUTE64(buf)                                                         \
  {                                                                            \
    bf16x8 af[2], bfr[2];                                                      \
    _Pragma("unroll")                                                          \
    for (int m = 0; m < 2; ++m)                                                \
      af[m] = *(const bf16x8*)&Al[buf][(wm*32 + m*16 + c)*32 + g*8];           \
    _Pragma("unroll")                                                          \
    for (int n = 0; n < 2; ++n)                                                \
      bfr[n] = *(const bf16x8*)&Bl[buf][(wn*32 + n*16 + c)*32 + g*8];          \
    _Pragma("unroll")                                                          \
    for (int m = 0; m < 2; ++m)                                                \
      _Pragma("unroll")                                                        \
      for (int n = 0; n < 2; ++n)                                              \
        acc[m][n] = __builtin_amdgcn_mfma_f32_16x16x32_bf16(af[m], bfr[n], acc[m][n], 0, 0, 0); \
  }

  STAGE64(0, 0);
  STAGE64(1, 32);
  STAGE64(2, 64);
  int buf = 0;
  for (int k0 = 0; k0 + 64 < KDIM; k0 += 32) {
    asm volatile("s_waitcnt vmcnt(4)" ::: "memory");
    __builtin_amdgcn_s_barrier();
    COMPUTE64(buf);
    asm volatile("s_waitcnt lgkmcnt(0)" ::: "memory");
    __builtin_amdgcn_s_barrier();
    if (k0 + 96 < KDIM) STAGE64(buf, k0 + 96);
    buf = (buf == 2) ? 0 : buf + 1;
  }
  asm volatile("s_waitcnt vmcnt(2)" ::: "memory");
  __builtin_amdgcn_s_barrier();
  COMPUTE64(buf);
  buf = (buf == 2) ? 0 : buf + 1;
  asm volatile("s_waitcnt vmcnt(0)" ::: "memory");
  __builtin_amdgcn_s_barrier();
  COMPUTE64(buf);
#undef STAGE64
#undef COMPUTE64

  #pragma unroll
  for (int m = 0; m < 2; ++m) {
    const int row0 = bm + wm*32 + m*16 + g*4;
    #pragma unroll
    for (int n = 0; n < 2; ++n) {
      const int col = bn + wn*32 + n*16 + c;
      const float bb = bias[col];
      #pragma unroll
      for (int r = 0; r < 4; ++r)
        C[(size_t)(row0 + r)*DIM + col] += acc[m][n][r] + bb;
    }
  }
}

// ---------------- flash attention (layer 0): 32 q-rows/block, max-free softmax ----------------
__global__ __launch_bounds__(256) void attn_mfma(
    const ushort* __restrict__ qh, const ushort* __restrict__ kh,
    const ushort* __restrict__ vph, const float* __restrict__ bm2l,
    ushort* __restrict__ O)
{
  const int bid = blockIdx.x;
  const int lin = ((bid & 7) << 8) + (bid >> 3);       // bijective (2048 % 8 == 0)
  const int tid = threadIdx.x, w = tid >> 6, lane = tid & 63;
  const int qw = lin & 31, h = (lin >> 5) & 7, b = lin >> 8;
  const int qb = qw << 5;
  const float scale2 = 0.17677669529663687f * 1.4426950408889634f;  // rsqrt(32)*log2e
  const int g = lane >> 4, c = lane & 15;
  const f32x4 fzero = {0.f, 0.f, 0.f, 0.f};
  const size_t bh = (size_t)(b*NH + h);

  const bf16x8 qf0 = *(const bf16x8*)(qh + ((bh*SEQ + qb + c)      << 5) + g*8);
  const bf16x8 qf1 = *(const bf16x8*)(qh + ((bh*SEQ + qb + 16 + c) << 5) + g*8);
  const ushort* kbase = kh  + ((bh*SEQ) << 5) + g*8;
  const ushort* vbase = vph + ((bh*SEQ) << 5) + g*8;
  const float*  bmb   = bm2l + b*SEQ;

  f32x4 oacc[2][2];
  oacc[0][0] = fzero; oacc[0][1] = fzero; oacc[1][0] = fzero; oacc[1][1] = fzero;
  float l0 = 0.f, l1 = 0.f;

  bf16x8 kfA[4], kfB[4];
  bf16x8 vfA[2][2], vfB[2][2];
  f32x4 bbA[4], bbB[4];

#define LOADT(kt, kf, vf, bb)                                                  \
  {                                                                            \
    _Pragma("unroll")                                                          \
    for (int ks = 0; ks < 4; ++ks) {                                           \
      kf[ks] = *(const bf16x8*)(kbase + (((kt) + ks*16 + c) << 5));            \
      bb[ks] = *(const f32x4*)(bmb + (kt) + ks*16 + g*4);                      \
    }                                                                          \
    _Pragma("unroll")                                                          \
    for (int ds_ = 0; ds_ < 2; ++ds_)                                          \
      _Pragma("unroll")                                                        \
      for (int sg = 0; sg < 2; ++sg)                                           \
        vf[ds_][sg] = *(const bf16x8*)(vbase +                                 \
            (((((kt) >> 5) + sg)*32 + ds_*16 + c) << 5));                      \
  }

#define ATILE(kf, vf, bb)                                                      \
  {                                                                            \
    f32x4 sf0[4], sf1[4];                                                      \
    __builtin_amdgcn_s_setprio(1);                                             \
    _Pragma("unroll")                                                          \
    for (int ks = 0; ks < 4; ++ks)                                             \
      sf0[ks] = __builtin_amdgcn_mfma_f32_16x16x32_bf16(kf[ks], qf0, fzero, 0, 0, 0); \
    _Pragma("unroll")                                                          \
    for (int ks = 0; ks < 4; ++ks)                                             \
      sf1[ks] = __builtin_amdgcn_mfma_f32_16x16x32_bf16(kf[ks], qf1, fzero, 0, 0, 0); \
    __builtin_amdgcn_s_setprio(0);                                             \
    float e0[4][4], e1[4][4];                                                  \
    _Pragma("unroll")                                                          \
    for (int ks = 0; ks < 4; ++ks)                                             \
      _Pragma("unroll")                                                        \
      for (int r = 0; r < 4; ++r) {                                            \
        e0[ks][r] = exp2_n(fmaf(sf0[ks][r], scale2, bb[ks][r]));               \
        e1[ks][r] = exp2_n(fmaf(sf1[ks][r], scale2, bb[ks][r]));               \
      }                                                                        \
    float a0 = 0.f, a1 = 0.f, a2 = 0.f, a3 = 0.f;                              \
    _Pragma("unroll")                                                          \
    for (int r = 0; r < 4; ++r) {                                              \
      a0 += e0[0][r] + e0[1][r]; a1 += e0[2][r] + e0[3][r];                    \
      a2 += e1[0][r] + e1[1][r]; a3 += e1[2][r] + e1[3][r];                    \
    }                                                                          \
    l0 += a0 + a1; l1 += a2 + a3;                                              \
    union { bf16x8 v; uint32_t u[4]; } p00, p01, p10, p11;                     \
    p00.u[0] = cvtpk(e0[0][0], e0[0][1]); p00.u[1] = cvtpk(e0[0][2], e0[0][3]);\
    p00.u[2] = cvtpk(e0[1][0], e0[1][1]); p00.u[3] = cvtpk(e0[1][2], e0[1][3]);\
    p01.u[0] = cvtpk(e0[2][0], e0[2][1]); p01.u[1] = cvtpk(e0[2][2], e0[2][3]);\
    p01.u[2] = cvtpk(e0[3][0], e0[3][1]); p01.u[3] = cvtpk(e0[3][2], e0[3][3]);\
    p10.u[0] = cvtpk(e1[0][0], e1[0][1]); p10.u[1] = cvtpk(e1[0][2], e1[0][3]);\
    p10.u[2] = cvtpk(e1[1][0], e1[1][1]); p10.u[3] = cvtpk(e1[1][2], e1[1][3]);\
    p11.u[0] = cvtpk(e1[2][0], e1[2][1]); p11.u[1] = cvtpk(e1[2][2], e1[2][3]);\
    p11.u[2] = cvtpk(e1[3][0], e1[3][1]); p11.u[3] = cvtpk(e1[3][2], e1[3][3]);\
    __builtin_amdgcn_s_setprio(1);                                             \
    oacc[0][0] = __builtin_amdgcn_mfma_f32_16x16x32_bf16(vf[0][0], p00.v, oacc[0][0], 0, 0, 0); \
    oacc[0][1] = __builtin_amdgcn_mfma_f32_16x16x32_bf16(vf[1][0], p00.v, oacc[0][1], 0, 0, 0); \
    oacc[1][0] = __builtin_amdgcn_mfma_f32_16x16x32_bf16(vf[0][0], p10.v, oacc[1][0], 0, 0, 0); \
    oacc[1][1] = __builtin_amdgcn_mfma_f32_16x16x32_bf16(vf[1][0], p10.v, oacc[1][1], 0, 0, 0); \
    oacc[0][0] = __builtin_amdgcn_mfma_f32_16x16x32_bf16(vf[0][1], p01.v, oacc[0][0], 0, 0, 0); \
    oacc[0][1] = __builtin_amdgcn_mfma_f32_16x16x32_bf16(vf[1][1], p01.v, oacc[0][1], 0, 0, 0); \
    oacc[1][0] = __builtin_amdgcn_mfma_f32_16x16x32_bf16(vf[0][1], p11.v, oacc[1][0], 0, 0, 0); \
    oacc[1][1] = __builtin_amdgcn_mfma_f32_16x16x32_bf16(vf[1][1], p11.v, oacc[1][1], 0, 0, 0); \
    __builtin_amdgcn_s_setprio(0);                                             \
  }

  const int kt0 = w << 8;
  LOADT(kt0, kfA, vfA, bbA);
  LOADT(kt0 + 64, kfB, vfB, bbB);
  ATILE(kfA, vfA, bbA);
  LOADT(kt0 + 128, kfA, vfA, bbA);
  ATILE(kfB, vfB, bbB);
  LOADT(kt0 + 192, kfB, vfB, bbB);
  ATILE(kfA, vfA, bbA);
  ATILE(kfB, vfB, bbB);
#undef LOADT
#undef ATILE

  __shared__ float Lo[4][64][19];
  #pragma unroll
  for (int q = 0; q < 2; ++q)
    #pragma unroll
    for (int ds_ = 0; ds_ < 2; ++ds_)
      #pragma unroll
      for (int i = 0; i < 4; ++i)
        Lo[w][lane][q*8 + ds_*4 + i] = oacc[q][ds_][i];
  Lo[w][lane][16] = l0;
  Lo[w][lane][17] = l1;
  __syncthreads();
  if (w < 2) {
    const int q = w;
    float o[8] = {0.f,0.f,0.f,0.f,0.f,0.f,0.f,0.f};
    float ls = 0.f;
    #pragma unroll
    for (int ww = 0; ww < 4; ++ww) {
      ls += Lo[ww][lane][16 + q];
      #pragma unroll
      for (int i = 0; i < 8; ++i) o[i] += Lo[ww][lane][q*8 + i];
    }
    ls += __shfl_xor(ls, 16);
    ls += __shfl_xor(ls, 32);
    const float inv = 1.f / ls;
    ushort* orow = O + (size_t)(b*SEQ + qb + q*16 + c)*DIM + h*32 + g*4;
    const uint32_t w0 = (uint32_t)f2bf(o[0]*inv) | ((uint32_t)f2bf(o[1]*inv) << 16);
    const uint32_t w1 = (uint32_t)f2bf(o[2]*inv) | ((uint32_t)f2bf(o[3]*inv) << 16);
    const uint32_t w2 = (uint32_t)f2bf(o[4]*inv) | ((uint32_t)f2bf(o[5]*inv) << 16);
    const uint32_t w3 = (uint32_t)f2bf(o[6]*inv) | ((uint32_t)f2bf(o[7]*inv) << 16);
    *(uint32_t*)(orow)      = w0;
    *(uint32_t*)(orow + 2)  = w1;
    *(uint32_t*)(orow + 16) = w2;
    *(uint32_t*)(orow + 18) = w3;
  }
}

// ---------------- layer-2 decode attention, 4-way key split (partials) ----------------
// grid 256: (bh, ks) ; each block: 256 keys; writes P[bh][ks][32 o-sums + l-sum].
__global__ __launch_bounds__(256) void decode512(
    const ushort* __restrict__ x2b, const ushort* __restrict__ Wq1,
    const float* __restrict__ bq1, const ushort* __restrict__ kh,
    const ushort* __restrict__ vh, const float* __restrict__ bm2l,
    float* __restrict__ P)
{
  const int lin = blockIdx.x;
  const int ks = lin & 3, bh = lin >> 2;
  const int b = bh >> 3, h = bh & 7;
  const int tid = threadIdx.x;
  const float scale2 = 0.17677669529663687f * 1.4426950408889634f;
  __shared__ float xrow[256];
  __shared__ float qv[32];
  xrow[tid] = bf2f(x2b[(size_t)(b*SEQ)*DIM + tid]);
  __syncthreads();
  if (tid < 32) {
    const ushort* wrow = Wq1 + (size_t)(h*32 + tid)*DIM;
    float acc = bq1[h*32 + tid];
    #pragma unroll
    for (int k8 = 0; k8 < 32; ++k8) {
      const bf16x8 wv = *(const bf16x8*)(wrow + k8*8);
      #pragma unroll
      for (int j = 0; j < 8; ++j)
        acc = fmaf(bf2f((ushort)wv[j]), xrow[k8*8 + j], acc);
    }
    qv[tid] = acc;
  }
  __syncthreads();
  const int key = ks*256 + tid;
  const ushort* kr = kh + (((size_t)bh*SEQ + key) << 5);
  float dot = 0.f;
  #pragma unroll
  for (int i = 0; i < 4; ++i) {
    const bf16x8 kv8 = *(const bf16x8*)(kr + i*8);
    #pragma unroll
    for (int j = 0; j < 8; ++j)
      dot = fmaf(bf2f((ushort)kv8[j]), qv[i*8 + j], dot);
  }
  const float e = exp2_n(fmaf(dot, scale2, bm2l[b*SEQ + key]));
  const ushort* vr = vh + (((size_t)bh*SEQ + key) << 5);
  __shared__ float red[256][33];
  #pragma unroll
  for (int i = 0; i < 4; ++i) {
    const bf16x8 vv8 = *(const bf16x8*)(vr + i*8);
    #pragma unroll
    for (int j = 0; j < 8; ++j)
      red[tid][i*8 + j] = e * bf2f((ushort)vv8[j]);
  }
  red[tid][32] = e;
  __syncthreads();
  for (int s = 128; s >= 1; s >>= 1) {
    for (int i = tid; i < s*33; i += 256) {
      const int r = i / 33, d = i - r*33;
      red[r][d] += red[r + s][d];
    }
    __syncthreads();
  }
  if (tid < 33) P[((size_t)bh*4 + ks)*33 + tid] = red[0][tid];
}

// ---------------- Wo GEMV, weight-stationary: grid 64, block = 4 cols x 8 batches ----------------
__global__ __launch_bounds__(256) void wo_part(
    const float* __restrict__ P, const ushort* __restrict__ WoT1,
    const float* __restrict__ bo1, float* __restrict__ wo_out)
{
  const int cc = blockIdx.x, tid = threadIdx.x;
  __shared__ float orow[8][256];
  {
    const int b = tid >> 5, d32 = tid & 31;
    #pragma unroll
    for (int h = 0; h < 8; ++h) {
      const float* pp = P + ((size_t)(b*8 + h)*4)*33;
      float ov = 0.f, l = 0.f;
      #pragma unroll
      for (int ks = 0; ks < 4; ++ks) { ov += pp[ks*33 + d32]; l += pp[ks*33 + 32]; }
      orow[b][h*32 + d32] = ov / l;
    }
  }
  __syncthreads();
  const int w = tid >> 6, lane = tid & 63;
  const int col = cc*4 + w;
  const ushort* wrow = WoT1 + (size_t)col*DIM + lane*4;
  float wk[4];
  #pragma unroll
  for (int j = 0; j < 4; ++j) wk[j] = bf2f(wrow[j]);
  #pragma unroll
  for (int b = 0; b < 8; ++b) {
    float p = 0.f;
    #pragma unroll
    for (int j = 0; j < 4; ++j) p = fmaf(wk[j], orow[b][lane*4 + j], p);
    #pragma unroll
    for (int off = 32; off >= 1; off >>= 1) p += __shfl_xor(p, off);
    if (lane == 0) wo_out[b*DIM + col] = p + bo1[col];
  }
}

// ---------------- residual + LN2 (grid 8) ----------------
__global__ __launch_bounds__(256) void ln2k(
    const float* __restrict__ x, const float* __restrict__ wo_out,
    const float* __restrict__ g21, const float* __restrict__ be21,
    float* __restrict__ newx_out, float* __restrict__ t2f)
{
  const int b = blockIdx.x, tid = threadIdx.x;
  const int wave = tid >> 6, lane = tid & 63;
  __shared__ float red[2][4];
  const float newx = x[(size_t)(b*SEQ)*DIM + tid] + wo_out[b*DIM + tid];
  newx_out[b*DIM + tid] = newx;
  float sm = newx;
  #pragma unroll
  for (int o = 32; o >= 1; o >>= 1) sm += __shfl_xor(sm, o);
  if (lane == 0) red[0][wave] = sm;
  __syncthreads();
  const float mean = (red[0][0]+red[0][1]+red[0][2]+red[0][3]) * (1.f/256.f);
  const float dv = newx - mean;
  float q = dv * dv;
  #pragma unroll
  for (int o = 32; o >= 1; o >>= 1) q += __shfl_xor(q, o);
  if (lane == 0) red[1][wave] = q;
  __syncthreads();
  const float var = (red[1][0]+red[1][1]+red[1][2]+red[1][3]) * (1.f/256.f);
  const float rs = rsqrtf(var + 1e-5f);
  t2f[b*DIM + tid] = dv*rs*g21[tid] + be21[tid];
}

// ---------------- FF1 GEMV, weight-stationary: grid 64, block = 16 cols x 8 batches ----------------
__global__ __launch_bounds__(256) void ff1_part(
    const float* __restrict__ t2f, const ushort* __restrict__ W1T1,
    const float* __restrict__ b11, float* __restrict__ mid)
{
  const int cc = blockIdx.x, tid = threadIdx.x;
  __shared__ float trow[8][256];
  #pragma unroll
  for (int b = 0; b < 8; ++b) trow[b][tid] = t2f[b*DIM + tid];
  __syncthreads();
  const int dotid = tid >> 1;
  const int col = cc*16 + (dotid & 15);
  const int b = dotid >> 4;
  const int kh_ = (tid & 1) * 128;
  const ushort* wrow = W1T1 + (size_t)col*DIM + kh_;
  float acc = 0.f;
  #pragma unroll
  for (int k8 = 0; k8 < 16; ++k8) {
    const bf16x8 wv = *(const bf16x8*)(wrow + k8*8);
    #pragma unroll
    for (int j = 0; j < 8; ++j)
      acc = fmaf(bf2f((ushort)wv[j]), trow[b][kh_ + k8*8 + j], acc);
  }
  acc += __shfl_xor(acc, 1);
  if ((tid & 1) == 0) mid[b*FFD + col] = fmaxf(acc + b11[col], 0.f);
}

// ---------------- FF2 GEMV, weight-stationary: grid 64, block = 4 cols x 8 batches ----------------
__global__ __launch_bounds__(256) void ff2_part(
    const float* __restrict__ mid, const ushort* __restrict__ W2T1,
    const float* __restrict__ b21, const float* __restrict__ newx_out,
    float* __restrict__ y2)
{
  const int cc = blockIdx.x, tid = threadIdx.x;
  __shared__ float mrow[8][1024];
  #pragma unroll
  for (int i = 0; i < 32; ++i) {
    const int idx = i*256 + tid;
    mrow[idx >> 10][idx & 1023] = mid[idx];
  }
  __syncthreads();
  const int dotid = tid >> 3;
  const int col = cc*4 + (dotid & 3);
  const int b = dotid >> 2;
  const int seg = (tid & 7) * 128;
  const ushort* wrow = W2T1 + (size_t)col*FFD + seg;
  float acc = 0.f;
  #pragma unroll
  for (int k8 = 0; k8 < 16; ++k8) {
    const bf16x8 wv = *(const bf16x8*)(wrow + k8*8);
    #pragma unroll
    for (int j = 0; j < 8; ++j)
      acc = fmaf(bf2f((ushort)wv[j]), mrow[b][seg + k8*8 + j], acc);
  }
  acc += __shfl_xor(acc, 1);
  acc += __shfl_xor(acc, 2);
  acc += __shfl_xor(acc, 4);
  if ((tid & 7) == 0)
    y2[b*DIM + col] = newx_out[b*DIM + col] + acc + b21[col];
}

// ---------------- final LN + classifier on y2 rows (grid 8) ----------------
__global__ __launch_bounds__(256) void cls2(
    const float* __restrict__ y2, const float* __restrict__ gf,
    const float* __restrict__ bfb, const float* __restrict__ Wc,
    const float* __restrict__ bc, float* __restrict__ out)
{
  const int b = blockIdx.x, tid = threadIdx.x;
  const int wave = tid >> 6, lane = tid & 63;
  const float v = y2[b*DIM + tid];
  __shared__ float redm[4], redv[4], redc[4][4];
  float s = v;
  #pragma unroll
  for (int o = 32; o >= 1; o >>= 1) s += __shfl_xor(s, o);
  if (lane == 0) redm[wave] = s;
  __syncthreads();
  const float mean = (redm[0]+redm[1]+redm[2]+redm[3]) * (1.f/256.f);
  const float dv = v - mean;
  float q = dv * dv;
  #pragma unroll
  for (int o = 32; o >= 1; o >>= 1) q += __shfl_xor(q, o);
  if (lane == 0) redv[wave] = q;
  __syncthreads();
  const float var = (redv[0]+redv[1]+redv[2]+redv[3]) * (1.f/256.f);
  const float rs = rsqrtf(var + 1e-5f);
  const float yn = dv*rs*gf[tid] + bfb[tid];
  float pc[4];
  #pragma unroll
  for (int cc = 0; cc < 4; ++cc) pc[cc] = yn * Wc[tid*4 + cc];
  #pragma unroll
  for (int cc = 0; cc < 4; ++cc) {
    #pragma unroll
    for (int o = 32; o >= 1; o >>= 1) pc[cc] += __shfl_xor(pc[cc], o);
  }
  if (lane == 0) {
    #pragma unroll
    for (int cc = 0; cc < 4; ++cc) redc[wave][cc] = pc[cc];
  }
  __syncthreads();
  if (tid < 4)
    out[b*4 + tid] = redc[0][tid] + redc[1][tid] + redc[2][tid] + redc[3][tid] + bc[tid];
}

extern "C" void kernel_launch(void* const* d_in, const int* in_sizes, int n_in,
                              void* d_out, int out_size, void* d_ws, size_t ws_size,
                              hipStream_t stream)
{
  const int*   ids    = (const int*)d_in[0];
  const int*   ngrams = (const int*)d_in[1];
  const float* tfidf  = (const float*)d_in[2];
  const float* emb    = (const float*)d_in[3];
  const float* pos    = (const float*)d_in[4];
  const float* bucket = (const float*)d_in[5];
  const float* Wq = (const float*)d_in[6];  const float* bq = (const float*)d_in[7];
  const float* Wk = (const float*)d_in[8];  const float* bk = (const float*)d_in[9];
  const float* Wv = (const float*)d_in[10]; const float* bv = (const float*)d_in[11];
  const float* Wo = (const float*)d_in[12]; const float* bo = (const float*)d_in[13];
  const float* g1 = (const float*)d_in[14]; const float* be1= (const float*)d_in[15];
  const float* g2 = (const float*)d_in[16]; const float* be2= (const float*)d_in[17];
  const float* W1 = (const float*)d_in[18]; const float* b1 = (const float*)d_in[19];
  const float* W2 = (const float*)d_in[20]; const float* b2 = (const float*)d_in[21];
  const float* alpha = (const float*)d_in[22];
  const float* gf = (const float*)d_in[23]; const float* bf = (const float*)d_in[24];
  const float* Wc = (const float*)d_in[25]; const float* bc = (const float*)d_in[26];

  uint8_t* base = (uint8_t*)d_ws;
  float*  x      = (float*)  base;                  //  8,388,608
  ushort* x2b    = (ushort*)(base + 8388608);       //  4,194,304
  ushort* qkh    = (ushort*)(base + 12582912);      //  8,388,608 (Q head-major, K at +QKSTRIDE)
  ushort* vtb    = (ushort*)(base + 20971520);      //  4,194,304 (V permuted l0 / V head-major l1)
  ushort* attb   = (ushort*)(base + 25165824);      //  4,194,304 (l0 attn out; later tail scratch)
  ushort* midb   = (ushort*)(base + 29360128);      // 16,777,216
  float*  bm2    = (float*) (base + 46137344);      //     65,536 (2 layers)
  ushort* WqkvT  = (ushort*)(base + 46202880);      //    786,432
  ushort* WoT    = (ushort*)(base + 46989312);      //    262,144
  ushort* W1T    = (ushort*)(base + 47251456);      //  1,048,576
  ushort* W2T    = (ushort*)(base + 48300032);      //  1,048,576  -> 49,348,608 total

  // tail scratch carved from attb region (dead after gemm64_acc<256> of layer 0)
  float* P       = (float*)(base + 25165824);            // 33,792 B
  float* wo_out  = (float*)(base + 25165824 + 65536);    // 8 KB
  float* newxo   = (float*)(base + 25165824 + 73728);    // 8 KB
  float* t2f     = (float*)(base + 25165824 + 81920);    // 8 KB
  float* midf    = (float*)(base + 25165824 + 90112);    // 32 KB
  float* y2      = (float*)(base + 25165824 + 122880);   // 8 KB

  TDescs td;
  for (int l = 0; l < NL; ++l) {
    td.d[6*l+0] = { Wq + (size_t)l*DIM*DIM, WqkvT + (size_t)l*768*DIM +   0*DIM, DIM, DIM };
    td.d[6*l+1] = { Wk + (size_t)l*DIM*DIM, WqkvT + (size_t)l*768*DIM + 256*DIM, DIM, DIM };
    td.d[6*l+2] = { Wv + (size_t)l*DIM*DIM, WqkvT + (size_t)l*768*DIM + 512*DIM, DIM, DIM };
    td.d[6*l+3] = { Wo + (size_t)l*DIM*DIM, WoT  + (size_t)l*DIM*DIM,  DIM, DIM };
    td.d[6*l+4] = { W1 + (size_t)l*DIM*FFD, W1T  + (size_t)l*FFD*DIM,  DIM, FFD };
    td.d[6*l+5] = { W2 + (size_t)l*FFD*DIM, W2T  + (size_t)l*DIM*FFD,  FFD, DIM };
  }
  transpose_conv<<<dim3(32, 32, 12), 256, 0, stream>>>(td);

  embed_ln_kernel<<<TOK, 256, 0, stream>>>(
      ids, ngrams, tfidf, emb, pos, bucket, alpha, g1, be1, x, x2b, bm2);

  const dim3 gqkv(6, TOK/64), gkv(4, TOK/64), gff1(8, TOK/64), g64(4, TOK/64);

  // ---------- layer 0: full pipeline ----------
  gemm_mfma<256, 768, 3><<<gqkv, 256, 0, stream>>>(
      x2b, WqkvT, bq, bk, bv, qkh, vtb);
  attn_mfma<<<2048, 256, 0, stream>>>(qkh, qkh + QKSTRIDE, vtb, bm2, attb);
  gemm64_acc<256><<<g64, 256, 0, stream>>>(attb, WoT, bo, x);
  ln_bf16<<<TOK/4, 256, 0, stream>>>(x, g2, be2, x2b);
  gemm_mfma<256, 1024, 1><<<gff1, 256, 0, stream>>>(
      x2b, W1T, b1, nullptr, nullptr, midb, nullptr);
  gemm64_acc<1024><<<g64, 256, 0, stream>>>(midb, W2T, b2, x);

  // ---------- layer 1: only row 0 per batch feeds the output ----------
  ln_bf16<<<TOK/4, 256, 0, stream>>>(x, g1 + DIM, be1 + DIM, x2b);
  gemm_mfma<256, 512, 4><<<gkv, 256, 0, stream>>>(
      x2b, WqkvT + (size_t)768*DIM + 256*DIM, bk + DIM, bv + DIM, nullptr,
      qkh + QKSTRIDE, vtb);
  decode512<<<256, 256, 0, stream>>>(
      x2b, WqkvT + (size_t)768*DIM, bq + DIM,
      qkh + QKSTRIDE, vtb, bm2 + TOK, P);
  wo_part<<<64, 256, 0, stream>>>(P, WoT + DIM*DIM, bo + DIM, wo_out);
  ln2k<<<8, 256, 0, stream>>>(x, wo_out, g2 + DIM, be2 + DIM, newxo, t2f);
  ff1_part<<<64, 256, 0, stream>>>(t2f, W1T + FFD*DIM, b1 + FFD, midf);
  ff2_part<<<64, 256, 0, stream>>>(midf, W2T + DIM*FFD, b2 + DIM, newxo, y2);
  cls2<<<8, 256, 0, stream>>>(y2, gf, bf, Wc, bc, (float*)d_out);
}

// Round 15
// 143.674 us; speedup vs baseline: 1.3166x; 1.0471x over previous
//
#include <hip/hip_runtime.h>
#include <hip/hip_bf16.h>
#include <math.h>

#define TOK 8192       // B*S
#define DIM 256
#define SEQ 1024
#define NH 8
#define FFD 1024
#define NL 2
#define VOCAB 32000
#define QKSTRIDE 2097152   // elems between Q and K head-major blocks

typedef short bf16x8 __attribute__((ext_vector_type(8)));
typedef float f32x4 __attribute__((ext_vector_type(4)));

__device__ __forceinline__ ushort f2bf(float f) {
  union { float f; uint32_t u; } v; v.f = f;
  uint32_t r = v.u + 0x7FFFu + ((v.u >> 16) & 1u);
  return (ushort)(r >> 16);
}

__device__ __forceinline__ float bf2f(ushort u) {
  union { uint32_t u; float f; } v; v.u = (uint32_t)u << 16; return v.f;
}

__device__ __forceinline__ float exp2_n(float x) {
  float r; asm("v_exp_f32 %0, %1" : "=v"(r) : "v"(x)); return r;
}

__device__ __forceinline__ uint32_t cvtpk(float lo, float hi) {
  uint32_t r; asm("v_cvt_pk_bf16_f32 %0, %1, %2" : "=v"(r) : "v"(lo), "v"(hi));
  return r;
}

__device__ __forceinline__ void gload_lds16(const ushort* gp, ushort* lp) {
  __builtin_amdgcn_global_load_lds(
      (const __attribute__((address_space(1))) void*)gp,
      (__attribute__((address_space(3))) void*)lp, 16, 0, 0);
}

// ---------------- embedding + ngram + tfidf bias + fused layer-0 LN ----------------
// 4 tokens/block (one wave each), float4 per lane, pure-shfl LN. grid TOK/4.
__global__ __launch_bounds__(256) void embed_ln_kernel(
    const int* __restrict__ ids, const int* __restrict__ ngram_ids,
    const float* __restrict__ tfidf, const float* __restrict__ emb,
    const float* __restrict__ pos, const float* __restrict__ bucket,
    const float* __restrict__ alpha, const float* __restrict__ g1,
    const float* __restrict__ be1,
    float* __restrict__ x, ushort* __restrict__ x2b, float* __restrict__ bm2)
{
  __shared__ int ngs[4][12];
  const int wave = threadIdx.x >> 6, lane = threadIdx.x & 63;
  const int t = blockIdx.x * 4 + wave;
  const int id = ids[t];
  int idc = id; if (idc < 0) idc = 0; if (idc > VOCAB-1) idc = VOCAB-1;
  if (lane < 12) ngs[wave][lane] = ngram_ids[idc*12 + lane];
  if (lane == 0) {
    const float tf = tfidf[idc];
    const bool msk = (id == 0);
    const float l2e = 1.4426950408889634f;
    bm2[t]       = msk ? -1e30f : tf * alpha[0] * l2e;
    bm2[TOK + t] = msk ? -1e30f : tf * alpha[1] * l2e;
  }
  __syncthreads();
  const int d0 = lane * 4;
  const int s = t & (SEQ - 1);
  float4 v = *reinterpret_cast<const float4*>(emb + (size_t)id*DIM + d0);
  const float4 p4 = *reinterpret_cast<const float4*>(pos + s*DIM + d0);
  v.x += p4.x; v.y += p4.y; v.z += p4.z; v.w += p4.w;
  float4 sum = {0.f, 0.f, 0.f, 0.f}; int cnt = 0;
  #pragma unroll
  for (int g = 0; g < 12; ++g) {
    const int ng = ngs[wave][g];
    if (ng != 0) {
      const float4 b4 = *reinterpret_cast<const float4*>(bucket + (size_t)ng*DIM + d0);
      sum.x += b4.x; sum.y += b4.y; sum.z += b4.z; sum.w += b4.w;
      cnt++;
    }
  }
  const float inv = 1.f / fmaxf((float)cnt, 1.0f);
  v.x += sum.x*inv; v.y += sum.y*inv; v.z += sum.z*inv; v.w += sum.w*inv;
  *reinterpret_cast<float4*>(x + (size_t)t*DIM + d0) = v;
  // LN (layer 0, ln1) across the wave
  float sm = v.x + v.y + v.z + v.w;
  #pragma unroll
  for (int o = 32; o >= 1; o >>= 1) sm += __shfl_xor(sm, o);
  const float mean = sm * (1.f/256.f);
  const float dx0 = v.x-mean, dx1 = v.y-mean, dx2 = v.z-mean, dx3 = v.w-mean;
  float q = dx0*dx0 + dx1*dx1 + dx2*dx2 + dx3*dx3;
  #pragma unroll
  for (int o = 32; o >= 1; o >>= 1) q += __shfl_xor(q, o);
  const float rs = rsqrtf(q * (1.f/256.f) + 1e-5f);
  const float4 gv = *reinterpret_cast<const float4*>(g1 + d0);
  const float4 bv = *reinterpret_cast<const float4*>(be1 + d0);
  ushort4 o4;
  o4.x = f2bf(dx0*rs*gv.x + bv.x);
  o4.y = f2bf(dx1*rs*gv.y + bv.y);
  o4.z = f2bf(dx2*rs*gv.z + bv.z);
  o4.w = f2bf(dx3*rs*gv.w + bv.w);
  *reinterpret_cast<ushort4*>(x2b + (size_t)t*DIM + d0) = o4;
}

// ---------------- layernorm -> bf16 ----------------
__global__ __launch_bounds__(256) void ln_bf16(
    const float* __restrict__ x, const float* __restrict__ g,
    const float* __restrict__ b, ushort* __restrict__ y)
{
  const int wave = threadIdx.x >> 6, lane = threadIdx.x & 63;
  const int row = blockIdx.x * 4 + wave;
  const float* xr = x + (size_t)row * DIM;
  float4 v = *reinterpret_cast<const float4*>(xr + lane*4);
  float s = v.x + v.y + v.z + v.w;
  #pragma unroll
  for (int o = 32; o >= 1; o >>= 1) s += __shfl_xor(s, o);
  const float mean = s * (1.f/256.f);
  const float dx0 = v.x-mean, dx1 = v.y-mean, dx2 = v.z-mean, dx3 = v.w-mean;
  float q = dx0*dx0 + dx1*dx1 + dx2*dx2 + dx3*dx3;
  #pragma unroll
  for (int o = 32; o >= 1; o >>= 1) q += __shfl_xor(q, o);
  const float rs = rsqrtf(q * (1.f/256.f) + 1e-5f);
  float4 gv = *reinterpret_cast<const float4*>(g + lane*4);
  float4 bv = *reinterpret_cast<const float4*>(b + lane*4);
  ushort4 o4;
  o4.x = f2bf(dx0*rs*gv.x + bv.x);
  o4.y = f2bf(dx1*rs*gv.y + bv.y);
  o4.z = f2bf(dx2*rs*gv.z + bv.z);
  o4.w = f2bf(dx3*rs*gv.w + bv.w);
  *reinterpret_cast<ushort4*>(y + (size_t)row*DIM + lane*4) = o4;
}

// ---------------- weight transpose + bf16: f32 [K][N] -> bf16 [N][K] ----------------
struct TDesc { const float* src; ushort* dst; int K; int N; };
struct TDescs { TDesc d[12]; };

__global__ __launch_bounds__(256) void transpose_conv(TDescs descs)
{
  const TDesc t = descs.d[blockIdx.z];
  const int k0 = blockIdx.x * 32, n0 = blockIdx.y * 32;
  if (k0 >= t.K || n0 >= t.N) return;
  __shared__ float tile[32][33];
  const int r = threadIdx.x >> 5, cc = threadIdx.x & 31;
  #pragma unroll
  for (int i = 0; i < 4; ++i)
    tile[r + i*8][cc] = t.src[(size_t)(k0 + r + i*8)*t.N + n0 + cc];
  __syncthreads();
  #pragma unroll
  for (int i = 0; i < 4; ++i)
    t.dst[(size_t)(n0 + r + i*8)*t.K + k0 + cc] = f2bf(tile[cc][r + i*8]);
}

// ---------------- bf16 MFMA GEMM, counted-vmcnt 3-buffer pipeline ----------------
// MODE 1: relu + bf16 out; MODE 3: qkv -> Q,K head-major + V permuted;
// MODE 4: K,V BOTH head-major.
template<int KDIM, int NDIM, int MODE>
__global__ __launch_bounds__(256) void gemm_mfma(
    const ushort* __restrict__ A, const ushort* __restrict__ Bw,
    const float* __restrict__ bias0, const float* __restrict__ bias1,
    const float* __restrict__ bias2, void* __restrict__ Cout,
    ushort* __restrict__ vtb)
{
  __shared__ ushort Al[3][64*32];
  __shared__ ushort Bl[3][128*32];
  const int bm = blockIdx.y * 64, bn = blockIdx.x * 128;
  const int tid = threadIdx.x, w = tid >> 6, lane = tid & 63;
  const int g = lane >> 4, c = lane & 15;
  const int lrow = lane >> 2, lc8 = (lane & 3) << 3;
  const f32x4 fzero = {0.f, 0.f, 0.f, 0.f};
  f32x4 acc[4][2];
  #pragma unroll
  for (int m = 0; m < 4; ++m) { acc[m][0] = fzero; acc[m][1] = fzero; }

#define STAGE(buf, k0)                                                         \
  {                                                                            \
    _Pragma("unroll")                                                          \
    for (int ch = w; ch < 12; ch += 4) {                                       \
      if (ch < 4)                                                              \
        gload_lds16(A + (size_t)(bm + ch*16 + lrow)*KDIM + (k0) + lc8,         \
                    &Al[buf][ch*512]);                                         \
      else                                                                     \
        gload_lds16(Bw + (size_t)(bn + (ch-4)*16 + lrow)*KDIM + (k0) + lc8,    \
                    &Bl[buf][(ch-4)*512]);                                     \
    }                                                                          \
  }

#define COMPUTE(buf)                                                           \
  {                                                                            \
    bf16x8 af[4], bfr[2];                                                      \
    _Pragma("unroll")                                                          \
    for (int m = 0; m < 4; ++m)                                                \
      af[m] = *(const bf16x8*)&Al[buf][(m*16 + c)*32 + g*8];                   \
    _Pragma("unroll")                                                          \
    for (int n = 0; n < 2; ++n)                                                \
      bfr[n] = *(const bf16x8*)&Bl[buf][(w*32 + n*16 + c)*32 + g*8];           \
    _Pragma("unroll")                                                          \
    for (int m = 0; m < 4; ++m)                                                \
      _Pragma("unroll")                                                        \
      for (int n = 0; n < 2; ++n)                                              \
        acc[m][n] = __builtin_amdgcn_mfma_f32_16x16x32_bf16(af[m], bfr[n], acc[m][n], 0, 0, 0); \
  }

  STAGE(0, 0);
  STAGE(1, 32);
  STAGE(2, 64);
  int buf = 0;
  for (int k0 = 0; k0 + 64 < KDIM; k0 += 32) {
    asm volatile("s_waitcnt vmcnt(6)" ::: "memory");
    __builtin_amdgcn_s_barrier();
    COMPUTE(buf);
    asm volatile("s_waitcnt lgkmcnt(0)" ::: "memory");
    __builtin_amdgcn_s_barrier();
    if (k0 + 96 < KDIM) STAGE(buf, k0 + 96);
    buf = (buf == 2) ? 0 : buf + 1;
  }
  asm volatile("s_waitcnt vmcnt(3)" ::: "memory");
  __builtin_amdgcn_s_barrier();
  COMPUTE(buf);
  buf = (buf == 2) ? 0 : buf + 1;
  asm volatile("s_waitcnt vmcnt(0)" ::: "memory");
  __builtin_amdgcn_s_barrier();
  COMPUTE(buf);
#undef STAGE
#undef COMPUTE

  #pragma unroll
  for (int m = 0; m < 4; ++m) {
    const int row0 = bm + m*16 + g*4;
    #pragma unroll
    for (int n = 0; n < 2; ++n) {
      const int col = bn + w*32 + n*16 + c;
      if (MODE == 1) {
        const float bb = bias0[col];
        #pragma unroll
        for (int r = 0; r < 4; ++r) {
          const float vv = fmaxf(acc[m][n][r] + bb, 0.f);
          const float other = __shfl_xor(vv, 1);
          if ((c & 1) == 0) {
            const uint32_t word = (uint32_t)f2bf(vv) | ((uint32_t)f2bf(other) << 16);
            *(uint32_t*)((ushort*)Cout + (size_t)(row0 + r)*NDIM + col) = word;
          }
        }
      } else if (MODE == 4) {   // K,V both head-major
        const int b_ = row0 >> 10, s = row0 & (SEQ - 1);
        const int hd = col & 255;
        const int hh = hd >> 5, d = hd & 31;
        const float bb = (col < 256) ? bias0[hd] : bias1[hd];
        ushort* dst = ((col < 256) ? (ushort*)Cout : vtb)
                    + (((size_t)(b_*NH + hh)*SEQ + s) << 5) + d;
        #pragma unroll
        for (int r = 0; r < 4; ++r) {
          const float vv = acc[m][n][r] + bb;
          const float other = __shfl_xor(vv, 1);
          if ((c & 1) == 0) {
            const uint32_t word = (uint32_t)f2bf(vv) | ((uint32_t)f2bf(other) << 16);
            *(uint32_t*)(dst + (r << 5)) = word;
          }
        }
      } else {  // MODE 3
        const int b_ = row0 >> 10, s = row0 & (SEQ - 1);
        if (col < 512) {
          const int hd = col & 255;
          const int hh = hd >> 5, d = hd & 31;
          const float bb = (col < 256) ? bias0[hd] : bias1[hd];
          ushort* dst = (ushort*)Cout + (col < 256 ? 0 : QKSTRIDE)
                      + (((size_t)(b_*NH + hh)*SEQ + s) << 5) + d;
          #pragma unroll
          for (int r = 0; r < 4; ++r) {
            const float vv = acc[m][n][r] + bb;
            const float other = __shfl_xor(vv, 1);
            if ((c & 1) == 0) {
              const uint32_t word = (uint32_t)f2bf(vv) | ((uint32_t)f2bf(other) << 16);
              *(uint32_t*)(dst + (r << 5)) = word;
            }
          }
        } else {
          const int hd = col - 512;
          const int hh = hd >> 5, d = hd & 31;
          const float bb = bias2[hd];
          const int sg = s >> 5, a = (s & 31) >> 2;
          const int pbase = (a & 3)*8 + (a >> 2)*4;
          ushort4 w4;
          w4.x = f2bf(acc[m][n][0] + bb);
          w4.y = f2bf(acc[m][n][1] + bb);
          w4.z = f2bf(acc[m][n][2] + bb);
          w4.w = f2bf(acc[m][n][3] + bb);
          *(ushort4*)(vtb + (((size_t)((b_*NH + hh)*32 + sg)*32 + d) << 5) + pbase) = w4;
        }
      }
    }
  }
}

// ---------------- 64x64-tile accumulate GEMM (N=256), counted-vmcnt 3-buffer ----------------
template<int KDIM>
__global__ __launch_bounds__(256) void gemm64_acc(
    const ushort* __restrict__ A, const ushort* __restrict__ Bw,
    const float* __restrict__ bias, float* __restrict__ C)
{
  __shared__ ushort Al[3][64*32];
  __shared__ ushort Bl[3][64*32];
  const int bm = blockIdx.y * 64, bn = blockIdx.x * 64;
  const int tid = threadIdx.x, w = tid >> 6, lane = tid & 63;
  const int wm = w >> 1, wn = w & 1;
  const int g = lane >> 4, c = lane & 15;
  const int lrow = tid >> 2, lc8 = (tid & 3) << 3;
  const f32x4 fzero = {0.f, 0.f, 0.f, 0.f};
  f32x4 acc[2][2];
  acc[0][0] = fzero; acc[0][1] = fzero; acc[1][0] = fzero; acc[1][1] = fzero;

#define STAGE64(buf, k0)                                                       \
  {                                                                            \
    gload_lds16(A  + (size_t)(bm + lrow)*KDIM + (k0) + lc8,                    \
                &Al[buf][lrow*32 + lc8]);                                      \
    gload_lds16(Bw + (size_t)(bn + lrow)*KDIM + (k0) + lc8,                    \
                &Bl[buf][lrow*32 + lc8]);                                      \
  }

#define COMPUTE64(buf)                                                         \
  {                                                                            \
    bf16x8 af[2], bfr[2];                                                      \
    _Pragma("unroll")                                                          \
    for (int m = 0; m < 2; ++m)                                                \
      af[m] = *(const bf16x8*)&Al[buf][(wm*32 + m*16 + c)*32 + g*8];           \
    _Pragma("unroll")                                                          \
    for (int n = 0; n < 2; ++n)                                                \
      bfr[n] = *(const bf16x8*)&Bl[buf][(wn*32 + n*16 + c)*32 + g*8];          \
    _Pragma("unroll")                                                          \
    for (int m = 0; m < 2; ++m)                                                \
      _Pragma("unroll")                                                        \
      for (int n = 0; n < 2; ++n)                                              \
        acc[m][n] = __builtin_amdgcn_mfma_f32_16x16x32_bf16(af[m], bfr[n], acc[m][n], 0, 0, 0); \
  }

  STAGE64(0, 0);
  STAGE64(1, 32);
  STAGE64(2, 64);
  int buf = 0;
  for (int k0 = 0; k0 + 64 < KDIM; k0 += 32) {
    asm volatile("s_waitcnt vmcnt(4)" ::: "memory");
    __builtin_amdgcn_s_barrier();
    COMPUTE64(buf);
    asm volatile("s_waitcnt lgkmcnt(0)" ::: "memory");
    __builtin_amdgcn_s_barrier();
    if (k0 + 96 < KDIM) STAGE64(buf, k0 + 96);
    buf = (buf == 2) ? 0 : buf + 1;
  }
  asm volatile("s_waitcnt vmcnt(2)" ::: "memory");
  __builtin_amdgcn_s_barrier();
  COMPUTE64(buf);
  buf = (buf == 2) ? 0 : buf + 1;
  asm volatile("s_waitcnt vmcnt(0)" ::: "memory");
  __builtin_amdgcn_s_barrier();
  COMPUTE64(buf);
#undef STAGE64
#undef COMPUTE64

  #pragma unroll
  for (int m = 0; m < 2; ++m) {
    const int row0 = bm + wm*32 + m*16 + g*4;
    #pragma unroll
    for (int n = 0; n < 2; ++n) {
      const int col = bn + wn*32 + n*16 + c;
      const float bb = bias[col];
      #pragma unroll
      for (int r = 0; r < 4; ++r)
        C[(size_t)(row0 + r)*DIM + col] += acc[m][n][r] + bb;
    }
  }
}

// ---------------- flash attention (layer 0): 32 q-rows/block, max-free softmax ----------------
// bias loaded at use (L2-hot) instead of prefetch arrays.
__global__ __launch_bounds__(256) void attn_mfma(
    const ushort* __restrict__ qh, const ushort* __restrict__ kh,
    const ushort* __restrict__ vph, const float* __restrict__ bm2l,
    ushort* __restrict__ O)
{
  const int bid = blockIdx.x;
  const int lin = ((bid & 7) << 8) + (bid >> 3);       // bijective (2048 % 8 == 0)
  const int tid = threadIdx.x, w = tid >> 6, lane = tid & 63;
  const int qw = lin & 31, h = (lin >> 5) & 7, b = lin >> 8;
  const int qb = qw << 5;
  const float scale2 = 0.17677669529663687f * 1.4426950408889634f;  // rsqrt(32)*log2e
  const int g = lane >> 4, c = lane & 15;
  const f32x4 fzero = {0.f, 0.f, 0.f, 0.f};
  const size_t bh = (size_t)(b*NH + h);

  const bf16x8 qf0 = *(const bf16x8*)(qh + ((bh*SEQ + qb + c)      << 5) + g*8);
  const bf16x8 qf1 = *(const bf16x8*)(qh + ((bh*SEQ + qb + 16 + c) << 5) + g*8);
  const ushort* kbase = kh  + ((bh*SEQ) << 5) + g*8;
  const ushort* vbase = vph + ((bh*SEQ) << 5) + g*8;
  const float*  bmb   = bm2l + b*SEQ;

  f32x4 oacc[2][2];
  oacc[0][0] = fzero; oacc[0][1] = fzero; oacc[1][0] = fzero; oacc[1][1] = fzero;
  float l0 = 0.f, l1 = 0.f;

  bf16x8 kfA[4], kfB[4];
  bf16x8 vfA[2][2], vfB[2][2];

#define LOADT(kt, kf, vf)                                                      \
  {                                                                            \
    _Pragma("unroll")                                                          \
    for (int ks = 0; ks < 4; ++ks)                                             \
      kf[ks] = *(const bf16x8*)(kbase + (((kt) + ks*16 + c) << 5));            \
    _Pragma("unroll")                                                          \
    for (int ds_ = 0; ds_ < 2; ++ds_)                                          \
      _Pragma("unroll")                                                        \
      for (int sg = 0; sg < 2; ++sg)                                           \
        vf[ds_][sg] = *(const bf16x8*)(vbase +                                 \
            (((((kt) >> 5) + sg)*32 + ds_*16 + c) << 5));                      \
  }

#define ATILE(kf, vf, kt)                                                      \
  {                                                                            \
    f32x4 sf0[4], sf1[4];                                                      \
    __builtin_amdgcn_s_setprio(1);                                             \
    _Pragma("unroll")                                                          \
    for (int ks = 0; ks < 4; ++ks)                                             \
      sf0[ks] = __builtin_amdgcn_mfma_f32_16x16x32_bf16(kf[ks], qf0, fzero, 0, 0, 0); \
    _Pragma("unroll")                                                          \
    for (int ks = 0; ks < 4; ++ks)                                             \
      sf1[ks] = __builtin_amdgcn_mfma_f32_16x16x32_bf16(kf[ks], qf1, fzero, 0, 0, 0); \
    __builtin_amdgcn_s_setprio(0);                                             \
    float e0[4][4], e1[4][4];                                                  \
    _Pragma("unroll")                                                          \
    for (int ks = 0; ks < 4; ++ks) {                                           \
      const f32x4 bb = *(const f32x4*)(bmb + (kt) + ks*16 + g*4);              \
      _Pragma("unroll")                                                        \
      for (int r = 0; r < 4; ++r) {                                            \
        e0[ks][r] = exp2_n(fmaf(sf0[ks][r], scale2, bb[r]));                   \
        e1[ks][r] = exp2_n(fmaf(sf1[ks][r], scale2, bb[r]));                   \
      }                                                                        \
    }                                                                          \
    float a0 = 0.f, a1 = 0.f, a2 = 0.f, a3 = 0.f;                              \
    _Pragma("unroll")                                                          \
    for (int r = 0; r < 4; ++r) {                                              \
      a0 += e0[0][r] + e0[1][r]; a1 += e0[2][r] + e0[3][r];                    \
      a2 += e1[0][r] + e1[1][r]; a3 += e1[2][r] + e1[3][r];                    \
    }                                                                          \
    l0 += a0 + a1; l1 += a2 + a3;                                              \
    union { bf16x8 v; uint32_t u[4]; } p00, p01, p10, p11;                     \
    p00.u[0] = cvtpk(e0[0][0], e0[0][1]); p00.u[1] = cvtpk(e0[0][2], e0[0][3]);\
    p00.u[2] = cvtpk(e0[1][0], e0[1][1]); p00.u[3] = cvtpk(e0[1][2], e0[1][3]);\
    p01.u[0] = cvtpk(e0[2][0], e0[2][1]); p01.u[1] = cvtpk(e0[2][2], e0[2][3]);\
    p01.u[2] = cvtpk(e0[3][0], e0[3][1]); p01.u[3] = cvtpk(e0[3][2], e0[3][3]);\
    p10.u[0] = cvtpk(e1[0][0], e1[0][1]); p10.u[1] = cvtpk(e1[0][2], e1[0][3]);\
    p10.u[2] = cvtpk(e1[1][0], e1[1][1]); p10.u[3] = cvtpk(e1[1][2], e1[1][3]);\
    p11.u[0] = cvtpk(e1[2][0], e1[2][1]); p11.u[1] = cvtpk(e1[2][2], e1[2][3]);\
    p11.u[2] = cvtpk(e1[3][0], e1[3][1]); p11.u[3] = cvtpk(e1[3][2], e1[3][3]);\
    __builtin_amdgcn_s_setprio(1);                                             \
    oacc[0][0] = __builtin_amdgcn_mfma_f32_16x16x32_bf16(vf[0][0], p00.v, oacc[0][0], 0, 0, 0); \
    oacc[0][1] = __builtin_amdgcn_mfma_f32_16x16x32_bf16(vf[1][0], p00.v, oacc[0][1], 0, 0, 0); \
    oacc[1][0] = __builtin_amdgcn_mfma_f32_16x16x32_bf16(vf[0][0], p10.v, oacc[1][0], 0, 0, 0); \
    oacc[1][1] = __builtin_amdgcn_mfma_f32_16x16x32_bf16(vf[1][0], p10.v, oacc[1][1], 0, 0, 0); \
    oacc[0][0] = __builtin_amdgcn_mfma_f32_16x16x32_bf16(vf[0][1], p01.v, oacc[0][0], 0, 0, 0); \
    oacc[0][1] = __builtin_amdgcn_mfma_f32_16x16x32_bf16(vf[1][1], p01.v, oacc[0][1], 0, 0, 0); \
    oacc[1][0] = __builtin_amdgcn_mfma_f32_16x16x32_bf16(vf[0][1], p11.v, oacc[1][0], 0, 0, 0); \
    oacc[1][1] = __builtin_amdgcn_mfma_f32_16x16x32_bf16(vf[1][1], p11.v, oacc[1][1], 0, 0, 0); \
    __builtin_amdgcn_s_setprio(0);                                             \
  }

  const int kt0 = w << 8;
  LOADT(kt0, kfA, vfA);
  LOADT(kt0 + 64, kfB, vfB);
  ATILE(kfA, vfA, kt0);
  LOADT(kt0 + 128, kfA, vfA);
  ATILE(kfB, vfB, kt0 + 64);
  LOADT(kt0 + 192, kfB, vfB);
  ATILE(kfA, vfA, kt0 + 128);
  ATILE(kfB, vfB, kt0 + 192);
#undef LOADT
#undef ATILE

  __shared__ float Lo[4][64][19];
  #pragma unroll
  for (int q = 0; q < 2; ++q)
    #pragma unroll
    for (int ds_ = 0; ds_ < 2; ++ds_)
      #pragma unroll
      for (int i = 0; i < 4; ++i)
        Lo[w][lane][q*8 + ds_*4 + i] = oacc[q][ds_][i];
  Lo[w][lane][16] = l0;
  Lo[w][lane][17] = l1;
  __syncthreads();
  if (w < 2) {
    const int q = w;
    float o[8] = {0.f,0.f,0.f,0.f,0.f,0.f,0.f,0.f};
    float ls = 0.f;
    #pragma unroll
    for (int ww = 0; ww < 4; ++ww) {
      ls += Lo[ww][lane][16 + q];
      #pragma unroll
      for (int i = 0; i < 8; ++i) o[i] += Lo[ww][lane][q*8 + i];
    }
    ls += __shfl_xor(ls, 16);
    ls += __shfl_xor(ls, 32);
    const float inv = 1.f / ls;
    ushort* orow = O + (size_t)(b*SEQ + qb + q*16 + c)*DIM + h*32 + g*4;
    const uint32_t w0 = (uint32_t)f2bf(o[0]*inv) | ((uint32_t)f2bf(o[1]*inv) << 16);
    const uint32_t w1 = (uint32_t)f2bf(o[2]*inv) | ((uint32_t)f2bf(o[3]*inv) << 16);
    const uint32_t w2 = (uint32_t)f2bf(o[4]*inv) | ((uint32_t)f2bf(o[5]*inv) << 16);
    const uint32_t w3 = (uint32_t)f2bf(o[6]*inv) | ((uint32_t)f2bf(o[7]*inv) << 16);
    *(uint32_t*)(orow)      = w0;
    *(uint32_t*)(orow + 2)  = w1;
    *(uint32_t*)(orow + 16) = w2;
    *(uint32_t*)(orow + 18) = w3;
  }
}

// ---------------- layer-2 decode attention, 4-way key split (partials) ----------------
__global__ __launch_bounds__(256) void decode512(
    const ushort* __restrict__ x2b, const ushort* __restrict__ Wq1,
    const float* __restrict__ bq1, const ushort* __restrict__ kh,
    const ushort* __restrict__ vh, const float* __restrict__ bm2l,
    float* __restrict__ P)
{
  const int lin = blockIdx.x;
  const int ks = lin & 3, bh = lin >> 2;
  const int b = bh >> 3, h = bh & 7;
  const int tid = threadIdx.x;
  const float scale2 = 0.17677669529663687f * 1.4426950408889634f;
  __shared__ float xrow[256];
  __shared__ float qv[32];
  xrow[tid] = bf2f(x2b[(size_t)(b*SEQ)*DIM + tid]);
  __syncthreads();
  if (tid < 32) {
    const ushort* wrow = Wq1 + (size_t)(h*32 + tid)*DIM;
    float acc = bq1[h*32 + tid];
    #pragma unroll
    for (int k8 = 0; k8 < 32; ++k8) {
      const bf16x8 wv = *(const bf16x8*)(wrow + k8*8);
      #pragma unroll
      for (int j = 0; j < 8; ++j)
        acc = fmaf(bf2f((ushort)wv[j]), xrow[k8*8 + j], acc);
    }
    qv[tid] = acc;
  }
  __syncthreads();
  const int key = ks*256 + tid;
  const ushort* kr = kh + (((size_t)bh*SEQ + key) << 5);
  float dot = 0.f;
  #pragma unroll
  for (int i = 0; i < 4; ++i) {
    const bf16x8 kv8 = *(const bf16x8*)(kr + i*8);
    #pragma unroll
    for (int j = 0; j < 8; ++j)
      dot = fmaf(bf2f((ushort)kv8[j]), qv[i*8 + j], dot);
  }
  const float e = exp2_n(fmaf(dot, scale2, bm2l[b*SEQ + key]));
  const ushort* vr = vh + (((size_t)bh*SEQ + key) << 5);
  __shared__ float red[256][33];
  #pragma unroll
  for (int i = 0; i < 4; ++i) {
    const bf16x8 vv8 = *(const bf16x8*)(vr + i*8);
    #pragma unroll
    for (int j = 0; j < 8; ++j)
      red[tid][i*8 + j] = e * bf2f((ushort)vv8[j]);
  }
  red[tid][32] = e;
  __syncthreads();
  for (int s = 128; s >= 1; s >>= 1) {
    for (int i = tid; i < s*33; i += 256) {
      const int r = i / 33, d = i - r*33;
      red[r][d] += red[r + s][d];
    }
    __syncthreads();
  }
  if (tid < 33) P[((size_t)bh*4 + ks)*33 + tid] = red[0][tid];
}

// ---------------- Wo GEMV, weight-stationary: grid 64, block = 4 cols x 8 batches ----------------
__global__ __launch_bounds__(256) void wo_part(
    const float* __restrict__ P, const ushort* __restrict__ WoT1,
    const float* __restrict__ bo1, float* __restrict__ wo_out)
{
  const int cc = blockIdx.x, tid = threadIdx.x;
  __shared__ float orow[8][256];
  {
    const int b = tid >> 5, d32 = tid & 31;
    #pragma unroll
    for (int h = 0; h < 8; ++h) {
      const float* pp = P + ((size_t)(b*8 + h)*4)*33;
      float ov = 0.f, l = 0.f;
      #pragma unroll
      for (int ks = 0; ks < 4; ++ks) { ov += pp[ks*33 + d32]; l += pp[ks*33 + 32]; }
      orow[b][h*32 + d32] = ov / l;
    }
  }
  __syncthreads();
  const int w = tid >> 6, lane = tid & 63;
  const int col = cc*4 + w;
  const ushort* wrow = WoT1 + (size_t)col*DIM + lane*4;
  float wk[4];
  #pragma unroll
  for (int j = 0; j < 4; ++j) wk[j] = bf2f(wrow[j]);
  #pragma unroll
  for (int b = 0; b < 8; ++b) {
    float p = 0.f;
    #pragma unroll
    for (int j = 0; j < 4; ++j) p = fmaf(wk[j], orow[b][lane*4 + j], p);
    #pragma unroll
    for (int off = 32; off >= 1; off >>= 1) p += __shfl_xor(p, off);
    if (lane == 0) wo_out[b*DIM + col] = p + bo1[col];
  }
}

// ---------------- FF1 GEMV + in-block residual/LN2: grid 64, block = 16 cols x 8 batches ----------------
__global__ __launch_bounds__(256) void ff1_part(
    const float* __restrict__ x, const float* __restrict__ wo_out,
    const float* __restrict__ g21, const float* __restrict__ be21,
    const ushort* __restrict__ W1T1, const float* __restrict__ b11,
    float* __restrict__ mid)
{
  const int cc = blockIdx.x, tid = threadIdx.x;
  const int wave = tid >> 6, lane = tid & 63;
  __shared__ float trow[8][256];
  #pragma unroll
  for (int b = 0; b < 8; ++b)
    trow[b][tid] = x[(size_t)(b*SEQ)*DIM + tid] + wo_out[b*DIM + tid];
  __syncthreads();
  // per-wave LN: wave handles batches {wave, wave+4}
  #pragma unroll
  for (int bb_ = 0; bb_ < 2; ++bb_) {
    const int b = wave + bb_*4;
    float4 vv = *(float4*)&trow[b][lane*4];
    float sm = vv.x + vv.y + vv.z + vv.w;
    #pragma unroll
    for (int o = 32; o >= 1; o >>= 1) sm += __shfl_xor(sm, o);
    const float mean = sm * (1.f/256.f);
    const float dx0 = vv.x-mean, dx1 = vv.y-mean, dx2 = vv.z-mean, dx3 = vv.w-mean;
    float q = dx0*dx0 + dx1*dx1 + dx2*dx2 + dx3*dx3;
    #pragma unroll
    for (int o = 32; o >= 1; o >>= 1) q += __shfl_xor(q, o);
    const float rs = rsqrtf(q * (1.f/256.f) + 1e-5f);
    const float4 gv = *(const float4*)(g21 + lane*4);
    const float4 bv = *(const float4*)(be21 + lane*4);
    float4 nv;
    nv.x = dx0*rs*gv.x + bv.x;
    nv.y = dx1*rs*gv.y + bv.y;
    nv.z = dx2*rs*gv.z + bv.z;
    nv.w = dx3*rs*gv.w + bv.w;
    *(float4*)&trow[b][lane*4] = nv;
  }
  __syncthreads();
  const int dotid = tid >> 1;
  const int col = cc*16 + (dotid & 15);
  const int b = dotid >> 4;
  const int kh_ = (tid & 1) * 128;
  const ushort* wrow = W1T1 + (size_t)col*DIM + kh_;
  float acc = 0.f;
  #pragma unroll
  for (int k8 = 0; k8 < 16; ++k8) {
    const bf16x8 wv = *(const bf16x8*)(wrow + k8*8);
    #pragma unroll
    for (int j = 0; j < 8; ++j)
      acc = fmaf(bf2f((ushort)wv[j]), trow[b][kh_ + k8*8 + j], acc);
  }
  acc += __shfl_xor(acc, 1);
  if ((tid & 1) == 0) mid[b*FFD + col] = fmaxf(acc + b11[col], 0.f);
}

// ---------------- FF2 GEMV + residual: grid 64, block = 4 cols x 8 batches ----------------
__global__ __launch_bounds__(256) void ff2_part(
    const float* __restrict__ mid, const ushort* __restrict__ W2T1,
    const float* __restrict__ b21, const float* __restrict__ x,
    const float* __restrict__ wo_out, float* __restrict__ y2)
{
  const int cc = blockIdx.x, tid = threadIdx.x;
  __shared__ float mrow[8][1024];
  #pragma unroll
  for (int i = 0; i < 32; ++i) {
    const int idx = i*256 + tid;
    mrow[idx >> 10][idx & 1023] = mid[idx];
  }
  __syncthreads();
  const int dotid = tid >> 3;
  const int col = cc*4 + (dotid & 3);
  const int b = dotid >> 2;
  const int seg = (tid & 7) * 128;
  const ushort* wrow = W2T1 + (size_t)col*FFD + seg;
  float acc = 0.f;
  #pragma unroll
  for (int k8 = 0; k8 < 16; ++k8) {
    const bf16x8 wv = *(const bf16x8*)(wrow + k8*8);
    #pragma unroll
    for (int j = 0; j < 8; ++j)
      acc = fmaf(bf2f((ushort)wv[j]), mrow[b][seg + k8*8 + j], acc);
  }
  acc += __shfl_xor(acc, 1);
  acc += __shfl_xor(acc, 2);
  acc += __shfl_xor(acc, 4);
  if ((tid & 7) == 0)
    y2[b*DIM + col] = x[(size_t)(b*SEQ)*DIM + col] + wo_out[b*DIM + col]
                    + acc + b21[col];
}

// ---------------- final LN + classifier on y2 rows (grid 8) ----------------
__global__ __launch_bounds__(256) void cls2(
    const float* __restrict__ y2, const float* __restrict__ gf,
    const float* __restrict__ bfb, const float* __restrict__ Wc,
    const float* __restrict__ bc, float* __restrict__ out)
{
  const int b = blockIdx.x, tid = threadIdx.x;
  const int wave = tid >> 6, lane = tid & 63;
  const float v = y2[b*DIM + tid];
  __shared__ float redm[4], redv[4], redc[4][4];
  float s = v;
  #pragma unroll
  for (int o = 32; o >= 1; o >>= 1) s += __shfl_xor(s, o);
  if (lane == 0) redm[wave] = s;
  __syncthreads();
  const float mean = (redm[0]+redm[1]+redm[2]+redm[3]) * (1.f/256.f);
  const float dv = v - mean;
  float q = dv * dv;
  #pragma unroll
  for (int o = 32; o >= 1; o >>= 1) q += __shfl_xor(q, o);
  if (lane == 0) redv[wave] = q;
  __syncthreads();
  const float var = (redv[0]+redv[1]+redv[2]+redv[3]) * (1.f/256.f);
  const float rs = rsqrtf(var + 1e-5f);
  const float yn = dv*rs*gf[tid] + bfb[tid];
  float pc[4];
  #pragma unroll
  for (int cc = 0; cc < 4; ++cc) pc[cc] = yn * Wc[tid*4 + cc];
  #pragma unroll
  for (int cc = 0; cc < 4; ++cc) {
    #pragma unroll
    for (int o = 32; o >= 1; o >>= 1) pc[cc] += __shfl_xor(pc[cc], o);
  }
  if (lane == 0) {
    #pragma unroll
    for (int cc = 0; cc < 4; ++cc) redc[wave][cc] = pc[cc];
  }
  __syncthreads();
  if (tid < 4)
    out[b*4 + tid] = redc[0][tid] + redc[1][tid] + redc[2][tid] + redc[3][tid] + bc[tid];
}

extern "C" void kernel_launch(void* const* d_in, const int* in_sizes, int n_in,
                              void* d_out, int out_size, void* d_ws, size_t ws_size,
                              hipStream_t stream)
{
  const int*   ids    = (const int*)d_in[0];
  const int*   ngrams = (const int*)d_in[1];
  const float* tfidf  = (const float*)d_in[2];
  const float* emb    = (const float*)d_in[3];
  const float* pos    = (const float*)d_in[4];
  const float* bucket = (const float*)d_in[5];
  const float* Wq = (const float*)d_in[6];  const float* bq = (const float*)d_in[7];
  const float* Wk = (const float*)d_in[8];  const float* bk = (const float*)d_in[9];
  const float* Wv = (const float*)d_in[10]; const float* bv = (const float*)d_in[11];
  const float* Wo = (const float*)d_in[12]; const float* bo = (const float*)d_in[13];
  const float* g1 = (const float*)d_in[14]; const float* be1= (const float*)d_in[15];
  const float* g2 = (const float*)d_in[16]; const float* be2= (const float*)d_in[17];
  const float* W1 = (const float*)d_in[18]; const float* b1 = (const float*)d_in[19];
  const float* W2 = (const float*)d_in[20]; const float* b2 = (const float*)d_in[21];
  const float* alpha = (const float*)d_in[22];
  const float* gf = (const float*)d_in[23]; const float* bf = (const float*)d_in[24];
  const float* Wc = (const float*)d_in[25]; const float* bc = (const float*)d_in[26];

  uint8_t* base = (uint8_t*)d_ws;
  float*  x      = (float*)  base;                  //  8,388,608
  ushort* x2b    = (ushort*)(base + 8388608);       //  4,194,304
  ushort* qkh    = (ushort*)(base + 12582912);      //  8,388,608 (Q head-major, K at +QKSTRIDE)
  ushort* vtb    = (ushort*)(base + 20971520);      //  4,194,304 (V permuted l0 / V head-major l1)
  ushort* attb   = (ushort*)(base + 25165824);      //  4,194,304 (l0 attn out; later tail scratch)
  ushort* midb   = (ushort*)(base + 29360128);      // 16,777,216
  float*  bm2    = (float*) (base + 46137344);      //     65,536 (2 layers)
  ushort* WqkvT  = (ushort*)(base + 46202880);      //    786,432
  ushort* WoT    = (ushort*)(base + 46989312);      //    262,144
  ushort* W1T    = (ushort*)(base + 47251456);      //  1,048,576
  ushort* W2T    = (ushort*)(base + 48300032);      //  1,048,576  -> 49,348,608 total

  // tail scratch carved from attb region (dead after gemm64_acc<256> of layer 0)
  float* P       = (float*)(base + 25165824);            // 33,792 B
  float* wo_out  = (float*)(base + 25165824 + 65536);    // 8 KB
  float* midf    = (float*)(base + 25165824 + 90112);    // 32 KB
  float* y2      = (float*)(base + 25165824 + 122880);   // 8 KB

  TDescs td;
  for (int l = 0; l < NL; ++l) {
    td.d[6*l+0] = { Wq + (size_t)l*DIM*DIM, WqkvT + (size_t)l*768*DIM +   0*DIM, DIM, DIM };
    td.d[6*l+1] = { Wk + (size_t)l*DIM*DIM, WqkvT + (size_t)l*768*DIM + 256*DIM, DIM, DIM };
    td.d[6*l+2] = { Wv + (size_t)l*DIM*DIM, WqkvT + (size_t)l*768*DIM + 512*DIM, DIM, DIM };
    td.d[6*l+3] = { Wo + (size_t)l*DIM*DIM, WoT  + (size_t)l*DIM*DIM,  DIM, DIM };
    td.d[6*l+4] = { W1 + (size_t)l*DIM*FFD, W1T  + (size_t)l*FFD*DIM,  DIM, FFD };
    td.d[6*l+5] = { W2 + (size_t)l*FFD*DIM, W2T  + (size_t)l*DIM*FFD,  FFD, DIM };
  }
  transpose_conv<<<dim3(32, 32, 12), 256, 0, stream>>>(td);

  embed_ln_kernel<<<TOK/4, 256, 0, stream>>>(
      ids, ngrams, tfidf, emb, pos, bucket, alpha, g1, be1, x, x2b, bm2);

  const dim3 gqkv(6, TOK/64), gkv(4, TOK/64), gff1(8, TOK/64), g64(4, TOK/64);

  // ---------- layer 0: full pipeline ----------
  gemm_mfma<256, 768, 3><<<gqkv, 256, 0, stream>>>(
      x2b, WqkvT, bq, bk, bv, qkh, vtb);
  attn_mfma<<<2048, 256, 0, stream>>>(qkh, qkh + QKSTRIDE, vtb, bm2, attb);
  gemm64_acc<256><<<g64, 256, 0, stream>>>(attb, WoT, bo, x);
  ln_bf16<<<TOK/4, 256, 0, stream>>>(x, g2, be2, x2b);
  gemm_mfma<256, 1024, 1><<<gff1, 256, 0, stream>>>(
      x2b, W1T, b1, nullptr, nullptr, midb, nullptr);
  gemm64_acc<1024><<<g64, 256, 0, stream>>>(midb, W2T, b2, x);

  // ---------- layer 1: only row 0 per batch feeds the output ----------
  ln_bf16<<<TOK/4, 256, 0, stream>>>(x, g1 + DIM, be1 + DIM, x2b);
  gemm_mfma<256, 512, 4><<<gkv, 256, 0, stream>>>(
      x2b, WqkvT + (size_t)768*DIM + 256*DIM, bk + DIM, bv + DIM, nullptr,
      qkh + QKSTRIDE, vtb);
  decode512<<<256, 256, 0, stream>>>(
      x2b, WqkvT + (size_t)768*DIM, bq + DIM,
      qkh + QKSTRIDE, vtb, bm2 + TOK, P);
  wo_part<<<64, 256, 0, stream>>>(P, WoT + DIM*DIM, bo + DIM, wo_out);
  ff1_part<<<64, 256, 0, stream>>>(x, wo_out, g2 + DIM, be2 + DIM,
                                   W1T + FFD*DIM, b1 + FFD, midf);
  ff2_part<<<64, 256, 0, stream>>>(midf, W2T + DIM*FFD, b2 + DIM, x, wo_out, y2);
  cls2<<<8, 256, 0, stream>>>(y2, gf, bf, Wc, bc, (float*)d_out);
}

// Round 16
// 140.282 us; speedup vs baseline: 1.3485x; 1.0242x over previous
//
#include <hip/hip_runtime.h>
#include <hip/hip_bf16.h>
#include <math.h>

#define TOK 8192       // B*S
#define DIM 256
#define SEQ 1024
#define NH 8
#define FFD 1024
#define NL 2
#define VOCAB 32000
#define QKSTRIDE 2097152   // elems between Q and K head-major blocks

typedef short bf16x8 __attribute__((ext_vector_type(8)));
typedef float f32x4 __attribute__((ext_vector_type(4)));

__device__ __forceinline__ ushort f2bf(float f) {
  union { float f; uint32_t u; } v; v.f = f;
  uint32_t r = v.u + 0x7FFFu + ((v.u >> 16) & 1u);
  return (ushort)(r >> 16);
}

__device__ __forceinline__ float bf2f(ushort u) {
  union { uint32_t u; float f; } v; v.u = (uint32_t)u << 16; return v.f;
}

__device__ __forceinline__ float exp2_n(float x) {
  float r; asm("v_exp_f32 %0, %1" : "=v"(r) : "v"(x)); return r;
}

__device__ __forceinline__ uint32_t cvtpk(float lo, float hi) {
  uint32_t r; asm("v_cvt_pk_bf16_f32 %0, %1, %2" : "=v"(r) : "v"(lo), "v"(hi));
  return r;
}

__device__ __forceinline__ void gload_lds16(const ushort* gp, ushort* lp) {
  __builtin_amdgcn_global_load_lds(
      (const __attribute__((address_space(1))) void*)gp,
      (__attribute__((address_space(3))) void*)lp, 16, 0, 0);
}

// ---------------- embedding + ngram + tfidf bias + fused layer-0 LN ----------------
__global__ __launch_bounds__(256) void embed_ln_kernel(
    const int* __restrict__ ids, const int* __restrict__ ngram_ids,
    const float* __restrict__ tfidf, const float* __restrict__ emb,
    const float* __restrict__ pos, const float* __restrict__ bucket,
    const float* __restrict__ alpha, const float* __restrict__ g1,
    const float* __restrict__ be1,
    float* __restrict__ x, ushort* __restrict__ x2b, float* __restrict__ bm2)
{
  __shared__ int ngs[4][12];
  const int wave = threadIdx.x >> 6, lane = threadIdx.x & 63;
  const int t = blockIdx.x * 4 + wave;
  const int id = ids[t];
  int idc = id; if (idc < 0) idc = 0; if (idc > VOCAB-1) idc = VOCAB-1;
  if (lane < 12) ngs[wave][lane] = ngram_ids[idc*12 + lane];
  if (lane == 0) {
    const float tf = tfidf[idc];
    const bool msk = (id == 0);
    const float l2e = 1.4426950408889634f;
    bm2[t]       = msk ? -1e30f : tf * alpha[0] * l2e;
    bm2[TOK + t] = msk ? -1e30f : tf * alpha[1] * l2e;
  }
  __syncthreads();
  const int d0 = lane * 4;
  const int s = t & (SEQ - 1);
  float4 v = *reinterpret_cast<const float4*>(emb + (size_t)id*DIM + d0);
  const float4 p4 = *reinterpret_cast<const float4*>(pos + s*DIM + d0);
  v.x += p4.x; v.y += p4.y; v.z += p4.z; v.w += p4.w;
  float4 sum = {0.f, 0.f, 0.f, 0.f}; int cnt = 0;
  #pragma unroll
  for (int g = 0; g < 12; ++g) {
    const int ng = ngs[wave][g];
    if (ng != 0) {
      const float4 b4 = *reinterpret_cast<const float4*>(bucket + (size_t)ng*DIM + d0);
      sum.x += b4.x; sum.y += b4.y; sum.z += b4.z; sum.w += b4.w;
      cnt++;
    }
  }
  const float inv = 1.f / fmaxf((float)cnt, 1.0f);
  v.x += sum.x*inv; v.y += sum.y*inv; v.z += sum.z*inv; v.w += sum.w*inv;
  *reinterpret_cast<float4*>(x + (size_t)t*DIM + d0) = v;
  float sm = v.x + v.y + v.z + v.w;
  #pragma unroll
  for (int o = 32; o >= 1; o >>= 1) sm += __shfl_xor(sm, o);
  const float mean = sm * (1.f/256.f);
  const float dx0 = v.x-mean, dx1 = v.y-mean, dx2 = v.z-mean, dx3 = v.w-mean;
  float q = dx0*dx0 + dx1*dx1 + dx2*dx2 + dx3*dx3;
  #pragma unroll
  for (int o = 32; o >= 1; o >>= 1) q += __shfl_xor(q, o);
  const float rs = rsqrtf(q * (1.f/256.f) + 1e-5f);
  const float4 gv = *reinterpret_cast<const float4*>(g1 + d0);
  const float4 bv = *reinterpret_cast<const float4*>(be1 + d0);
  ushort4 o4;
  o4.x = f2bf(dx0*rs*gv.x + bv.x);
  o4.y = f2bf(dx1*rs*gv.y + bv.y);
  o4.z = f2bf(dx2*rs*gv.z + bv.z);
  o4.w = f2bf(dx3*rs*gv.w + bv.w);
  *reinterpret_cast<ushort4*>(x2b + (size_t)t*DIM + d0) = o4;
}

// ---------------- layernorm -> bf16 ----------------
__global__ __launch_bounds__(256) void ln_bf16(
    const float* __restrict__ x, const float* __restrict__ g,
    const float* __restrict__ b, ushort* __restrict__ y)
{
  const int wave = threadIdx.x >> 6, lane = threadIdx.x & 63;
  const int row = blockIdx.x * 4 + wave;
  const float* xr = x + (size_t)row * DIM;
  float4 v = *reinterpret_cast<const float4*>(xr + lane*4);
  float s = v.x + v.y + v.z + v.w;
  #pragma unroll
  for (int o = 32; o >= 1; o >>= 1) s += __shfl_xor(s, o);
  const float mean = s * (1.f/256.f);
  const float dx0 = v.x-mean, dx1 = v.y-mean, dx2 = v.z-mean, dx3 = v.w-mean;
  float q = dx0*dx0 + dx1*dx1 + dx2*dx2 + dx3*dx3;
  #pragma unroll
  for (int o = 32; o >= 1; o >>= 1) q += __shfl_xor(q, o);
  const float rs = rsqrtf(q * (1.f/256.f) + 1e-5f);
  float4 gv = *reinterpret_cast<const float4*>(g + lane*4);
  float4 bv = *reinterpret_cast<const float4*>(b + lane*4);
  ushort4 o4;
  o4.x = f2bf(dx0*rs*gv.x + bv.x);
  o4.y = f2bf(dx1*rs*gv.y + bv.y);
  o4.z = f2bf(dx2*rs*gv.z + bv.z);
  o4.w = f2bf(dx3*rs*gv.w + bv.w);
  *reinterpret_cast<ushort4*>(y + (size_t)row*DIM + lane*4) = o4;
}

// ---------------- weight transpose + bf16: f32 [K][N] -> bf16 [N][K] ----------------
struct TDesc { const float* src; ushort* dst; int K; int N; };
struct TDescs { TDesc d[12]; };

__global__ __launch_bounds__(256) void transpose_conv(TDescs descs)
{
  const TDesc t = descs.d[blockIdx.z];
  const int k0 = blockIdx.x * 32, n0 = blockIdx.y * 32;
  if (k0 >= t.K || n0 >= t.N) return;
  __shared__ float tile[32][33];
  const int r = threadIdx.x >> 5, cc = threadIdx.x & 31;
  #pragma unroll
  for (int i = 0; i < 4; ++i)
    tile[r + i*8][cc] = t.src[(size_t)(k0 + r + i*8)*t.N + n0 + cc];
  __syncthreads();
  #pragma unroll
  for (int i = 0; i < 4; ++i)
    t.dst[(size_t)(n0 + r + i*8)*t.K + k0 + cc] = f2bf(tile[cc][r + i*8]);
}

// ---------------- bf16 MFMA GEMM, counted-vmcnt 3-buffer pipeline ----------------
// MODE 1: relu + bf16 out; MODE 3: qkv -> Q,K head-major + V permuted;
// MODE 4: K,V BOTH head-major.
template<int KDIM, int NDIM, int MODE>
__global__ __launch_bounds__(256) void gemm_mfma(
    const ushort* __restrict__ A, const ushort* __restrict__ Bw,
    const float* __restrict__ bias0, const float* __restrict__ bias1,
    const float* __restrict__ bias2, void* __restrict__ Cout,
    ushort* __restrict__ vtb)
{
  __shared__ ushort Al[3][64*32];
  __shared__ ushort Bl[3][128*32];
  const int bm = blockIdx.y * 64, bn = blockIdx.x * 128;
  const int tid = threadIdx.x, w = tid >> 6, lane = tid & 63;
  const int g = lane >> 4, c = lane & 15;
  const int lrow = lane >> 2, lc8 = (lane & 3) << 3;
  const f32x4 fzero = {0.f, 0.f, 0.f, 0.f};
  f32x4 acc[4][2];
  #pragma unroll
  for (int m = 0; m < 4; ++m) { acc[m][0] = fzero; acc[m][1] = fzero; }

#define STAGE(buf, k0)                                                         \
  {                                                                            \
    _Pragma("unroll")                                                          \
    for (int ch = w; ch < 12; ch += 4) {                                       \
      if (ch < 4)                                                              \
        gload_lds16(A + (size_t)(bm + ch*16 + lrow)*KDIM + (k0) + lc8,         \
                    &Al[buf][ch*512]);                                         \
      else                                                                     \
        gload_lds16(Bw + (size_t)(bn + (ch-4)*16 + lrow)*KDIM + (k0) + lc8,    \
                    &Bl[buf][(ch-4)*512]);                                     \
    }                                                                          \
  }

#define COMPUTE(buf)                                                           \
  {                                                                            \
    bf16x8 af[4], bfr[2];                                                      \
    _Pragma("unroll")                                                          \
    for (int m = 0; m < 4; ++m)                                                \
      af[m] = *(const bf16x8*)&Al[buf][(m*16 + c)*32 + g*8];                   \
    _Pragma("unroll")                                                          \
    for (int n = 0; n < 2; ++n)                                                \
      bfr[n] = *(const bf16x8*)&Bl[buf][(w*32 + n*16 + c)*32 + g*8];           \
    _Pragma("unroll")                                                          \
    for (int m = 0; m < 4; ++m)                                                \
      _Pragma("unroll")                                                        \
      for (int n = 0; n < 2; ++n)                                              \
        acc[m][n] = __builtin_amdgcn_mfma_f32_16x16x32_bf16(af[m], bfr[n], acc[m][n], 0, 0, 0); \
  }

  STAGE(0, 0);
  STAGE(1, 32);
  STAGE(2, 64);
  int buf = 0;
  for (int k0 = 0; k0 + 64 < KDIM; k0 += 32) {
    asm volatile("s_waitcnt vmcnt(6)" ::: "memory");
    __builtin_amdgcn_s_barrier();
    COMPUTE(buf);
    asm volatile("s_waitcnt lgkmcnt(0)" ::: "memory");
    __builtin_amdgcn_s_barrier();
    if (k0 + 96 < KDIM) STAGE(buf, k0 + 96);
    buf = (buf == 2) ? 0 : buf + 1;
  }
  asm volatile("s_waitcnt vmcnt(3)" ::: "memory");
  __builtin_amdgcn_s_barrier();
  COMPUTE(buf);
  buf = (buf == 2) ? 0 : buf + 1;
  asm volatile("s_waitcnt vmcnt(0)" ::: "memory");
  __builtin_amdgcn_s_barrier();
  COMPUTE(buf);
#undef STAGE
#undef COMPUTE

  #pragma unroll
  for (int m = 0; m < 4; ++m) {
    const int row0 = bm + m*16 + g*4;
    #pragma unroll
    for (int n = 0; n < 2; ++n) {
      const int col = bn + w*32 + n*16 + c;
      if (MODE == 1) {
        const float bb = bias0[col];
        #pragma unroll
        for (int r = 0; r < 4; ++r) {
          const float vv = fmaxf(acc[m][n][r] + bb, 0.f);
          const float other = __shfl_xor(vv, 1);
          if ((c & 1) == 0) {
            const uint32_t word = (uint32_t)f2bf(vv) | ((uint32_t)f2bf(other) << 16);
            *(uint32_t*)((ushort*)Cout + (size_t)(row0 + r)*NDIM + col) = word;
          }
        }
      } else if (MODE == 4) {   // K,V both head-major
        const int b_ = row0 >> 10, s = row0 & (SEQ - 1);
        const int hd = col & 255;
        const int hh = hd >> 5, d = hd & 31;
        const float bb = (col < 256) ? bias0[hd] : bias1[hd];
        ushort* dst = ((col < 256) ? (ushort*)Cout : vtb)
                    + (((size_t)(b_*NH + hh)*SEQ + s) << 5) + d;
        #pragma unroll
        for (int r = 0; r < 4; ++r) {
          const float vv = acc[m][n][r] + bb;
          const float other = __shfl_xor(vv, 1);
          if ((c & 1) == 0) {
            const uint32_t word = (uint32_t)f2bf(vv) | ((uint32_t)f2bf(other) << 16);
            *(uint32_t*)(dst + (r << 5)) = word;
          }
        }
      } else {  // MODE 3
        const int b_ = row0 >> 10, s = row0 & (SEQ - 1);
        if (col < 512) {
          const int hd = col & 255;
          const int hh = hd >> 5, d = hd & 31;
          const float bb = (col < 256) ? bias0[hd] : bias1[hd];
          ushort* dst = (ushort*)Cout + (col < 256 ? 0 : QKSTRIDE)
                      + (((size_t)(b_*NH + hh)*SEQ + s) << 5) + d;
          #pragma unroll
          for (int r = 0; r < 4; ++r) {
            const float vv = acc[m][n][r] + bb;
            const float other = __shfl_xor(vv, 1);
            if ((c & 1) == 0) {
              const uint32_t word = (uint32_t)f2bf(vv) | ((uint32_t)f2bf(other) << 16);
              *(uint32_t*)(dst + (r << 5)) = word;
            }
          }
        } else {
          const int hd = col - 512;
          const int hh = hd >> 5, d = hd & 31;
          const float bb = bias2[hd];
          const int sg = s >> 5, a = (s & 31) >> 2;
          const int pbase = (a & 3)*8 + (a >> 2)*4;
          ushort4 w4;
          w4.x = f2bf(acc[m][n][0] + bb);
          w4.y = f2bf(acc[m][n][1] + bb);
          w4.z = f2bf(acc[m][n][2] + bb);
          w4.w = f2bf(acc[m][n][3] + bb);
          *(ushort4*)(vtb + (((size_t)((b_*NH + hh)*32 + sg)*32 + d) << 5) + pbase) = w4;
        }
      }
    }
  }
}

// ---------------- 64x64-tile accumulate GEMM (N=256), counted-vmcnt 3-buffer ----------------
template<int KDIM>
__global__ __launch_bounds__(256) void gemm64_acc(
    const ushort* __restrict__ A, const ushort* __restrict__ Bw,
    const float* __restrict__ bias, float* __restrict__ C)
{
  __shared__ ushort Al[3][64*32];
  __shared__ ushort Bl[3][64*32];
  const int bm = blockIdx.y * 64, bn = blockIdx.x * 64;
  const int tid = threadIdx.x, w = tid >> 6, lane = tid & 63;
  const int wm = w >> 1, wn = w & 1;
  const int g = lane >> 4, c = lane & 15;
  const int lrow = tid >> 2, lc8 = (tid & 3) << 3;
  const f32x4 fzero = {0.f, 0.f, 0.f, 0.f};
  f32x4 acc[2][2];
  acc[0][0] = fzero; acc[0][1] = fzero; acc[1][0] = fzero; acc[1][1] = fzero;

#define STAGE64(buf, k0)                                                       \
  {                                                                            \
    gload_lds16(A  + (size_t)(bm + lrow)*KDIM + (k0) + lc8,                    \
                &Al[buf][lrow*32 + lc8]);                                      \
    gload_lds16(Bw + (size_t)(bn + lrow)*KDIM + (k0) + lc8,                    \
                &Bl[buf][lrow*32 + lc8]);                                      \
  }

#define COMPUTE64(buf)                                                         \
  {                                                                            \
    bf16x8 af[2], bfr[2];                                                      \
    _Pragma("unroll")                                                          \
    for (int m = 0; m < 2; ++m)                                                \
      af[m] = *(const bf16x8*)&Al[buf][(wm*32 + m*16 + c)*32 + g*8];           \
    _Pragma("unroll")                                                          \
    for (int n = 0; n < 2; ++n)                                                \
      bfr[n] = *(const bf16x8*)&Bl[buf][(wn*32 + n*16 + c)*32 + g*8];          \
    _Pragma("unroll")                                                          \
    for (int m = 0; m < 2; ++m)                                                \
      _Pragma("unroll")                                                        \
      for (int n = 0; n < 2; ++n)                                              \
        acc[m][n] = __builtin_amdgcn_mfma_f32_16x16x32_bf16(af[m], bfr[n], acc[m][n], 0, 0, 0); \
  }

  STAGE64(0, 0);
  STAGE64(1, 32);
  STAGE64(2, 64);
  int buf = 0;
  for (int k0 = 0; k0 + 64 < KDIM; k0 += 32) {
    asm volatile("s_waitcnt vmcnt(4)" ::: "memory");
    __builtin_amdgcn_s_barrier();
    COMPUTE64(buf);
    asm volatile("s_waitcnt lgkmcnt(0)" ::: "memory");
    __builtin_amdgcn_s_barrier();
    if (k0 + 96 < KDIM) STAGE64(buf, k0 + 96);
    buf = (buf == 2) ? 0 : buf + 1;
  }
  asm volatile("s_waitcnt vmcnt(2)" ::: "memory");
  __builtin_amdgcn_s_barrier();
  COMPUTE64(buf);
  buf = (buf == 2) ? 0 : buf + 1;
  asm volatile("s_waitcnt vmcnt(0)" ::: "memory");
  __builtin_amdgcn_s_barrier();
  COMPUTE64(buf);
#undef STAGE64
#undef COMPUTE64

  #pragma unroll
  for (int m = 0; m < 2; ++m) {
    const int row0 = bm + wm*32 + m*16 + g*4;
    #pragma unroll
    for (int n = 0; n < 2; ++n) {
      const int col = bn + wn*32 + n*16 + c;
      const float bb = bias[col];
      #pragma unroll
      for (int r = 0; r < 4; ++r)
        C[(size_t)(row0 + r)*DIM + col] += acc[m][n][r] + bb;
    }
  }
}

// ---------------- flash attention (layer 0): 64 q-rows/block, 2x2 wave split ----------------
// grid 1024 = (b,h,q64); wave w: qg = w>>1 (32 q-rows), kg = w&1 (512 keys, 8 tiles).
// Max-free base-2 softmax; bias loaded at use; combine = pure sum over 2 key-halves.
__global__ __launch_bounds__(256) void attn_mfma(
    const ushort* __restrict__ qh, const ushort* __restrict__ kh,
    const ushort* __restrict__ vph, const float* __restrict__ bm2l,
    ushort* __restrict__ O)
{
  const int bid = blockIdx.x;
  const int lin = ((bid & 7) << 7) + (bid >> 3);       // bijective (1024 % 8 == 0)
  const int tid = threadIdx.x, w = tid >> 6, lane = tid & 63;
  const int q64 = lin & 15, h = (lin >> 4) & 7, b = lin >> 7;
  const int qg = w >> 1, kg = w & 1;
  const int qb = (q64 << 6) + (qg << 5);
  const float scale2 = 0.17677669529663687f * 1.4426950408889634f;  // rsqrt(32)*log2e
  const int g = lane >> 4, c = lane & 15;
  const f32x4 fzero = {0.f, 0.f, 0.f, 0.f};
  const size_t bh = (size_t)(b*NH + h);

  const bf16x8 qf0 = *(const bf16x8*)(qh + ((bh*SEQ + qb + c)      << 5) + g*8);
  const bf16x8 qf1 = *(const bf16x8*)(qh + ((bh*SEQ + qb + 16 + c) << 5) + g*8);
  const ushort* kbase = kh  + ((bh*SEQ) << 5) + g*8;
  const ushort* vbase = vph + ((bh*SEQ) << 5) + g*8;
  const float*  bmb   = bm2l + b*SEQ;

  f32x4 oacc[2][2];
  oacc[0][0] = fzero; oacc[0][1] = fzero; oacc[1][0] = fzero; oacc[1][1] = fzero;
  float l0 = 0.f, l1 = 0.f;

  bf16x8 kfA[4], kfB[4];
  bf16x8 vfA[2][2], vfB[2][2];

#define LOADT(kt, kf, vf)                                                      \
  {                                                                            \
    _Pragma("unroll")                                                          \
    for (int ks = 0; ks < 4; ++ks)                                             \
      kf[ks] = *(const bf16x8*)(kbase + (((kt) + ks*16 + c) << 5));            \
    _Pragma("unroll")                                                          \
    for (int ds_ = 0; ds_ < 2; ++ds_)                                          \
      _Pragma("unroll")                                                        \
      for (int sg = 0; sg < 2; ++sg)                                           \
        vf[ds_][sg] = *(const bf16x8*)(vbase +                                 \
            (((((kt) >> 5) + sg)*32 + ds_*16 + c) << 5));                      \
  }

#define ATILE(kf, vf, kt)                                                      \
  {                                                                            \
    f32x4 sf0[4], sf1[4];                                                      \
    __builtin_amdgcn_s_setprio(1);                                             \
    _Pragma("unroll")                                                          \
    for (int ks = 0; ks < 4; ++ks)                                             \
      sf0[ks] = __builtin_amdgcn_mfma_f32_16x16x32_bf16(kf[ks], qf0, fzero, 0, 0, 0); \
    _Pragma("unroll")                                                          \
    for (int ks = 0; ks < 4; ++ks)                                             \
      sf1[ks] = __builtin_amdgcn_mfma_f32_16x16x32_bf16(kf[ks], qf1, fzero, 0, 0, 0); \
    __builtin_amdgcn_s_setprio(0);                                             \
    float e0[4][4], e1[4][4];                                                  \
    _Pragma("unroll")                                                          \
    for (int ks = 0; ks < 4; ++ks) {                                           \
      const f32x4 bb = *(const f32x4*)(bmb + (kt) + ks*16 + g*4);              \
      _Pragma("unroll")                                                        \
      for (int r = 0; r < 4; ++r) {                                            \
        e0[ks][r] = exp2_n(fmaf(sf0[ks][r], scale2, bb[r]));                   \
        e1[ks][r] = exp2_n(fmaf(sf1[ks][r], scale2, bb[r]));                   \
      }                                                                        \
    }                                                                          \
    float a0 = 0.f, a1 = 0.f, a2 = 0.f, a3 = 0.f;                              \
    _Pragma("unroll")                                                          \
    for (int r = 0; r < 4; ++r) {                                              \
      a0 += e0[0][r] + e0[1][r]; a1 += e0[2][r] + e0[3][r];                    \
      a2 += e1[0][r] + e1[1][r]; a3 += e1[2][r] + e1[3][r];                    \
    }                                                                          \
    l0 += a0 + a1; l1 += a2 + a3;                                              \
    union { bf16x8 v; uint32_t u[4]; } p00, p01, p10, p11;                     \
    p00.u[0] = cvtpk(e0[0][0], e0[0][1]); p00.u[1] = cvtpk(e0[0][2], e0[0][3]);\
    p00.u[2] = cvtpk(e0[1][0], e0[1][1]); p00.u[3] = cvtpk(e0[1][2], e0[1][3]);\
    p01.u[0] = cvtpk(e0[2][0], e0[2][1]); p01.u[1] = cvtpk(e0[2][2], e0[2][3]);\
    p01.u[2] = cvtpk(e0[3][0], e0[3][1]); p01.u[3] = cvtpk(e0[3][2], e0[3][3]);\
    p10.u[0] = cvtpk(e1[0][0], e1[0][1]); p10.u[1] = cvtpk(e1[0][2], e1[0][3]);\
    p10.u[2] = cvtpk(e1[1][0], e1[1][1]); p10.u[3] = cvtpk(e1[1][2], e1[1][3]);\
    p11.u[0] = cvtpk(e1[2][0], e1[2][1]); p11.u[1] = cvtpk(e1[2][2], e1[2][3]);\
    p11.u[2] = cvtpk(e1[3][0], e1[3][1]); p11.u[3] = cvtpk(e1[3][2], e1[3][3]);\
    __builtin_amdgcn_s_setprio(1);                                             \
    oacc[0][0] = __builtin_amdgcn_mfma_f32_16x16x32_bf16(vf[0][0], p00.v, oacc[0][0], 0, 0, 0); \
    oacc[0][1] = __builtin_amdgcn_mfma_f32_16x16x32_bf16(vf[1][0], p00.v, oacc[0][1], 0, 0, 0); \
    oacc[1][0] = __builtin_amdgcn_mfma_f32_16x16x32_bf16(vf[0][0], p10.v, oacc[1][0], 0, 0, 0); \
    oacc[1][1] = __builtin_amdgcn_mfma_f32_16x16x32_bf16(vf[1][0], p10.v, oacc[1][1], 0, 0, 0); \
    oacc[0][0] = __builtin_amdgcn_mfma_f32_16x16x32_bf16(vf[0][1], p01.v, oacc[0][0], 0, 0, 0); \
    oacc[0][1] = __builtin_amdgcn_mfma_f32_16x16x32_bf16(vf[1][1], p01.v, oacc[0][1], 0, 0, 0); \
    oacc[1][0] = __builtin_amdgcn_mfma_f32_16x16x32_bf16(vf[0][1], p11.v, oacc[1][0], 0, 0, 0); \
    oacc[1][1] = __builtin_amdgcn_mfma_f32_16x16x32_bf16(vf[1][1], p11.v, oacc[1][1], 0, 0, 0); \
    __builtin_amdgcn_s_setprio(0);                                             \
  }

  const int kt0 = kg << 9;          // 512 keys per wave, 8 tiles
  LOADT(kt0, kfA, vfA);
  for (int kt = kt0; kt < kt0 + 512; kt += 128) {
    LOADT(kt + 64, kfB, vfB);
    ATILE(kfA, vfA, kt);
    if (kt + 128 < kt0 + 512) LOADT(kt + 128, kfA, vfA);
    ATILE(kfB, vfB, kt + 64);
  }
#undef LOADT
#undef ATILE

  // combine the 2 key-halves per q-group (pure sums)
  __shared__ float Lo[4][64][19];
  #pragma unroll
  for (int q = 0; q < 2; ++q)
    #pragma unroll
    for (int ds_ = 0; ds_ < 2; ++ds_)
      #pragma unroll
      for (int i = 0; i < 4; ++i)
        Lo[w][lane][q*8 + ds_*4 + i] = oacc[q][ds_][i];
  Lo[w][lane][16] = l0;
  Lo[w][lane][17] = l1;
  __syncthreads();
  if (w < 2) {
    const int qgv = w;               // this wave finalizes q-group qgv
    const int w0i = qgv*2, w1i = qgv*2 + 1;
    #pragma unroll
    for (int q = 0; q < 2; ++q) {
      float o[8];
      #pragma unroll
      for (int i = 0; i < 8; ++i)
        o[i] = Lo[w0i][lane][q*8 + i] + Lo[w1i][lane][q*8 + i];
      float ls = Lo[w0i][lane][16 + q] + Lo[w1i][lane][16 + q];
      ls += __shfl_xor(ls, 16);
      ls += __shfl_xor(ls, 32);
      const float inv = 1.f / ls;
      const int row = (q64 << 6) + (qgv << 5) + q*16 + c;
      ushort* orow = O + (size_t)(b*SEQ + row)*DIM + h*32 + g*4;
      const uint32_t w0 = (uint32_t)f2bf(o[0]*inv) | ((uint32_t)f2bf(o[1]*inv) << 16);
      const uint32_t w1 = (uint32_t)f2bf(o[2]*inv) | ((uint32_t)f2bf(o[3]*inv) << 16);
      const uint32_t w2 = (uint32_t)f2bf(o[4]*inv) | ((uint32_t)f2bf(o[5]*inv) << 16);
      const uint32_t w3 = (uint32_t)f2bf(o[6]*inv) | ((uint32_t)f2bf(o[7]*inv) << 16);
      *(uint32_t*)(orow)      = w0;
      *(uint32_t*)(orow + 2)  = w1;
      *(uint32_t*)(orow + 16) = w2;
      *(uint32_t*)(orow + 18) = w3;
    }
  }
}

// ---------------- layer-2 decode attention, 4-way key split (partials) ----------------
__global__ __launch_bounds__(256) void decode512(
    const ushort* __restrict__ x2b, const ushort* __restrict__ Wq1,
    const float* __restrict__ bq1, const ushort* __restrict__ kh,
    const ushort* __restrict__ vh, const float* __restrict__ bm2l,
    float* __restrict__ P)
{
  const int lin = blockIdx.x;
  const int ks = lin & 3, bh = lin >> 2;
  const int b = bh >> 3, h = bh & 7;
  const int tid = threadIdx.x;
  const float scale2 = 0.17677669529663687f * 1.4426950408889634f;
  __shared__ float xrow[256];
  __shared__ float qv[32];
  xrow[tid] = bf2f(x2b[(size_t)(b*SEQ)*DIM + tid]);
  __syncthreads();
  if (tid < 32) {
    const ushort* wrow = Wq1 + (size_t)(h*32 + tid)*DIM;
    float acc = bq1[h*32 + tid];
    #pragma unroll
    for (int k8 = 0; k8 < 32; ++k8) {
      const bf16x8 wv = *(const bf16x8*)(wrow + k8*8);
      #pragma unroll
      for (int j = 0; j < 8; ++j)
        acc = fmaf(bf2f((ushort)wv[j]), xrow[k8*8 + j], acc);
    }
    qv[tid] = acc;
  }
  __syncthreads();
  const int key = ks*256 + tid;
  const ushort* kr = kh + (((size_t)bh*SEQ + key) << 5);
  float dot = 0.f;
  #pragma unroll
  for (int i = 0; i < 4; ++i) {
    const bf16x8 kv8 = *(const bf16x8*)(kr + i*8);
    #pragma unroll
    for (int j = 0; j < 8; ++j)
      dot = fmaf(bf2f((ushort)kv8[j]), qv[i*8 + j], dot);
  }
  const float e = exp2_n(fmaf(dot, scale2, bm2l[b*SEQ + key]));
  const ushort* vr = vh + (((size_t)bh*SEQ + key) << 5);
  __shared__ float red[256][33];
  #pragma unroll
  for (int i = 0; i < 4; ++i) {
    const bf16x8 vv8 = *(const bf16x8*)(vr + i*8);
    #pragma unroll
    for (int j = 0; j < 8; ++j)
      red[tid][i*8 + j] = e * bf2f((ushort)vv8[j]);
  }
  red[tid][32] = e;
  __syncthreads();
  for (int s = 128; s >= 1; s >>= 1) {
    for (int i = tid; i < s*33; i += 256) {
      const int r = i / 33, d = i - r*33;
      red[r][d] += red[r + s][d];
    }
    __syncthreads();
  }
  if (tid < 33) P[((size_t)bh*4 + ks)*33 + tid] = red[0][tid];
}

// ---------------- Wo GEMV, weight-stationary: grid 64, block = 4 cols x 8 batches ----------------
__global__ __launch_bounds__(256) void wo_part(
    const float* __restrict__ P, const ushort* __restrict__ WoT1,
    const float* __restrict__ bo1, float* __restrict__ wo_out)
{
  const int cc = blockIdx.x, tid = threadIdx.x;
  __shared__ float orow[8][256];
  {
    const int b = tid >> 5, d32 = tid & 31;
    #pragma unroll
    for (int h = 0; h < 8; ++h) {
      const float* pp = P + ((size_t)(b*8 + h)*4)*33;
      float ov = 0.f, l = 0.f;
      #pragma unroll
      for (int ks = 0; ks < 4; ++ks) { ov += pp[ks*33 + d32]; l += pp[ks*33 + 32]; }
      orow[b][h*32 + d32] = ov / l;
    }
  }
  __syncthreads();
  const int w = tid >> 6, lane = tid & 63;
  const int col = cc*4 + w;
  const ushort* wrow = WoT1 + (size_t)col*DIM + lane*4;
  float wk[4];
  #pragma unroll
  for (int j = 0; j < 4; ++j) wk[j] = bf2f(wrow[j]);
  #pragma unroll
  for (int b = 0; b < 8; ++b) {
    float p = 0.f;
    #pragma unroll
    for (int j = 0; j < 4; ++j) p = fmaf(wk[j], orow[b][lane*4 + j], p);
    #pragma unroll
    for (int off = 32; off >= 1; off >>= 1) p += __shfl_xor(p, off);
    if (lane == 0) wo_out[b*DIM + col] = p + bo1[col];
  }
}

// ---------------- FF1 GEMV + in-block residual/LN2: grid 64, block = 16 cols x 8 batches ----------------
__global__ __launch_bounds__(256) void ff1_part(
    const float* __restrict__ x, const float* __restrict__ wo_out,
    const float* __restrict__ g21, const float* __restrict__ be21,
    const ushort* __restrict__ W1T1, const float* __restrict__ b11,
    float* __restrict__ mid)
{
  const int cc = blockIdx.x, tid = threadIdx.x;
  const int wave = tid >> 6, lane = tid & 63;
  __shared__ float trow[8][256];
  #pragma unroll
  for (int b = 0; b < 8; ++b)
    trow[b][tid] = x[(size_t)(b*SEQ)*DIM + tid] + wo_out[b*DIM + tid];
  __syncthreads();
  #pragma unroll
  for (int bb_ = 0; bb_ < 2; ++bb_) {
    const int b = wave + bb_*4;
    float4 vv = *(float4*)&trow[b][lane*4];
    float sm = vv.x + vv.y + vv.z + vv.w;
    #pragma unroll
    for (int o = 32; o >= 1; o >>= 1) sm += __shfl_xor(sm, o);
    const float mean = sm * (1.f/256.f);
    const float dx0 = vv.x-mean, dx1 = vv.y-mean, dx2 = vv.z-mean, dx3 = vv.w-mean;
    float q = dx0*dx0 + dx1*dx1 + dx2*dx2 + dx3*dx3;
    #pragma unroll
    for (int o = 32; o >= 1; o >>= 1) q += __shfl_xor(q, o);
    const float rs = rsqrtf(q * (1.f/256.f) + 1e-5f);
    const float4 gv = *(const float4*)(g21 + lane*4);
    const float4 bv = *(const float4*)(be21 + lane*4);
    float4 nv;
    nv.x = dx0*rs*gv.x + bv.x;
    nv.y = dx1*rs*gv.y + bv.y;
    nv.z = dx2*rs*gv.z + bv.z;
    nv.w = dx3*rs*gv.w + bv.w;
    *(float4*)&trow[b][lane*4] = nv;
  }
  __syncthreads();
  const int dotid = tid >> 1;
  const int col = cc*16 + (dotid & 15);
  const int b = dotid >> 4;
  const int kh_ = (tid & 1) * 128;
  const ushort* wrow = W1T1 + (size_t)col*DIM + kh_;
  float acc = 0.f;
  #pragma unroll
  for (int k8 = 0; k8 < 16; ++k8) {
    const bf16x8 wv = *(const bf16x8*)(wrow + k8*8);
    #pragma unroll
    for (int j = 0; j < 8; ++j)
      acc = fmaf(bf2f((ushort)wv[j]), trow[b][kh_ + k8*8 + j], acc);
  }
  acc += __shfl_xor(acc, 1);
  if ((tid & 1) == 0) mid[b*FFD + col] = fmaxf(acc + b11[col], 0.f);
}

// ---------------- FF2 GEMV + residual: grid 64, block = 4 cols x 8 batches ----------------
__global__ __launch_bounds__(256) void ff2_part(
    const float* __restrict__ mid, const ushort* __restrict__ W2T1,
    const float* __restrict__ b21, const float* __restrict__ x,
    const float* __restrict__ wo_out, float* __restrict__ y2)
{
  const int cc = blockIdx.x, tid = threadIdx.x;
  __shared__ float mrow[8][1024];
  #pragma unroll
  for (int i = 0; i < 32; ++i) {
    const int idx = i*256 + tid;
    mrow[idx >> 10][idx & 1023] = mid[idx];
  }
  __syncthreads();
  const int dotid = tid >> 3;
  const int col = cc*4 + (dotid & 3);
  const int b = dotid >> 2;
  const int seg = (tid & 7) * 128;
  const ushort* wrow = W2T1 + (size_t)col*FFD + seg;
  float acc = 0.f;
  #pragma unroll
  for (int k8 = 0; k8 < 16; ++k8) {
    const bf16x8 wv = *(const bf16x8*)(wrow + k8*8);
    #pragma unroll
    for (int j = 0; j < 8; ++j)
      acc = fmaf(bf2f((ushort)wv[j]), mrow[b][seg + k8*8 + j], acc);
  }
  acc += __shfl_xor(acc, 1);
  acc += __shfl_xor(acc, 2);
  acc += __shfl_xor(acc, 4);
  if ((tid & 7) == 0)
    y2[b*DIM + col] = x[(size_t)(b*SEQ)*DIM + col] + wo_out[b*DIM + col]
                    + acc + b21[col];
}

// ---------------- final LN + classifier on y2 rows (grid 8) ----------------
__global__ __launch_bounds__(256) void cls2(
    const float* __restrict__ y2, const float* __restrict__ gf,
    const float* __restrict__ bfb, const float* __restrict__ Wc,
    const float* __restrict__ bc, float* __restrict__ out)
{
  const int b = blockIdx.x, tid = threadIdx.x;
  const int wave = tid >> 6, lane = tid & 63;
  const float v = y2[b*DIM + tid];
  __shared__ float redm[4], redv[4], redc[4][4];
  float s = v;
  #pragma unroll
  for (int o = 32; o >= 1; o >>= 1) s += __shfl_xor(s, o);
  if (lane == 0) redm[wave] = s;
  __syncthreads();
  const float mean = (redm[0]+redm[1]+redm[2]+redm[3]) * (1.f/256.f);
  const float dv = v - mean;
  float q = dv * dv;
  #pragma unroll
  for (int o = 32; o >= 1; o >>= 1) q += __shfl_xor(q, o);
  if (lane == 0) redv[wave] = q;
  __syncthreads();
  const float var = (redv[0]+redv[1]+redv[2]+redv[3]) * (1.f/256.f);
  const float rs = rsqrtf(var + 1e-5f);
  const float yn = dv*rs*gf[tid] + bfb[tid];
  float pc[4];
  #pragma unroll
  for (int cc = 0; cc < 4; ++cc) pc[cc] = yn * Wc[tid*4 + cc];
  #pragma unroll
  for (int cc = 0; cc < 4; ++cc) {
    #pragma unroll
    for (int o = 32; o >= 1; o >>= 1) pc[cc] += __shfl_xor(pc[cc], o);
  }
  if (lane == 0) {
    #pragma unroll
    for (int cc = 0; cc < 4; ++cc) redc[wave][cc] = pc[cc];
  }
  __syncthreads();
  if (tid < 4)
    out[b*4 + tid] = redc[0][tid] + redc[1][tid] + redc[2][tid] + redc[3][tid] + bc[tid];
}

extern "C" void kernel_launch(void* const* d_in, const int* in_sizes, int n_in,
                              void* d_out, int out_size, void* d_ws, size_t ws_size,
                              hipStream_t stream)
{
  const int*   ids    = (const int*)d_in[0];
  const int*   ngrams = (const int*)d_in[1];
  const float* tfidf  = (const float*)d_in[2];
  const float* emb    = (const float*)d_in[3];
  const float* pos    = (const float*)d_in[4];
  const float* bucket = (const float*)d_in[5];
  const float* Wq = (const float*)d_in[6];  const float* bq = (const float*)d_in[7];
  const float* Wk = (const float*)d_in[8];  const float* bk = (const float*)d_in[9];
  const float* Wv = (const float*)d_in[10]; const float* bv = (const float*)d_in[11];
  const float* Wo = (const float*)d_in[12]; const float* bo = (const float*)d_in[13];
  const float* g1 = (const float*)d_in[14]; const float* be1= (const float*)d_in[15];
  const float* g2 = (const float*)d_in[16]; const float* be2= (const float*)d_in[17];
  const float* W1 = (const float*)d_in[18]; const float* b1 = (const float*)d_in[19];
  const float* W2 = (const float*)d_in[20]; const float* b2 = (const float*)d_in[21];
  const float* alpha = (const float*)d_in[22];
  const float* gf = (const float*)d_in[23]; const float* bf = (const float*)d_in[24];
  const float* Wc = (const float*)d_in[25]; const float* bc = (const float*)d_in[26];

  uint8_t* base = (uint8_t*)d_ws;
  float*  x      = (float*)  base;                  //  8,388,608
  ushort* x2b    = (ushort*)(base + 8388608);       //  4,194,304
  ushort* qkh    = (ushort*)(base + 12582912);      //  8,388,608 (Q head-major, K at +QKSTRIDE)
  ushort* vtb    = (ushort*)(base + 20971520);      //  4,194,304 (V permuted l0 / V head-major l1)
  ushort* attb   = (ushort*)(base + 25165824);      //  4,194,304 (l0 attn out; later tail scratch)
  ushort* midb   = (ushort*)(base + 29360128);      // 16,777,216
  float*  bm2    = (float*) (base + 46137344);      //     65,536 (2 layers)
  ushort* WqkvT  = (ushort*)(base + 46202880);      //    786,432
  ushort* WoT    = (ushort*)(base + 46989312);      //    262,144
  ushort* W1T    = (ushort*)(base + 47251456);      //  1,048,576
  ushort* W2T    = (ushort*)(base + 48300032);      //  1,048,576  -> 49,348,608 total

  // tail scratch carved from attb region (dead after gemm64_acc<256> of layer 0)
  float* P       = (float*)(base + 25165824);            // 33,792 B
  float* wo_out  = (float*)(base + 25165824 + 65536);    // 8 KB
  float* midf    = (float*)(base + 25165824 + 90112);    // 32 KB
  float* y2      = (float*)(base + 25165824 + 122880);   // 8 KB

  TDescs td;
  for (int l = 0; l < NL; ++l) {
    td.d[6*l+0] = { Wq + (size_t)l*DIM*DIM, WqkvT + (size_t)l*768*DIM +   0*DIM, DIM, DIM };
    td.d[6*l+1] = { Wk + (size_t)l*DIM*DIM, WqkvT + (size_t)l*768*DIM + 256*DIM, DIM, DIM };
    td.d[6*l+2] = { Wv + (size_t)l*DIM*DIM, WqkvT + (size_t)l*768*DIM + 512*DIM, DIM, DIM };
    td.d[6*l+3] = { Wo + (size_t)l*DIM*DIM, WoT  + (size_t)l*DIM*DIM,  DIM, DIM };
    td.d[6*l+4] = { W1 + (size_t)l*DIM*FFD, W1T  + (size_t)l*FFD*DIM,  DIM, FFD };
    td.d[6*l+5] = { W2 + (size_t)l*FFD*DIM, W2T  + (size_t)l*DIM*FFD,  FFD, DIM };
  }
  transpose_conv<<<dim3(32, 32, 12), 256, 0, stream>>>(td);

  embed_ln_kernel<<<TOK/4, 256, 0, stream>>>(
      ids, ngrams, tfidf, emb, pos, bucket, alpha, g1, be1, x, x2b, bm2);

  const dim3 gqkv(6, TOK/64), gkv(4, TOK/64), gff1(8, TOK/64), g64(4, TOK/64);

  // ---------- layer 0: full pipeline ----------
  gemm_mfma<256, 768, 3><<<gqkv, 256, 0, stream>>>(
      x2b, WqkvT, bq, bk, bv, qkh, vtb);
  attn_mfma<<<1024, 256, 0, stream>>>(qkh, qkh + QKSTRIDE, vtb, bm2, attb);
  gemm64_acc<256><<<g64, 256, 0, stream>>>(attb, WoT, bo, x);
  ln_bf16<<<TOK/4, 256, 0, stream>>>(x, g2, be2, x2b);
  gemm_mfma<256, 1024, 1><<<gff1, 256, 0, stream>>>(
      x2b, W1T, b1, nullptr, nullptr, midb, nullptr);
  gemm64_acc<1024><<<g64, 256, 0, stream>>>(midb, W2T, b2, x);

  // ---------- layer 1: only row 0 per batch feeds the output ----------
  ln_bf16<<<TOK/4, 256, 0, stream>>>(x, g1 + DIM, be1 + DIM, x2b);
  gemm_mfma<256, 512, 4><<<gkv, 256, 0, stream>>>(
      x2b, WqkvT + (size_t)768*DIM + 256*DIM, bk + DIM, bv + DIM, nullptr,
      qkh + QKSTRIDE, vtb);
  decode512<<<256, 256, 0, stream>>>(
      x2b, WqkvT + (size_t)768*DIM, bq + DIM,
      qkh + QKSTRIDE, vtb, bm2 + TOK, P);
  wo_part<<<64, 256, 0, stream>>>(P, WoT + DIM*DIM, bo + DIM, wo_out);
  ff1_part<<<64, 256, 0, stream>>>(x, wo_out, g2 + DIM, be2 + DIM,
                                   W1T + FFD*DIM, b1 + FFD, midf);
  ff2_part<<<64, 256, 0, stream>>>(midf, W2T + DIM*FFD, b2 + DIM, x, wo_out, y2);
  cls2<<<8, 256, 0, stream>>>(y2, gf, bf, Wc, bc, (float*)d_out);
}

// Round 17
// 138.914 us; speedup vs baseline: 1.3618x; 1.0098x over previous
//
#include <hip/hip_runtime.h>
#include <hip/hip_bf16.h>
#include <math.h>

#define TOK 8192       // B*S
#define DIM 256
#define SEQ 1024
#define NH 8
#define FFD 1024
#define NL 2
#define VOCAB 32000
#define QKSTRIDE 2097152   // elems between Q and K head-major blocks

typedef short bf16x8 __attribute__((ext_vector_type(8)));
typedef float f32x4 __attribute__((ext_vector_type(4)));

__device__ __forceinline__ ushort f2bf(float f) {
  union { float f; uint32_t u; } v; v.f = f;
  uint32_t r = v.u + 0x7FFFu + ((v.u >> 16) & 1u);
  return (ushort)(r >> 16);
}

__device__ __forceinline__ float bf2f(ushort u) {
  union { uint32_t u; float f; } v; v.u = (uint32_t)u << 16; return v.f;
}

__device__ __forceinline__ float exp2_n(float x) {
  float r; asm("v_exp_f32 %0, %1" : "=v"(r) : "v"(x)); return r;
}

__device__ __forceinline__ uint32_t cvtpk(float lo, float hi) {
  uint32_t r; asm("v_cvt_pk_bf16_f32 %0, %1, %2" : "=v"(r) : "v"(lo), "v"(hi));
  return r;
}

__device__ __forceinline__ void gload_lds16(const ushort* gp, ushort* lp) {
  __builtin_amdgcn_global_load_lds(
      (const __attribute__((address_space(1))) void*)gp,
      (__attribute__((address_space(3))) void*)lp, 16, 0, 0);
}

// ---------------- embedding + ngram + tfidf bias + fused layer-0 LN ----------------
__global__ __launch_bounds__(256) void embed_ln_kernel(
    const int* __restrict__ ids, const int* __restrict__ ngram_ids,
    const float* __restrict__ tfidf, const float* __restrict__ emb,
    const float* __restrict__ pos, const float* __restrict__ bucket,
    const float* __restrict__ alpha, const float* __restrict__ g1,
    const float* __restrict__ be1,
    float* __restrict__ x, ushort* __restrict__ x2b, float* __restrict__ bm2)
{
  __shared__ int ngs[4][12];
  const int wave = threadIdx.x >> 6, lane = threadIdx.x & 63;
  const int t = blockIdx.x * 4 + wave;
  const int id = ids[t];
  int idc = id; if (idc < 0) idc = 0; if (idc > VOCAB-1) idc = VOCAB-1;
  if (lane < 12) ngs[wave][lane] = ngram_ids[idc*12 + lane];
  if (lane == 0) {
    const float tf = tfidf[idc];
    const bool msk = (id == 0);
    const float l2e = 1.4426950408889634f;
    bm2[t]       = msk ? -1e30f : tf * alpha[0] * l2e;
    bm2[TOK + t] = msk ? -1e30f : tf * alpha[1] * l2e;
  }
  __syncthreads();
  const int d0 = lane * 4;
  const int s = t & (SEQ - 1);
  float4 v = *reinterpret_cast<const float4*>(emb + (size_t)id*DIM + d0);
  const float4 p4 = *reinterpret_cast<const float4*>(pos + s*DIM + d0);
  v.x += p4.x; v.y += p4.y; v.z += p4.z; v.w += p4.w;
  float4 sum = {0.f, 0.f, 0.f, 0.f}; int cnt = 0;
  #pragma unroll
  for (int g = 0; g < 12; ++g) {
    const int ng = ngs[wave][g];
    if (ng != 0) {
      const float4 b4 = *reinterpret_cast<const float4*>(bucket + (size_t)ng*DIM + d0);
      sum.x += b4.x; sum.y += b4.y; sum.z += b4.z; sum.w += b4.w;
      cnt++;
    }
  }
  const float inv = 1.f / fmaxf((float)cnt, 1.0f);
  v.x += sum.x*inv; v.y += sum.y*inv; v.z += sum.z*inv; v.w += sum.w*inv;
  *reinterpret_cast<float4*>(x + (size_t)t*DIM + d0) = v;
  float sm = v.x + v.y + v.z + v.w;
  #pragma unroll
  for (int o = 32; o >= 1; o >>= 1) sm += __shfl_xor(sm, o);
  const float mean = sm * (1.f/256.f);
  const float dx0 = v.x-mean, dx1 = v.y-mean, dx2 = v.z-mean, dx3 = v.w-mean;
  float q = dx0*dx0 + dx1*dx1 + dx2*dx2 + dx3*dx3;
  #pragma unroll
  for (int o = 32; o >= 1; o >>= 1) q += __shfl_xor(q, o);
  const float rs = rsqrtf(q * (1.f/256.f) + 1e-5f);
  const float4 gv = *reinterpret_cast<const float4*>(g1 + d0);
  const float4 bv = *reinterpret_cast<const float4*>(be1 + d0);
  ushort4 o4;
  o4.x = f2bf(dx0*rs*gv.x + bv.x);
  o4.y = f2bf(dx1*rs*gv.y + bv.y);
  o4.z = f2bf(dx2*rs*gv.z + bv.z);
  o4.w = f2bf(dx3*rs*gv.w + bv.w);
  *reinterpret_cast<ushort4*>(x2b + (size_t)t*DIM + d0) = o4;
}

// ---------------- layernorm -> bf16 ----------------
__global__ __launch_bounds__(256) void ln_bf16(
    const float* __restrict__ x, const float* __restrict__ g,
    const float* __restrict__ b, ushort* __restrict__ y)
{
  const int wave = threadIdx.x >> 6, lane = threadIdx.x & 63;
  const int row = blockIdx.x * 4 + wave;
  const float* xr = x + (size_t)row * DIM;
  float4 v = *reinterpret_cast<const float4*>(xr + lane*4);
  float s = v.x + v.y + v.z + v.w;
  #pragma unroll
  for (int o = 32; o >= 1; o >>= 1) s += __shfl_xor(s, o);
  const float mean = s * (1.f/256.f);
  const float dx0 = v.x-mean, dx1 = v.y-mean, dx2 = v.z-mean, dx3 = v.w-mean;
  float q = dx0*dx0 + dx1*dx1 + dx2*dx2 + dx3*dx3;
  #pragma unroll
  for (int o = 32; o >= 1; o >>= 1) q += __shfl_xor(q, o);
  const float rs = rsqrtf(q * (1.f/256.f) + 1e-5f);
  float4 gv = *reinterpret_cast<const float4*>(g + lane*4);
  float4 bv = *reinterpret_cast<const float4*>(b + lane*4);
  ushort4 o4;
  o4.x = f2bf(dx0*rs*gv.x + bv.x);
  o4.y = f2bf(dx1*rs*gv.y + bv.y);
  o4.z = f2bf(dx2*rs*gv.z + bv.z);
  o4.w = f2bf(dx3*rs*gv.w + bv.w);
  *reinterpret_cast<ushort4*>(y + (size_t)row*DIM + lane*4) = o4;
}

// ---------------- weight transpose + bf16: f32 [K][N] -> bf16 [N][K] ----------------
struct TDesc { const float* src; ushort* dst; int K; int N; };
struct TDescs { TDesc d[12]; };

__global__ __launch_bounds__(256) void transpose_conv(TDescs descs)
{
  const TDesc t = descs.d[blockIdx.z];
  const int k0 = blockIdx.x * 32, n0 = blockIdx.y * 32;
  if (k0 >= t.K || n0 >= t.N) return;
  __shared__ float tile[32][33];
  const int r = threadIdx.x >> 5, cc = threadIdx.x & 31;
  #pragma unroll
  for (int i = 0; i < 4; ++i)
    tile[r + i*8][cc] = t.src[(size_t)(k0 + r + i*8)*t.N + n0 + cc];
  __syncthreads();
  #pragma unroll
  for (int i = 0; i < 4; ++i)
    t.dst[(size_t)(n0 + r + i*8)*t.K + k0 + cc] = f2bf(tile[cc][r + i*8]);
}

// ---------------- bf16 MFMA GEMM, counted-vmcnt 3-buffer pipeline ----------------
// MODE 1: relu + bf16 out; MODE 3: qkv -> Q,K head-major + V permuted;
// MODE 4: K,V BOTH head-major.
template<int KDIM, int NDIM, int MODE>
__global__ __launch_bounds__(256) void gemm_mfma(
    const ushort* __restrict__ A, const ushort* __restrict__ Bw,
    const float* __restrict__ bias0, const float* __restrict__ bias1,
    const float* __restrict__ bias2, void* __restrict__ Cout,
    ushort* __restrict__ vtb)
{
  __shared__ ushort Al[3][64*32];
  __shared__ ushort Bl[3][128*32];
  const int bm = blockIdx.y * 64, bn = blockIdx.x * 128;
  const int tid = threadIdx.x, w = tid >> 6, lane = tid & 63;
  const int g = lane >> 4, c = lane & 15;
  const int lrow = lane >> 2, lc8 = (lane & 3) << 3;
  const f32x4 fzero = {0.f, 0.f, 0.f, 0.f};
  f32x4 acc[4][2];
  #pragma unroll
  for (int m = 0; m < 4; ++m) { acc[m][0] = fzero; acc[m][1] = fzero; }

#define STAGE(buf, k0)                                                         \
  {                                                                            \
    _Pragma("unroll")                                                          \
    for (int ch = w; ch < 12; ch += 4) {                                       \
      if (ch < 4)                                                              \
        gload_lds16(A + (size_t)(bm + ch*16 + lrow)*KDIM + (k0) + lc8,         \
                    &Al[buf][ch*512]);                                         \
      else                                                                     \
        gload_lds16(Bw + (size_t)(bn + (ch-4)*16 + lrow)*KDIM + (k0) + lc8,    \
                    &Bl[buf][(ch-4)*512]);                                     \
    }                                                                          \
  }

#define COMPUTE(buf)                                                           \
  {                                                                            \
    bf16x8 af[4], bfr[2];                                                      \
    _Pragma("unroll")                                                          \
    for (int m = 0; m < 4; ++m)                                                \
      af[m] = *(const bf16x8*)&Al[buf][(m*16 + c)*32 + g*8];                   \
    _Pragma("unroll")                                                          \
    for (int n = 0; n < 2; ++n)                                                \
      bfr[n] = *(const bf16x8*)&Bl[buf][(w*32 + n*16 + c)*32 + g*8];           \
    _Pragma("unroll")                                                          \
    for (int m = 0; m < 4; ++m)                                                \
      _Pragma("unroll")                                                        \
      for (int n = 0; n < 2; ++n)                                              \
        acc[m][n] = __builtin_amdgcn_mfma_f32_16x16x32_bf16(af[m], bfr[n], acc[m][n], 0, 0, 0); \
  }

  STAGE(0, 0);
  STAGE(1, 32);
  STAGE(2, 64);
  int buf = 0;
  for (int k0 = 0; k0 + 64 < KDIM; k0 += 32) {
    asm volatile("s_waitcnt vmcnt(6)" ::: "memory");
    __builtin_amdgcn_s_barrier();
    COMPUTE(buf);
    asm volatile("s_waitcnt lgkmcnt(0)" ::: "memory");
    __builtin_amdgcn_s_barrier();
    if (k0 + 96 < KDIM) STAGE(buf, k0 + 96);
    buf = (buf == 2) ? 0 : buf + 1;
  }
  asm volatile("s_waitcnt vmcnt(3)" ::: "memory");
  __builtin_amdgcn_s_barrier();
  COMPUTE(buf);
  buf = (buf == 2) ? 0 : buf + 1;
  asm volatile("s_waitcnt vmcnt(0)" ::: "memory");
  __builtin_amdgcn_s_barrier();
  COMPUTE(buf);
#undef STAGE
#undef COMPUTE

  #pragma unroll
  for (int m = 0; m < 4; ++m) {
    const int row0 = bm + m*16 + g*4;
    #pragma unroll
    for (int n = 0; n < 2; ++n) {
      const int col = bn + w*32 + n*16 + c;
      if (MODE == 1) {
        const float bb = bias0[col];
        #pragma unroll
        for (int r = 0; r < 4; ++r) {
          const float vv = fmaxf(acc[m][n][r] + bb, 0.f);
          const float other = __shfl_xor(vv, 1);
          if ((c & 1) == 0) {
            const uint32_t word = (uint32_t)f2bf(vv) | ((uint32_t)f2bf(other) << 16);
            *(uint32_t*)((ushort*)Cout + (size_t)(row0 + r)*NDIM + col) = word;
          }
        }
      } else if (MODE == 4) {   // K,V both head-major
        const int b_ = row0 >> 10, s = row0 & (SEQ - 1);
        const int hd = col & 255;
        const int hh = hd >> 5, d = hd & 31;
        const float bb = (col < 256) ? bias0[hd] : bias1[hd];
        ushort* dst = ((col < 256) ? (ushort*)Cout : vtb)
                    + (((size_t)(b_*NH + hh)*SEQ + s) << 5) + d;
        #pragma unroll
        for (int r = 0; r < 4; ++r) {
          const float vv = acc[m][n][r] + bb;
          const float other = __shfl_xor(vv, 1);
          if ((c & 1) == 0) {
            const uint32_t word = (uint32_t)f2bf(vv) | ((uint32_t)f2bf(other) << 16);
            *(uint32_t*)(dst + (r << 5)) = word;
          }
        }
      } else {  // MODE 3
        const int b_ = row0 >> 10, s = row0 & (SEQ - 1);
        if (col < 512) {
          const int hd = col & 255;
          const int hh = hd >> 5, d = hd & 31;
          const float bb = (col < 256) ? bias0[hd] : bias1[hd];
          ushort* dst = (ushort*)Cout + (col < 256 ? 0 : QKSTRIDE)
                      + (((size_t)(b_*NH + hh)*SEQ + s) << 5) + d;
          #pragma unroll
          for (int r = 0; r < 4; ++r) {
            const float vv = acc[m][n][r] + bb;
            const float other = __shfl_xor(vv, 1);
            if ((c & 1) == 0) {
              const uint32_t word = (uint32_t)f2bf(vv) | ((uint32_t)f2bf(other) << 16);
              *(uint32_t*)(dst + (r << 5)) = word;
            }
          }
        } else {
          const int hd = col - 512;
          const int hh = hd >> 5, d = hd & 31;
          const float bb = bias2[hd];
          const int sg = s >> 5, a = (s & 31) >> 2;
          const int pbase = (a & 3)*8 + (a >> 2)*4;
          ushort4 w4;
          w4.x = f2bf(acc[m][n][0] + bb);
          w4.y = f2bf(acc[m][n][1] + bb);
          w4.z = f2bf(acc[m][n][2] + bb);
          w4.w = f2bf(acc[m][n][3] + bb);
          *(ushort4*)(vtb + (((size_t)((b_*NH + hh)*32 + sg)*32 + d) << 5) + pbase) = w4;
        }
      }
    }
  }
}

// ---------------- 64x64-tile accumulate GEMM (N=256), BK=64, counted-vmcnt 3-buffer ----------------
// LDS [kstep][row][32] sub-tiles (64B rows, conflict-free). 4 loads/thread/stage:
// steady wait vmcnt(8), tail 4 -> 0. K-accumulation order identical (kk ascending).
template<int KDIM>
__global__ __launch_bounds__(256) void gemm64_acc(
    const ushort* __restrict__ A, const ushort* __restrict__ Bw,
    const float* __restrict__ bias, float* __restrict__ C)
{
  __shared__ ushort Al[3][2][64][32];
  __shared__ ushort Bl[3][2][64][32];
  const int bm = blockIdx.y * 64, bn = blockIdx.x * 64;
  const int tid = threadIdx.x, w = tid >> 6, lane = tid & 63;
  const int wm = w >> 1, wn = w & 1;
  const int g = lane >> 4, c = lane & 15;
  const f32x4 fzero = {0.f, 0.f, 0.f, 0.f};
  f32x4 acc[2][2];
  acc[0][0] = fzero; acc[0][1] = fzero; acc[1][0] = fzero; acc[1][1] = fzero;

  // chunk i in [0,512): ks = i>>8, row = (i>>2)&63, c8 = (i&3)*8
  const int i0 = tid, i1 = tid + 256;
  const int ks0 = i0 >> 8, r0 = (i0 >> 2) & 63, c80 = (i0 & 3) << 3;
  const int ks1 = i1 >> 8, r1 = (i1 >> 2) & 63, c81 = (i1 & 3) << 3;

#define STAGE64(buf, k0)                                                       \
  {                                                                            \
    gload_lds16(A  + (size_t)(bm + r0)*KDIM + (k0) + ks0*32 + c80,             \
                &Al[buf][ks0][r0][c80]);                                       \
    gload_lds16(A  + (size_t)(bm + r1)*KDIM + (k0) + ks1*32 + c81,             \
                &Al[buf][ks1][r1][c81]);                                       \
    gload_lds16(Bw + (size_t)(bn + r0)*KDIM + (k0) + ks0*32 + c80,             \
                &Bl[buf][ks0][r0][c80]);                                       \
    gload_lds16(Bw + (size_t)(bn + r1)*KDIM + (k0) + ks1*32 + c81,             \
                &Bl[buf][ks1][r1][c81]);                                       \
  }

#define COMPUTE64(buf)                                                         \
  {                                                                            \
    _Pragma("unroll")                                                          \
    for (int kk = 0; kk < 2; ++kk) {                                           \
      bf16x8 af[2], bfr[2];                                                    \
      _Pragma("unroll")                                                        \
      for (int m = 0; m < 2; ++m)                                              \
        af[m] = *(const bf16x8*)&Al[buf][kk][wm*32 + m*16 + c][g*8];           \
      _Pragma("unroll")                                                        \
      for (int n = 0; n < 2; ++n)                                              \
        bfr[n] = *(const bf16x8*)&Bl[buf][kk][wn*32 + n*16 + c][g*8];          \
      _Pragma("unroll")                                                        \
      for (int m = 0; m < 2; ++m)                                              \
        _Pragma("unroll")                                                      \
        for (int n = 0; n < 2; ++n)                                            \
          acc[m][n] = __builtin_amdgcn_mfma_f32_16x16x32_bf16(af[m], bfr[n], acc[m][n], 0, 0, 0); \
    }                                                                          \
  }

  STAGE64(0, 0);
  STAGE64(1, 64);
  STAGE64(2, 128);
  int buf = 0;
  for (int k0 = 0; k0 + 128 < KDIM; k0 += 64) {
    asm volatile("s_waitcnt vmcnt(8)" ::: "memory");
    __builtin_amdgcn_s_barrier();
    COMPUTE64(buf);
    asm volatile("s_waitcnt lgkmcnt(0)" ::: "memory");
    __builtin_amdgcn_s_barrier();
    if (k0 + 192 < KDIM) STAGE64(buf, k0 + 192);
    buf = (buf == 2) ? 0 : buf + 1;
  }
  asm volatile("s_waitcnt vmcnt(4)" ::: "memory");
  __builtin_amdgcn_s_barrier();
  COMPUTE64(buf);
  buf = (buf == 2) ? 0 : buf + 1;
  asm volatile("s_waitcnt vmcnt(0)" ::: "memory");
  __builtin_amdgcn_s_barrier();
  COMPUTE64(buf);
#undef STAGE64
#undef COMPUTE64

  #pragma unroll
  for (int m = 0; m < 2; ++m) {
    const int row0 = bm + wm*32 + m*16 + g*4;
    #pragma unroll
    for (int n = 0; n < 2; ++n) {
      const int col = bn + wn*32 + n*16 + c;
      const float bb = bias[col];
      #pragma unroll
      for (int r = 0; r < 4; ++r)
        C[(size_t)(row0 + r)*DIM + col] += acc[m][n][r] + bb;
    }
  }
}

// ---------------- flash attention (layer 0): 64 q-rows/block, 2x2 wave split ----------------
__global__ __launch_bounds__(256) void attn_mfma(
    const ushort* __restrict__ qh, const ushort* __restrict__ kh,
    const ushort* __restrict__ vph, const float* __restrict__ bm2l,
    ushort* __restrict__ O)
{
  const int bid = blockIdx.x;
  const int lin = ((bid & 7) << 7) + (bid >> 3);       // bijective (1024 % 8 == 0)
  const int tid = threadIdx.x, w = tid >> 6, lane = tid & 63;
  const int q64 = lin & 15, h = (lin >> 4) & 7, b = lin >> 7;
  const int qg = w >> 1, kg = w & 1;
  const int qb = (q64 << 6) + (qg << 5);
  const float scale2 = 0.17677669529663687f * 1.4426950408889634f;  // rsqrt(32)*log2e
  const int g = lane >> 4, c = lane & 15;
  const f32x4 fzero = {0.f, 0.f, 0.f, 0.f};
  const size_t bh = (size_t)(b*NH + h);

  const bf16x8 qf0 = *(const bf16x8*)(qh + ((bh*SEQ + qb + c)      << 5) + g*8);
  const bf16x8 qf1 = *(const bf16x8*)(qh + ((bh*SEQ + qb + 16 + c) << 5) + g*8);
  const ushort* kbase = kh  + ((bh*SEQ) << 5) + g*8;
  const ushort* vbase = vph + ((bh*SEQ) << 5) + g*8;
  const float*  bmb   = bm2l + b*SEQ;

  f32x4 oacc[2][2];
  oacc[0][0] = fzero; oacc[0][1] = fzero; oacc[1][0] = fzero; oacc[1][1] = fzero;
  float l0 = 0.f, l1 = 0.f;

  bf16x8 kfA[4], kfB[4];
  bf16x8 vfA[2][2], vfB[2][2];

#define LOADT(kt, kf, vf)                                                      \
  {                                                                            \
    _Pragma("unroll")                                                          \
    for (int ks = 0; ks < 4; ++ks)                                             \
      kf[ks] = *(const bf16x8*)(kbase + (((kt) + ks*16 + c) << 5));            \
    _Pragma("unroll")                                                          \
    for (int ds_ = 0; ds_ < 2; ++ds_)                                          \
      _Pragma("unroll")                                                        \
      for (int sg = 0; sg < 2; ++sg)                                           \
        vf[ds_][sg] = *(const bf16x8*)(vbase +                                 \
            (((((kt) >> 5) + sg)*32 + ds_*16 + c) << 5));                      \
  }

#define ATILE(kf, vf, kt)                                                      \
  {                                                                            \
    f32x4 sf0[4], sf1[4];                                                      \
    __builtin_amdgcn_s_setprio(1);                                             \
    _Pragma("unroll")                                                          \
    for (int ks = 0; ks < 4; ++ks)                                             \
      sf0[ks] = __builtin_amdgcn_mfma_f32_16x16x32_bf16(kf[ks], qf0, fzero, 0, 0, 0); \
    _Pragma("unroll")                                                          \
    for (int ks = 0; ks < 4; ++ks)                                             \
      sf1[ks] = __builtin_amdgcn_mfma_f32_16x16x32_bf16(kf[ks], qf1, fzero, 0, 0, 0); \
    __builtin_amdgcn_s_setprio(0);                                             \
    float e0[4][4], e1[4][4];                                                  \
    _Pragma("unroll")                                                          \
    for (int ks = 0; ks < 4; ++ks) {                                           \
      const f32x4 bb = *(const f32x4*)(bmb + (kt) + ks*16 + g*4);              \
      _Pragma("unroll")                                                        \
      for (int r = 0; r < 4; ++r) {                                            \
        e0[ks][r] = exp2_n(fmaf(sf0[ks][r], scale2, bb[r]));                   \
        e1[ks][r] = exp2_n(fmaf(sf1[ks][r], scale2, bb[r]));                   \
      }                                                                        \
    }                                                                          \
    float a0 = 0.f, a1 = 0.f, a2 = 0.f, a3 = 0.f;                              \
    _Pragma("unroll")                                                          \
    for (int r = 0; r < 4; ++r) {                                              \
      a0 += e0[0][r] + e0[1][r]; a1 += e0[2][r] + e0[3][r];                    \
      a2 += e1[0][r] + e1[1][r]; a3 += e1[2][r] + e1[3][r];                    \
    }                                                                          \
    l0 += a0 + a1; l1 += a2 + a3;                                              \
    union { bf16x8 v; uint32_t u[4]; } p00, p01, p10, p11;                     \
    p00.u[0] = cvtpk(e0[0][0], e0[0][1]); p00.u[1] = cvtpk(e0[0][2], e0[0][3]);\
    p00.u[2] = cvtpk(e0[1][0], e0[1][1]); p00.u[3] = cvtpk(e0[1][2], e0[1][3]);\
    p01.u[0] = cvtpk(e0[2][0], e0[2][1]); p01.u[1] = cvtpk(e0[2][2], e0[2][3]);\
    p01.u[2] = cvtpk(e0[3][0], e0[3][1]); p01.u[3] = cvtpk(e0[3][2], e0[3][3]);\
    p10.u[0] = cvtpk(e1[0][0], e1[0][1]); p10.u[1] = cvtpk(e1[0][2], e1[0][3]);\
    p10.u[2] = cvtpk(e1[1][0], e1[1][1]); p10.u[3] = cvtpk(e1[1][2], e1[1][3]);\
    p11.u[0] = cvtpk(e1[2][0], e1[2][1]); p11.u[1] = cvtpk(e1[2][2], e1[2][3]);\
    p11.u[2] = cvtpk(e1[3][0], e1[3][1]); p11.u[3] = cvtpk(e1[3][2], e1[3][3]);\
    __builtin_amdgcn_s_setprio(1);                                             \
    oacc[0][0] = __builtin_amdgcn_mfma_f32_16x16x32_bf16(vf[0][0], p00.v, oacc[0][0], 0, 0, 0); \
    oacc[0][1] = __builtin_amdgcn_mfma_f32_16x16x32_bf16(vf[1][0], p00.v, oacc[0][1], 0, 0, 0); \
    oacc[1][0] = __builtin_amdgcn_mfma_f32_16x16x32_bf16(vf[0][0], p10.v, oacc[1][0], 0, 0, 0); \
    oacc[1][1] = __builtin_amdgcn_mfma_f32_16x16x32_bf16(vf[1][0], p10.v, oacc[1][1], 0, 0, 0); \
    oacc[0][0] = __builtin_amdgcn_mfma_f32_16x16x32_bf16(vf[0][1], p01.v, oacc[0][0], 0, 0, 0); \
    oacc[0][1] = __builtin_amdgcn_mfma_f32_16x16x32_bf16(vf[1][1], p01.v, oacc[0][1], 0, 0, 0); \
    oacc[1][0] = __builtin_amdgcn_mfma_f32_16x16x32_bf16(vf[0][1], p11.v, oacc[1][0], 0, 0, 0); \
    oacc[1][1] = __builtin_amdgcn_mfma_f32_16x16x32_bf16(vf[1][1], p11.v, oacc[1][1], 0, 0, 0); \
    __builtin_amdgcn_s_setprio(0);                                             \
  }

  const int kt0 = kg << 9;          // 512 keys per wave, 8 tiles
  LOADT(kt0, kfA, vfA);
  for (int kt = kt0; kt < kt0 + 512; kt += 128) {
    LOADT(kt + 64, kfB, vfB);
    ATILE(kfA, vfA, kt);
    if (kt + 128 < kt0 + 512) LOADT(kt + 128, kfA, vfA);
    ATILE(kfB, vfB, kt + 64);
  }
#undef LOADT
#undef ATILE

  // combine the 2 key-halves per q-group (pure sums)
  __shared__ float Lo[4][64][19];
  #pragma unroll
  for (int q = 0; q < 2; ++q)
    #pragma unroll
    for (int ds_ = 0; ds_ < 2; ++ds_)
      #pragma unroll
      for (int i = 0; i < 4; ++i)
        Lo[w][lane][q*8 + ds_*4 + i] = oacc[q][ds_][i];
  Lo[w][lane][16] = l0;
  Lo[w][lane][17] = l1;
  __syncthreads();
  if (w < 2) {
    const int qgv = w;
    const int w0i = qgv*2, w1i = qgv*2 + 1;
    #pragma unroll
    for (int q = 0; q < 2; ++q) {
      float o[8];
      #pragma unroll
      for (int i = 0; i < 8; ++i)
        o[i] = Lo[w0i][lane][q*8 + i] + Lo[w1i][lane][q*8 + i];
      float ls = Lo[w0i][lane][16 + q] + Lo[w1i][lane][16 + q];
      ls += __shfl_xor(ls, 16);
      ls += __shfl_xor(ls, 32);
      const float inv = 1.f / ls;
      const int row = (q64 << 6) + (qgv << 5) + q*16 + c;
      ushort* orow = O + (size_t)(b*SEQ + row)*DIM + h*32 + g*4;
      const uint32_t w0 = (uint32_t)f2bf(o[0]*inv) | ((uint32_t)f2bf(o[1]*inv) << 16);
      const uint32_t w1 = (uint32_t)f2bf(o[2]*inv) | ((uint32_t)f2bf(o[3]*inv) << 16);
      const uint32_t w2 = (uint32_t)f2bf(o[4]*inv) | ((uint32_t)f2bf(o[5]*inv) << 16);
      const uint32_t w3 = (uint32_t)f2bf(o[6]*inv) | ((uint32_t)f2bf(o[7]*inv) << 16);
      *(uint32_t*)(orow)      = w0;
      *(uint32_t*)(orow + 2)  = w1;
      *(uint32_t*)(orow + 16) = w2;
      *(uint32_t*)(orow + 18) = w3;
    }
  }
}

// ---------------- layer-2 decode attention, 4-way key split (partials) ----------------
__global__ __launch_bounds__(256) void decode512(
    const ushort* __restrict__ x2b, const ushort* __restrict__ Wq1,
    const float* __restrict__ bq1, const ushort* __restrict__ kh,
    const ushort* __restrict__ vh, const float* __restrict__ bm2l,
    float* __restrict__ P)
{
  const int lin = blockIdx.x;
  const int ks = lin & 3, bh = lin >> 2;
  const int b = bh >> 3, h = bh & 7;
  const int tid = threadIdx.x;
  const float scale2 = 0.17677669529663687f * 1.4426950408889634f;
  __shared__ float xrow[256];
  __shared__ float qv[32];
  xrow[tid] = bf2f(x2b[(size_t)(b*SEQ)*DIM + tid]);
  __syncthreads();
  if (tid < 32) {
    const ushort* wrow = Wq1 + (size_t)(h*32 + tid)*DIM;
    float acc = bq1[h*32 + tid];
    #pragma unroll
    for (int k8 = 0; k8 < 32; ++k8) {
      const bf16x8 wv = *(const bf16x8*)(wrow + k8*8);
      #pragma unroll
      for (int j = 0; j < 8; ++j)
        acc = fmaf(bf2f((ushort)wv[j]), xrow[k8*8 + j], acc);
    }
    qv[tid] = acc;
  }
  __syncthreads();
  const int key = ks*256 + tid;
  const ushort* kr = kh + (((size_t)bh*SEQ + key) << 5);
  float dot = 0.f;
  #pragma unroll
  for (int i = 0; i < 4; ++i) {
    const bf16x8 kv8 = *(const bf16x8*)(kr + i*8);
    #pragma unroll
    for (int j = 0; j < 8; ++j)
      dot = fmaf(bf2f((ushort)kv8[j]), qv[i*8 + j], dot);
  }
  const float e = exp2_n(fmaf(dot, scale2, bm2l[b*SEQ + key]));
  const ushort* vr = vh + (((size_t)bh*SEQ + key) << 5);
  __shared__ float red[256][33];
  #pragma unroll
  for (int i = 0; i < 4; ++i) {
    const bf16x8 vv8 = *(const bf16x8*)(vr + i*8);
    #pragma unroll
    for (int j = 0; j < 8; ++j)
      red[tid][i*8 + j] = e * bf2f((ushort)vv8[j]);
  }
  red[tid][32] = e;
  __syncthreads();
  for (int s = 128; s >= 1; s >>= 1) {
    for (int i = tid; i < s*33; i += 256) {
      const int r = i / 33, d = i - r*33;
      red[r][d] += red[r + s][d];
    }
    __syncthreads();
  }
  if (tid < 33) P[((size_t)bh*4 + ks)*33 + tid] = red[0][tid];
}

// ---------------- Wo GEMV, weight-stationary: grid 64, block = 4 cols x 8 batches ----------------
__global__ __launch_bounds__(256) void wo_part(
    const float* __restrict__ P, const ushort* __restrict__ WoT1,
    const float* __restrict__ bo1, float* __restrict__ wo_out)
{
  const int cc = blockIdx.x, tid = threadIdx.x;
  __shared__ float orow[8][256];
  {
    const int b = tid >> 5, d32 = tid & 31;
    #pragma unroll
    for (int h = 0; h < 8; ++h) {
      const float* pp = P + ((size_t)(b*8 + h)*4)*33;
      float ov = 0.f, l = 0.f;
      #pragma unroll
      for (int ks = 0; ks < 4; ++ks) { ov += pp[ks*33 + d32]; l += pp[ks*33 + 32]; }
      orow[b][h*32 + d32] = ov / l;
    }
  }
  __syncthreads();
  const int w = tid >> 6, lane = tid & 63;
  const int col = cc*4 + w;
  const ushort* wrow = WoT1 + (size_t)col*DIM + lane*4;
  float wk[4];
  #pragma unroll
  for (int j = 0; j < 4; ++j) wk[j] = bf2f(wrow[j]);
  #pragma unroll
  for (int b = 0; b < 8; ++b) {
    float p = 0.f;
    #pragma unroll
    for (int j = 0; j < 4; ++j) p = fmaf(wk[j], orow[b][lane*4 + j], p);
    #pragma unroll
    for (int off = 32; off >= 1; off >>= 1) p += __shfl_xor(p, off);
    if (lane == 0) wo_out[b*DIM + col] = p + bo1[col];
  }
}

// ---------------- FF1 GEMV + in-block residual/LN2: grid 64 ----------------
__global__ __launch_bounds__(256) void ff1_part(
    const float* __restrict__ x, const float* __restrict__ wo_out,
    const float* __restrict__ g21, const float* __restrict__ be21,
    const ushort* __restrict__ W1T1, const float* __restrict__ b11,
    float* __restrict__ mid)
{
  const int cc = blockIdx.x, tid = threadIdx.x;
  const int wave = tid >> 6, lane = tid & 63;
  __shared__ float trow[8][256];
  #pragma unroll
  for (int b = 0; b < 8; ++b)
    trow[b][tid] = x[(size_t)(b*SEQ)*DIM + tid] + wo_out[b*DIM + tid];
  __syncthreads();
  #pragma unroll
  for (int bb_ = 0; bb_ < 2; ++bb_) {
    const int b = wave + bb_*4;
    float4 vv = *(float4*)&trow[b][lane*4];
    float sm = vv.x + vv.y + vv.z + vv.w;
    #pragma unroll
    for (int o = 32; o >= 1; o >>= 1) sm += __shfl_xor(sm, o);
    const float mean = sm * (1.f/256.f);
    const float dx0 = vv.x-mean, dx1 = vv.y-mean, dx2 = vv.z-mean, dx3 = vv.w-mean;
    float q = dx0*dx0 + dx1*dx1 + dx2*dx2 + dx3*dx3;
    #pragma unroll
    for (int o = 32; o >= 1; o >>= 1) q += __shfl_xor(q, o);
    const float rs = rsqrtf(q * (1.f/256.f) + 1e-5f);
    const float4 gv = *(const float4*)(g21 + lane*4);
    const float4 bv = *(const float4*)(be21 + lane*4);
    float4 nv;
    nv.x = dx0*rs*gv.x + bv.x;
    nv.y = dx1*rs*gv.y + bv.y;
    nv.z = dx2*rs*gv.z + bv.z;
    nv.w = dx3*rs*gv.w + bv.w;
    *(float4*)&trow[b][lane*4] = nv;
  }
  __syncthreads();
  const int dotid = tid >> 1;
  const int col = cc*16 + (dotid & 15);
  const int b = dotid >> 4;
  const int kh_ = (tid & 1) * 128;
  const ushort* wrow = W1T1 + (size_t)col*DIM + kh_;
  float acc = 0.f;
  #pragma unroll
  for (int k8 = 0; k8 < 16; ++k8) {
    const bf16x8 wv = *(const bf16x8*)(wrow + k8*8);
    #pragma unroll
    for (int j = 0; j < 8; ++j)
      acc = fmaf(bf2f((ushort)wv[j]), trow[b][kh_ + k8*8 + j], acc);
  }
  acc += __shfl_xor(acc, 1);
  if ((tid & 1) == 0) mid[b*FFD + col] = fmaxf(acc + b11[col], 0.f);
}

// ---------------- FF2 GEMV + residual: grid 64 ----------------
__global__ __launch_bounds__(256) void ff2_part(
    const float* __restrict__ mid, const ushort* __restrict__ W2T1,
    const float* __restrict__ b21, const float* __restrict__ x,
    const float* __restrict__ wo_out, float* __restrict__ y2)
{
  const int cc = blockIdx.x, tid = threadIdx.x;
  __shared__ float mrow[8][1024];
  #pragma unroll
  for (int i = 0; i < 32; ++i) {
    const int idx = i*256 + tid;
    mrow[idx >> 10][idx & 1023] = mid[idx];
  }
  __syncthreads();
  const int dotid = tid >> 3;
  const int col = cc*4 + (dotid & 3);
  const int b = dotid >> 2;
  const int seg = (tid & 7) * 128;
  const ushort* wrow = W2T1 + (size_t)col*FFD + seg;
  float acc = 0.f;
  #pragma unroll
  for (int k8 = 0; k8 < 16; ++k8) {
    const bf16x8 wv = *(const bf16x8*)(wrow + k8*8);
    #pragma unroll
    for (int j = 0; j < 8; ++j)
      acc = fmaf(bf2f((ushort)wv[j]), mrow[b][seg + k8*8 + j], acc);
  }
  acc += __shfl_xor(acc, 1);
  acc += __shfl_xor(acc, 2);
  acc += __shfl_xor(acc, 4);
  if ((tid & 7) == 0)
    y2[b*DIM + col] = x[(size_t)(b*SEQ)*DIM + col] + wo_out[b*DIM + col]
                    + acc + b21[col];
}

// ---------------- final LN + classifier on y2 rows (grid 8) ----------------
__global__ __launch_bounds__(256) void cls2(
    const float* __restrict__ y2, const float* __restrict__ gf,
    const float* __restrict__ bfb, const float* __restrict__ Wc,
    const float* __restrict__ bc, float* __restrict__ out)
{
  const int b = blockIdx.x, tid = threadIdx.x;
  const int wave = tid >> 6, lane = tid & 63;
  const float v = y2[b*DIM + tid];
  __shared__ float redm[4], redv[4], redc[4][4];
  float s = v;
  #pragma unroll
  for (int o = 32; o >= 1; o >>= 1) s += __shfl_xor(s, o);
  if (lane == 0) redm[wave] = s;
  __syncthreads();
  const float mean = (redm[0]+redm[1]+redm[2]+redm[3]) * (1.f/256.f);
  const float dv = v - mean;
  float q = dv * dv;
  #pragma unroll
  for (int o = 32; o >= 1; o >>= 1) q += __shfl_xor(q, o);
  if (lane == 0) redv[wave] = q;
  __syncthreads();
  const float var = (redv[0]+redv[1]+redv[2]+redv[3]) * (1.f/256.f);
  const float rs = rsqrtf(var + 1e-5f);
  const float yn = dv*rs*gf[tid] + bfb[tid];
  float pc[4];
  #pragma unroll
  for (int cc = 0; cc < 4; ++cc) pc[cc] = yn * Wc[tid*4 + cc];
  #pragma unroll
  for (int cc = 0; cc < 4; ++cc) {
    #pragma unroll
    for (int o = 32; o >= 1; o >>= 1) pc[cc] += __shfl_xor(pc[cc], o);
  }
  if (lane == 0) {
    #pragma unroll
    for (int cc = 0; cc < 4; ++cc) redc[wave][cc] = pc[cc];
  }
  __syncthreads();
  if (tid < 4)
    out[b*4 + tid] = redc[0][tid] + redc[1][tid] + redc[2][tid] + redc[3][tid] + bc[tid];
}

extern "C" void kernel_launch(void* const* d_in, const int* in_sizes, int n_in,
                              void* d_out, int out_size, void* d_ws, size_t ws_size,
                              hipStream_t stream)
{
  const int*   ids    = (const int*)d_in[0];
  const int*   ngrams = (const int*)d_in[1];
  const float* tfidf  = (const float*)d_in[2];
  const float* emb    = (const float*)d_in[3];
  const float* pos    = (const float*)d_in[4];
  const float* bucket = (const float*)d_in[5];
  const float* Wq = (const float*)d_in[6];  const float* bq = (const float*)d_in[7];
  const float* Wk = (const float*)d_in[8];  const float* bk = (const float*)d_in[9];
  const float* Wv = (const float*)d_in[10]; const float* bv = (const float*)d_in[11];
  const float* Wo = (const float*)d_in[12]; const float* bo = (const float*)d_in[13];
  const float* g1 = (const float*)d_in[14]; const float* be1= (const float*)d_in[15];
  const float* g2 = (const float*)d_in[16]; const float* be2= (const float*)d_in[17];
  const float* W1 = (const float*)d_in[18]; const float* b1 = (const float*)d_in[19];
  const float* W2 = (const float*)d_in[20]; const float* b2 = (const float*)d_in[21];
  const float* alpha = (const float*)d_in[22];
  const float* gf = (const float*)d_in[23]; const float* bf = (const float*)d_in[24];
  const float* Wc = (const float*)d_in[25]; const float* bc = (const float*)d_in[26];

  uint8_t* base = (uint8_t*)d_ws;
  float*  x      = (float*)  base;                  //  8,388,608
  ushort* x2b    = (ushort*)(base + 8388608);       //  4,194,304
  ushort* qkh    = (ushort*)(base + 12582912);      //  8,388,608 (Q head-major, K at +QKSTRIDE)
  ushort* vtb    = (ushort*)(base + 20971520);      //  4,194,304 (V permuted l0 / V head-major l1)
  ushort* attb   = (ushort*)(base + 25165824);      //  4,194,304 (l0 attn out; later tail scratch)
  ushort* midb   = (ushort*)(base + 29360128);      // 16,777,216
  float*  bm2    = (float*) (base + 46137344);      //     65,536 (2 layers)
  ushort* WqkvT  = (ushort*)(base + 46202880);      //    786,432
  ushort* WoT    = (ushort*)(base + 46989312);      //    262,144
  ushort* W1T    = (ushort*)(base + 47251456);      //  1,048,576
  ushort* W2T    = (ushort*)(base + 48300032);      //  1,048,576  -> 49,348,608 total

  // tail scratch carved from attb region (dead after gemm64_acc<256> of layer 0)
  float* P       = (float*)(base + 25165824);            // 33,792 B
  float* wo_out  = (float*)(base + 25165824 + 65536);    // 8 KB
  float* midf    = (float*)(base + 25165824 + 90112);    // 32 KB
  float* y2      = (float*)(base + 25165824 + 122880);   // 8 KB

  TDescs td;
  for (int l = 0; l < NL; ++l) {
    td.d[6*l+0] = { Wq + (size_t)l*DIM*DIM, WqkvT + (size_t)l*768*DIM +   0*DIM, DIM, DIM };
    td.d[6*l+1] = { Wk + (size_t)l*DIM*DIM, WqkvT + (size_t)l*768*DIM + 256*DIM, DIM, DIM };
    td.d[6*l+2] = { Wv + (size_t)l*DIM*DIM, WqkvT + (size_t)l*768*DIM + 512*DIM, DIM, DIM };
    td.d[6*l+3] = { Wo + (size_t)l*DIM*DIM, WoT  + (size_t)l*DIM*DIM,  DIM, DIM };
    td.d[6*l+4] = { W1 + (size_t)l*DIM*FFD, W1T  + (size_t)l*FFD*DIM,  DIM, FFD };
    td.d[6*l+5] = { W2 + (size_t)l*FFD*DIM, W2T  + (size_t)l*DIM*FFD,  FFD, DIM };
  }
  transpose_conv<<<dim3(32, 32, 12), 256, 0, stream>>>(td);

  embed_ln_kernel<<<TOK/4, 256, 0, stream>>>(
      ids, ngrams, tfidf, emb, pos, bucket, alpha, g1, be1, x, x2b, bm2);

  const dim3 gqkv(6, TOK/64), gkv(4, TOK/64), gff1(8, TOK/64), g64(4, TOK/64);

  // ---------- layer 0: full pipeline ----------
  gemm_mfma<256, 768, 3><<<gqkv, 256, 0, stream>>>(
      x2b, WqkvT, bq, bk, bv, qkh, vtb);
  attn_mfma<<<1024, 256, 0, stream>>>(qkh, qkh + QKSTRIDE, vtb, bm2, attb);
  gemm64_acc<256><<<g64, 256, 0, stream>>>(attb, WoT, bo, x);
  ln_bf16<<<TOK/4, 256, 0, stream>>>(x, g2, be2, x2b);
  gemm_mfma<256, 1024, 1><<<gff1, 256, 0, stream>>>(
      x2b, W1T, b1, nullptr, nullptr, midb, nullptr);
  gemm64_acc<1024><<<g64, 256, 0, stream>>>(midb, W2T, b2, x);

  // ---------- layer 1: only row 0 per batch feeds the output ----------
  ln_bf16<<<TOK/4, 256, 0, stream>>>(x, g1 + DIM, be1 + DIM, x2b);
  gemm_mfma<256, 512, 4><<<gkv, 256, 0, stream>>>(
      x2b, WqkvT + (size_t)768*DIM + 256*DIM, bk + DIM, bv + DIM, nullptr,
      qkh + QKSTRIDE, vtb);
  decode512<<<256, 256, 0, stream>>>(
      x2b, WqkvT + (size_t)768*DIM, bq + DIM,
      qkh + QKSTRIDE, vtb, bm2 + TOK, P);
  wo_part<<<64, 256, 0, stream>>>(P, WoT + DIM*DIM, bo + DIM, wo_out);
  ff1_part<<<64, 256, 0, stream>>>(x, wo_out, g2 + DIM, be2 + DIM,
                                   W1T + FFD*DIM, b1 + FFD, midf);
  ff2_part<<<64, 256, 0, stream>>>(midf, W2T + DIM*FFD, b2 + DIM, x, wo_out, y2);
  cls2<<<8, 256, 0, stream>>>(y2, gf, bf, Wc, bc, (float*)d_out);
}